// Round 7
// baseline (589.267 us; speedup 1.0000x reference)
//
#include <hip/hip_runtime.h>

typedef _Float16 f16;
typedef _Float16 f16x8 __attribute__((ext_vector_type(8)));
typedef _Float16 f16x4 __attribute__((ext_vector_type(4)));
typedef float    f32x4 __attribute__((ext_vector_type(4)));

#define N_TOK   100000
#define NPAD    100032         // 3126 * 32 = 1563 * 64
#define NT1     1563           // 64-row n-tiles
#define CDIM    512
#define KSTEPS  (NPAD/32)      // 3126
#define K2SPL   128            // split-K slots

// ---------------- workspace layout (bytes) ----------------
#define O_WT     ((size_t)0)                       // w^T fp16 [512][NPAD]
#define SZ_WT    ((size_t)512*NPAD*2)
#define O_YT     (O_WT + SZ_WT)                    // y^T fp16 [64][NPAD]
#define SZ_YT    ((size_t)64*NPAD*2)
#define O_WFR    (O_YT + SZ_YT)                    // frag-linear W+w1 fp16
#define SZ_WFR   ((size_t)16*4*9*64*8*2)
#define O_SPP    (O_WFR + SZ_WFR)                  // s_pre partials [128][32768] f32
#define SZ_SPP   ((size_t)K2SPL*32768*4)
#define O_DPP    (O_SPP + SZ_SPP)                  // d partials [128][512] f32
#define SZ_DPP   ((size_t)K2SPL*512*4)
#define O_SPRE   (O_DPP + SZ_DPP)                  // s_pre [512][64] f32
#define SZ_SPRE  ((size_t)32768*4)
#define O_DSTD   (O_SPRE + SZ_SPRE)                // d [512] f32
#define SZ_DSTD  ((size_t)512*4)
#define O_SOUT   (O_DSTD + SZ_DSTD)                // s_out^T fp16 [8][64dh][64m]
#define SZ_SOUT  ((size_t)8*64*64*2)

// ---------------- K0: pack W = [w_slice; w1] (576x512) into MFMA-fragment-linear fp16 ----------------
__global__ void k0_pack(const float* __restrict__ wsf, const float* __restrict__ w1f,
                        f16* __restrict__ wfr) {
    int c = blockIdx.x * 256 + threadIdx.x;      // 36864 chunks total
    int lane = c & 63, g = c >> 6;               // g in 0..575
    int u  = g % 9,  r = g / 9;                  // r in 0..63
    int we = r & 3,  kg = r >> 2;
    int col = lane & 15, quad = lane >> 4;
    int k = kg * 32 + quad * 8;
    const float* src;
    if (u < 8) src = wsf + (size_t)(we*128 + u*16 + col) * CDIM + k;
    else       src = w1f + (size_t)(we*16  + col) * CDIM + k;
    float4 a = *(const float4*)(src);
    float4 b = *(const float4*)(src + 4);
    f16x8 h;
    h[0]=(f16)a.x; h[1]=(f16)a.y; h[2]=(f16)a.z; h[3]=(f16)a.w;
    h[4]=(f16)b.x; h[5]=(f16)b.y; h[6]=(f16)b.z; h[7]=(f16)b.w;
    *(f16x8*)(wfr + (size_t)c * 8) = h;
}

// ---------------- K1: slice GEMM + softmax + y GEMM (4-way hg split, 4 waves/SIMD) ----------------
// grid = 4*NT1. Block hg covers heads {hg*2, hg*2+1} x 64 rows. Wave w owns head
// hg*2+(w&1) for rows (w>>1)*32..+32: accS[2][4]=32 AGPR (+accY[2][2] on hg0).
// Softmax is wave-private (rows partitioned). XCD pairing: 4 co-tile blocks 8 apart.
#define XROW 40
#define TPITCH 72                                // wT stage pitch (f16)
__launch_bounds__(256, 4)
__global__ void k1_slice(const float* __restrict__ x, const float* __restrict__ temperature,
                         const f16* __restrict__ wfr, const float* __restrict__ bsl,
                         f16* __restrict__ wT, f16* __restrict__ yT) {
    __shared__ f16 smem[128 * TPITCH];           // 18432 B, aliased 2 ways
    f16* lX = smem;                               // [2][64*XROW] = 10240 B
    f16* lT = smem;                               // [128][TPITCH]

    const int tid  = threadIdx.x;
    const int w    = tid >> 6;
    const int lane = tid & 63;
    const int quad = lane >> 4;
    const int col  = lane & 15;

    // bid -> (ntile, hg): groups of 4 co-tile blocks land on the same XCD (8 apart)
    const int b = blockIdx.x;
    int nt, hg;
    if (b < 6240) { nt = (b >> 5) * 8 + (b & 7); hg = (b >> 3) & 3; }
    else          { int t = b - 6240; nt = 1560 + (t >> 2); hg = t & 3; }
    const int n0 = nt * 64;
    const int hd = hg * 2 + (w & 1);             // head owned by this wave
    const int nh = w >> 1;                       // n-half (0: rows 0-31, 1: rows 32-63)

    const int srow = tid >> 2, sch = tid & 3;
    int snr = n0 + srow; if (snr > N_TOK - 1) snr = N_TOK - 1;
    const float* sbase = x + (size_t)snr * CDIM + sch * 8;

    {
        float4 a = *(const float4*)(sbase);
        float4 bb = *(const float4*)(sbase + 4);
        f16x8 hh;
        hh[0]=(f16)a.x; hh[1]=(f16)a.y; hh[2]=(f16)a.z; hh[3]=(f16)a.w;
        hh[4]=(f16)bb.x; hh[5]=(f16)bb.y; hh[6]=(f16)bb.z; hh[7]=(f16)bb.w;
        *(f16x8*)(&lX[srow * XROW + sch * 8]) = hh;
    }

    f32x4 accS[2][4];
    f32x4 accY[2][2];
    #pragma unroll
    for (int nf = 0; nf < 2; ++nf) {
        #pragma unroll
        for (int j = 0; j < 4; ++j) accS[nf][j] = f32x4{0.f,0.f,0.f,0.f};
        #pragma unroll
        for (int jy = 0; jy < 2; ++jy) accY[nf][jy] = f32x4{0.f,0.f,0.f,0.f};
    }

    __syncthreads();

    #pragma unroll 2
    for (int kg = 0; kg < 16; ++kg) {
        const f16* wb = wfr + ((size_t)(kg*4 + (hd >> 1)) * 9 + (size_t)(hd & 1) * 4) * 512
                            + (size_t)lane * 8;
        f16x8 bf[4];
        #pragma unroll
        for (int j = 0; j < 4; ++j) bf[j] = *(const f16x8*)(wb + j * 512);
        f16x8 bfy[2];
        if (hg == 0) {
            #pragma unroll
            for (int jy = 0; jy < 2; ++jy)
                bfy[jy] = *(const f16x8*)(wfr + ((size_t)(kg*4 + ((w & 1)*2 + jy)) * 9 + 8) * 512
                                               + (size_t)lane * 8);
        }

        float4 xa, xb;
        if (kg < 15) {
            xa = *(const float4*)(sbase + (kg + 1) * 32);
            xb = *(const float4*)(sbase + (kg + 1) * 32 + 4);
        }

        const f16* xbuf = lX + (kg & 1) * (64 * XROW);
        f16x8 af[2];
        #pragma unroll
        for (int nf = 0; nf < 2; ++nf)
            af[nf] = *(const f16x8*)(xbuf + (nh*32 + nf*16 + col) * XROW + quad * 8);

        #pragma unroll
        for (int nf = 0; nf < 2; ++nf)
            #pragma unroll
            for (int j = 0; j < 4; ++j)
                accS[nf][j] = __builtin_amdgcn_mfma_f32_16x16x32_f16(af[nf], bf[j], accS[nf][j], 0, 0, 0);
        if (hg == 0) {
            #pragma unroll
            for (int nf = 0; nf < 2; ++nf)
                #pragma unroll
                for (int jy = 0; jy < 2; ++jy)
                    accY[nf][jy] = __builtin_amdgcn_mfma_f32_16x16x32_f16(af[nf], bfy[jy], accY[nf][jy], 0, 0, 0);
        }

        if (kg < 15) {
            f16x8 hh;
            hh[0]=(f16)xa.x; hh[1]=(f16)xa.y; hh[2]=(f16)xa.z; hh[3]=(f16)xa.w;
            hh[4]=(f16)xb.x; hh[5]=(f16)xb.y; hh[6]=(f16)xb.z; hh[7]=(f16)xb.w;
            *(f16x8*)(&lX[((kg + 1) & 1) * (64 * XROW) + srow * XROW + sch * 8]) = hh;
        }
        __syncthreads();
    }

    // ---- bias + temperature (one head per wave) ----
    #pragma unroll
    for (int j = 0; j < 4; ++j) {
        float bb = bsl[hd*64 + j*16 + col];
        #pragma unroll
        for (int nf = 0; nf < 2; ++nf)
            #pragma unroll
            for (int r = 0; r < 4; ++r) accS[nf][j][r] += bb;
    }
    float tv = temperature[hd];
    tv = fminf(fmaxf(tv, 0.1f), 5.0f);
    const float invt = 1.0f / tv;

    // ---- softmax over M=64 (4 frags x 16 cols), wave-private rows; wT staged to LDS ----
    #pragma unroll
    for (int nf = 0; nf < 2; ++nf) {
        const int nloc = nh*32 + nf*16 + quad*4;
        float mx[4];
        #pragma unroll
        for (int r = 0; r < 4; ++r) {
            float m01 = fmaxf(accS[nf][0][r], accS[nf][1][r]);
            float m23 = fmaxf(accS[nf][2][r], accS[nf][3][r]);
            mx[r] = fmaxf(m01, m23);
        }
        #pragma unroll
        for (int d = 1; d < 16; d <<= 1)
            #pragma unroll
            for (int r = 0; r < 4; ++r) mx[r] = fmaxf(mx[r], __shfl_xor(mx[r], d));
        float sm[4] = {0.f, 0.f, 0.f, 0.f};
        #pragma unroll
        for (int j = 0; j < 4; ++j)
            #pragma unroll
            for (int r = 0; r < 4; ++r) {
                float ev = __expf((accS[nf][j][r] - mx[r]) * invt);
                accS[nf][j][r] = ev;
                sm[r] += ev;
            }
        #pragma unroll
        for (int d = 1; d < 16; d <<= 1)
            #pragma unroll
            for (int r = 0; r < 4; ++r) sm[r] += __shfl_xor(sm[r], d);
        #pragma unroll
        for (int r = 0; r < 4; ++r) sm[r] = 1.0f / sm[r];
        #pragma unroll
        for (int j = 0; j < 4; ++j) {
            f16x4 pk;
            #pragma unroll
            for (int r = 0; r < 4; ++r) {
                int n = n0 + nloc + r;
                float wv = (n < N_TOK) ? accS[nf][j][r] * sm[r] : 0.0f;
                pk[r] = (f16)wv;
            }
            int e_loc = (w & 1)*64 + j*16 + col;     // local e within block's 128
            *(f16x4*)(lT + (size_t)e_loc*TPITCH + nloc) = pk;
        }
        if (hg == 0) {
            #pragma unroll
            for (int jy = 0; jy < 2; ++jy) {
                f16x4 pk;
                #pragma unroll
                for (int r = 0; r < 4; ++r) {
                    int n = n0 + nloc + r;
                    pk[r] = (n < N_TOK) ? (f16)accY[nf][jy][r] : (f16)0.f;
                }
                int d = ((w & 1)*2 + jy)*16 + col;
                *(f16x4*)(yT + (size_t)d * NPAD + n0 + nloc) = pk;
            }
        }
    }
    __syncthreads();

    // ---- coalesced wT store: 128 e-rows x 64 n ----
    #pragma unroll
    for (int i = 0; i < 4; ++i) {
        int id = tid + i*256;                 // 1024 = 128 rows x 8 chunks(8 f16)
        int e = id >> 3, p = id & 7;
        f16x8 v = *(const f16x8*)(lT + (size_t)e*TPITCH + p*8);
        *(f16x8*)(wT + (size_t)(hg*128 + e)*NPAD + n0 + p*8) = v;
    }
}

// ---------------- K2: s_pre = sum_n w[n,e]*y[n,d]  (contiguous split-K x e-quarter) ----------------
#define K2_LOAD(AF, BF, kss)                                                         \
    {   int nb_ = (kss)*32 + quad*8;                                                 \
        _Pragma("unroll")                                                            \
        for (int v = 0; v < 4; ++v)                                                  \
            BF[v] = *(const f16x8*)(yT + (size_t)(v*16 + col)*NPAD + nb_);           \
        _Pragma("unroll")                                                            \
        for (int u = 0; u < 2; ++u)                                                  \
            AF[u] = *(const f16x8*)(wT + (size_t)(ebase + u*16 + col)*NPAD + nb_);   \
    }
#define K2_MFMA(AF, BF)                                                              \
    {   _Pragma("unroll")                                                            \
        for (int u = 0; u < 2; ++u) {                                                \
            _Pragma("unroll")                                                        \
            for (int v = 0; v < 4; ++v)                                              \
                acc[u][v] = __builtin_amdgcn_mfma_f32_16x16x32_f16(AF[u], BF[v], acc[u][v], 0, 0, 0); \
            float s_ = 0.f;                                                          \
            _Pragma("unroll")                                                        \
            for (int j = 0; j < 8; ++j) s_ += (float)AF[u][j];                       \
            dac[u] += s_;                                                            \
        }                                                                            \
    }
__launch_bounds__(256, 4)
__global__ void k2_spre(const f16* __restrict__ wT, const f16* __restrict__ yT,
                        float* __restrict__ spp, float* __restrict__ dpp) {
    const int tid = threadIdx.x, wave = tid >> 6, lane = tid & 63;
    const int quad = lane >> 4, col = lane & 15;
    const int slot = blockIdx.x >> 2, equad = blockIdx.x & 3;
    const int ebase = equad * 128 + wave * 32;

    const int ks0 = (slot * KSTEPS) >> 7;
    const int ks1 = ((slot + 1) * KSTEPS) >> 7;

    f32x4 acc[2][4];
    float dac[2];
    #pragma unroll
    for (int u = 0; u < 2; ++u) {
        dac[u] = 0.f;
        #pragma unroll
        for (int v = 0; v < 4; ++v) acc[u][v] = f32x4{0.f,0.f,0.f,0.f};
    }

    f16x8 afA[2], bfA[4], afB[2], bfB[4];
    K2_LOAD(afA, bfA, ks0)
    int ks = ks0;
    for (; ks + 2 <= ks1; ks += 2) {
        K2_LOAD(afB, bfB, ks + 1)
        K2_MFMA(afA, bfA)
        K2_LOAD(afA, bfA, ks + 2)   // one-step overread stays inside workspace; unused
        K2_MFMA(afB, bfB)
    }
    if (ks < ks1) K2_MFMA(afA, bfA)

    #pragma unroll
    for (int u = 0; u < 2; ++u) {
        dac[u] += __shfl_xor(dac[u], 16);
        dac[u] += __shfl_xor(dac[u], 32);
    }
    if (quad == 0) {
        #pragma unroll
        for (int u = 0; u < 2; ++u)
            dpp[slot*512 + ebase + u*16 + col] = dac[u];
    }
    float* dst = spp + (size_t)slot * 32768 + (size_t)equad * 8192;
    #pragma unroll
    for (int u = 0; u < 2; ++u)
        #pragma unroll
        for (int v = 0; v < 4; ++v)
            *(f32x4*)(dst + (size_t)((wave*2 + u)*4 + v)*256 + (size_t)lane*4) = acc[u][v];
}

// ---------------- K2r: reduce partials, de-swizzle frag order ----------------
__global__ void k2r_reduce(const float* __restrict__ spp, const float* __restrict__ dpp,
                           float* __restrict__ spre, float* __restrict__ dstd) {
    int i = blockIdx.x*256 + threadIdx.x;   // 32768
    float s = 0.f;
    for (int p = 0; p < K2SPL; ++p) s += spp[(size_t)p*32768 + i];
    int r = i & 3, L = (i >> 2) & 63, v = (i >> 8) & 3, g = (i >> 10) & 7, eq = (i >> 13) & 3;
    int e = eq*128 + (g >> 1)*32 + (g & 1)*16 + (L >> 4)*4 + r;
    int d = v*16 + (L & 15);
    spre[e*64 + d] = s;
    if (i < 512) {
        float tt = 0.f;
        for (int p = 0; p < K2SPL; ++p) tt += dpp[p*512 + i];
        dstd[i] = tt;
    }
}

// ---------------- K3: per-head middle block, m-split 8 ways (grid 64) ----------------
__global__ void k3_attn(const float* __restrict__ spre, const float* __restrict__ dstd,
                        const float* __restrict__ b1, const float* __restrict__ wq,
                        const float* __restrict__ wk, const float* __restrict__ wv,
                        const float* __restrict__ w3, const float* __restrict__ b3,
                        f16* __restrict__ sout) {
    __shared__ float wa[64][65], wb[64][65], wc[64][65];   // wq,wk,wv; wa reused for w3
    __shared__ float ss[64][65], kk[64][65], vv[64][65];
    __shared__ float qq[8][65], sc[8][65];                 // slice-local (8 m-rows)
    const int h = blockIdx.x >> 3, ms = blockIdx.x & 7, tid = threadIdx.x;

    for (int i = tid; i < 4096; i += 256) {
        int r = i >> 6, c = i & 63;
        wa[r][c] = wq[i];
        wb[r][c] = wk[i];
        wc[r][c] = wv[i];
        ss[r][c] = spre[h*4096 + i] / (dstd[h*64 + r] + 1e-5f) + b1[c];
    }
    __syncthreads();

    // k, v full (64 rows)
    #pragma unroll
    for (int it = 0; it < 16; ++it) {
        int m = it*4 + (tid >> 6), e = tid & 63;
        float ak = 0.f, av = 0.f;
        #pragma unroll 8
        for (int d = 0; d < 64; ++d) {
            float sv = ss[m][d];
            ak += sv * wb[e][d];
            av += sv * wc[e][d];
        }
        kk[m][e] = ak; vv[m][e] = av;
    }
    // q: slice only (8 rows)
    #pragma unroll
    for (int it = 0; it < 2; ++it) {
        int ml = it*4 + (tid >> 6), e = tid & 63;
        float aq = 0.f;
        #pragma unroll 8
        for (int d = 0; d < 64; ++d) aq += ss[ms*8 + ml][d] * wa[e][d];
        qq[ml][e] = aq;
    }
    __syncthreads();

    // scores (slice); stage w3 into wa (wq dead after qq)
    for (int i = tid; i < 4096; i += 256) wa[i >> 6][i & 63] = w3[i];
    #pragma unroll
    for (int it = 0; it < 2; ++it) {
        int ml = it*4 + (tid >> 6), l = tid & 63;
        float a = 0.f;
        #pragma unroll 8
        for (int e = 0; e < 64; ++e) a += qq[ml][e] * kk[l][e];
        sc[ml][l] = a * 0.125f;
    }
    __syncthreads();

    if (tid < 8) {
        int ml = tid;
        float mx = -1e30f;
        #pragma unroll 8
        for (int l = 0; l < 64; ++l) mx = fmaxf(mx, sc[ml][l]);
        float sm = 0.f;
        #pragma unroll 8
        for (int l = 0; l < 64; ++l) { float ev = __expf(sc[ml][l] - mx); sc[ml][l] = ev; sm += ev; }
        float rs = 1.0f / sm;
        #pragma unroll 8
        for (int l = 0; l < 64; ++l) sc[ml][l] *= rs;
    }
    __syncthreads();

    // s_att (slice) -> qq
    #pragma unroll
    for (int it = 0; it < 2; ++it) {
        int ml = it*4 + (tid >> 6), e = tid & 63;
        float a = 0.f;
        #pragma unroll 8
        for (int l = 0; l < 64; ++l) a += sc[ml][l] * vv[l][e];
        qq[ml][e] = a;
    }
    __syncthreads();

    // s_out^T slice: all 64 d, 8 m
    #pragma unroll
    for (int it = 0; it < 2; ++it) {
        int d = it*32 + (tid >> 3), ml = tid & 7;
        float a = b3[d];
        #pragma unroll 8
        for (int e = 0; e < 64; ++e) a += qq[ml][e] * wa[d][e];
        sout[(h*64 + d)*64 + ms*8 + ml] = (f16)a;
    }
}

// ---------------- K4: deslice x_out = w @ s_out (wT gather, XCD-swizzled, coalesced stores) ----------------
#define K4PITCH 36                               // f16; 72 B rows, <=2-way LDS banks
__launch_bounds__(256, 4)
__global__ void k4_deslice(const f16* __restrict__ wT, const f16* __restrict__ sout,
                           float* __restrict__ out) {
    __shared__ __align__(16) char lmem[512 * K4PITCH * 2];   // 36864 B, aliased
    f16*   ldsW = (f16*)lmem;                    // [512][K4PITCH] gather stage
    float* ldsO = (float*)lmem;                  // [16][516] f32 store stage (33024 B)

    const int tid = threadIdx.x, wave = tid >> 6, lane = tid & 63;
    const int quad = lane >> 4, col = lane & 15;

    // bijective XCD swizzle (nwg = 3126 = 8*390 + 6): neighbors share wT lines
    const int bid = blockIdx.x;
    const int xcd = bid & 7, idx = bid >> 3;
    const int q = KSTEPS >> 3, r = KSTEPS & 7;   // 390, 6
    const int swz = (xcd < r ? xcd*(q+1) : r*(q+1) + (xcd - r)*q) + idx;
    const int n0 = swz * 32;

    // stage wT[:, n0:n0+32] -> ldsW[e][nlocal]
    #pragma unroll
    for (int i = 0; i < 8; ++i) {
        int id = tid + i*256;               // 2048 = 512 rows x 4 chunks(8 f16 = 16 B)
        int e = id >> 2, p = id & 3;
        f16x8 v = *(const f16x8*)(wT + (size_t)e*NPAD + n0 + p*8);
        *(f16x8*)(ldsW + (size_t)e*K4PITCH + p*8) = v;
    }
    __syncthreads();

    f32x4 acc[2][2][4];
    #pragma unroll
    for (int hh = 0; hh < 2; ++hh)
        #pragma unroll
        for (int t = 0; t < 2; ++t)
            #pragma unroll
            for (int v = 0; v < 4; ++v) acc[hh][t][v] = f32x4{0.f,0.f,0.f,0.f};

    #pragma unroll
    for (int hh = 0; hh < 2; ++hh) {
        int h = wave*2 + hh;
        #pragma unroll
        for (int ks = 0; ks < 2; ++ks) {
            f16x8 af[2], bf[4];
            #pragma unroll
            for (int t = 0; t < 2; ++t) {
                f16x8 a;
                #pragma unroll
                for (int j = 0; j < 8; ++j)
                    a[j] = ldsW[(size_t)(h*64 + ks*32 + quad*8 + j)*K4PITCH + t*16 + col];
                af[t] = a;
            }
            #pragma unroll
            for (int v = 0; v < 4; ++v)
                bf[v] = *(const f16x8*)(sout + (size_t)(h*64 + v*16 + col)*64 + ks*32 + quad*8);
            #pragma unroll
            for (int t = 0; t < 2; ++t)
                #pragma unroll
                for (int v = 0; v < 4; ++v)
                    acc[hh][t][v] = __builtin_amdgcn_mfma_f32_16x16x32_f16(af[t], bf[v], acc[hh][t][v], 0, 0, 0);
        }
    }

    // ---- epilogue: LDS transpose -> fully coalesced 2 KB-row stores (2 passes of 16 n) ----
    #pragma unroll
    for (int p = 0; p < 2; ++p) {
        __syncthreads();                         // p0: ldsW reads done; p1: p0 stores done
        #pragma unroll
        for (int hh = 0; hh < 2; ++hh) {
            int h = wave*2 + hh;
            #pragma unroll
            for (int v = 0; v < 4; ++v)
                #pragma unroll
                for (int r2 = 0; r2 < 4; ++r2)
                    ldsO[(size_t)(quad*4 + r2)*516 + h*64 + v*16 + col] = acc[hh][p][v][r2];
        }
        __syncthreads();
        #pragma unroll
        for (int it = 0; it < 8; ++it) {
            int id = tid + it*256;               // 2048 chunks of 16 B (16 rows x 128)
            int row = id >> 7, ch = id & 127;
            int n = n0 + p*16 + row;
            if (n < N_TOK) {
                float4 v4 = *(const float4*)(ldsO + (size_t)row*516 + ch*4);
                *(float4*)(out + (size_t)n*512 + ch*4) = v4;
            }
        }
    }
}

// ---------------- launcher ----------------
extern "C" void kernel_launch(void* const* d_in, const int* in_sizes, int n_in,
                              void* d_out, int out_size, void* d_ws, size_t ws_size,
                              hipStream_t stream) {
    const float* x           = (const float*)d_in[0];
    const float* temperature = (const float*)d_in[1];
    const float* w_slice     = (const float*)d_in[2];
    const float* b_slice     = (const float*)d_in[3];
    const float* w1          = (const float*)d_in[4];
    const float* b1          = (const float*)d_in[5];
    const float* wq          = (const float*)d_in[6];
    const float* wk          = (const float*)d_in[7];
    const float* wv          = (const float*)d_in[8];
    const float* w3          = (const float*)d_in[9];
    const float* b3          = (const float*)d_in[10];
    float* out = (float*)d_out;
    char*  ws  = (char*)d_ws;

    f16*   wT    = (f16*)(ws + O_WT);
    f16*   yT    = (f16*)(ws + O_YT);
    f16*   wfr   = (f16*)(ws + O_WFR);
    float* spp   = (float*)(ws + O_SPP);
    float* dpp   = (float*)(ws + O_DPP);
    float* spre  = (float*)(ws + O_SPRE);
    float* dstd  = (float*)(ws + O_DSTD);
    f16*   sout  = (f16*)(ws + O_SOUT);

    k0_pack<<<144, 256, 0, stream>>>(w_slice, w1, wfr);
    k1_slice<<<NT1*4, 256, 0, stream>>>(x, temperature, wfr, b_slice, wT, yT);
    k2_spre<<<K2SPL*4, 256, 0, stream>>>(wT, yT, spp, dpp);
    k2r_reduce<<<128, 256, 0, stream>>>(spp, dpp, spre, dstd);
    k3_attn<<<64, 256, 0, stream>>>(spre, dstd, b1, wq, wk, wv, w3, b3, sout);
    k4_deslice<<<KSTEPS, 256, 0, stream>>>(wT, sout, out);
}

// Round 8
// 587.629 us; speedup vs baseline: 1.0028x; 1.0028x over previous
//
#include <hip/hip_runtime.h>

typedef _Float16 f16;
typedef _Float16 f16x8 __attribute__((ext_vector_type(8)));
typedef _Float16 f16x4 __attribute__((ext_vector_type(4)));
typedef float    f32x4 __attribute__((ext_vector_type(4)));

#define N_TOK   100000
#define NPAD    100032         // 3126 * 32 = 1563 * 64
#define NT1     1563           // 64-row n-tiles
#define CDIM    512
#define KSTEPS  (NPAD/32)      // 3126
#define K2SPL   128            // split-K slots

// ---------------- workspace layout (bytes) ----------------
#define O_WT     ((size_t)0)                       // w^T fp16 [512][NPAD]
#define SZ_WT    ((size_t)512*NPAD*2)
#define O_YT     (O_WT + SZ_WT)                    // y^T fp16 [64][NPAD]
#define SZ_YT    ((size_t)64*NPAD*2)
#define O_WFR    (O_YT + SZ_YT)                    // frag-linear W+w1 fp16
#define SZ_WFR   ((size_t)16*4*9*64*8*2)
#define O_SPP    (O_WFR + SZ_WFR)                  // s_pre partials [128][32768] f32
#define SZ_SPP   ((size_t)K2SPL*32768*4)
#define O_DPP    (O_SPP + SZ_SPP)                  // d partials [128][512] f32
#define SZ_DPP   ((size_t)K2SPL*512*4)
#define O_SPRE   (O_DPP + SZ_DPP)                  // s_pre [512][64] f32
#define SZ_SPRE  ((size_t)32768*4)
#define O_DSTD   (O_SPRE + SZ_SPRE)                // d [512] f32
#define SZ_DSTD  ((size_t)512*4)
#define O_SOUT   (O_DSTD + SZ_DSTD)                // s_out^T fp16 [8][64dh][64m]
#define SZ_SOUT  ((size_t)8*64*64*2)

// ---------------- K0: pack W = [w_slice; w1] (576x512) into MFMA-fragment-linear fp16 ----------------
__global__ void k0_pack(const float* __restrict__ wsf, const float* __restrict__ w1f,
                        f16* __restrict__ wfr) {
    int c = blockIdx.x * 256 + threadIdx.x;      // 36864 chunks total
    int lane = c & 63, g = c >> 6;               // g in 0..575
    int u  = g % 9,  r = g / 9;                  // r in 0..63
    int we = r & 3,  kg = r >> 2;
    int col = lane & 15, quad = lane >> 4;
    int k = kg * 32 + quad * 8;
    const float* src;
    if (u < 8) src = wsf + (size_t)(we*128 + u*16 + col) * CDIM + k;
    else       src = w1f + (size_t)(we*16  + col) * CDIM + k;
    float4 a = *(const float4*)(src);
    float4 b = *(const float4*)(src + 4);
    f16x8 h;
    h[0]=(f16)a.x; h[1]=(f16)a.y; h[2]=(f16)a.z; h[3]=(f16)a.w;
    h[4]=(f16)b.x; h[5]=(f16)b.y; h[6]=(f16)b.z; h[7]=(f16)b.w;
    *(f16x8*)(wfr + (size_t)c * 8) = h;
}

// ---------------- K1: slice GEMM + softmax + y GEMM (r5 shape, BK=128: 4 barriers) ----------------
// grid = 2*NT1: bid = nt*2 + hgrp; block = 4 waves, wave owns head hgrp*4+wave.
// K-loop: 4 outer steps of K=128 (one barrier each; drains amortized 4x vs K=32),
// 4 inner sub-steps with no barriers. X tile double-buffered (2 x 64 x 136 f16).
#define XR128 136                                // padded row for 128-col step
#define TPITCH 72                                // wT stage pitch (f16)
__launch_bounds__(256, 3)
__global__ void k1_slice(const float* __restrict__ x, const float* __restrict__ temperature,
                         const f16* __restrict__ wfr, const float* __restrict__ bsl,
                         f16* __restrict__ wT, f16* __restrict__ yT) {
    __shared__ f16 smem[256 * TPITCH];           // 36864 B; lX (34816 B) aliases lT
    f16* lX = smem;                               // [2][64*XR128]
    f16* lT = smem;                               // [256][TPITCH]

    const int tid  = threadIdx.x;
    const int wave = tid >> 6;
    const int lane = tid & 63;
    const int quad = lane >> 4;
    const int col  = lane & 15;
    const int hgrp = blockIdx.x & 1;
    const int n0   = (blockIdx.x >> 1) * 64;
    const int h    = hgrp * 4 + wave;            // head owned by this wave

    // staging role: thread -> (row srow, chunk sch); step kgo covers cols kgo*128..+128
    const int srow = tid >> 2, sch = tid & 3;
    int snr = n0 + srow; if (snr > N_TOK - 1) snr = N_TOK - 1;
    const float* sbase = x + (size_t)snr * CDIM + sch * 8;

    // prologue: stage step 0 (cols 0..127) into buf 0
    #pragma unroll
    for (int c = 0; c < 4; ++c) {
        float4 a  = *(const float4*)(sbase + c * 32);
        float4 bb = *(const float4*)(sbase + c * 32 + 4);
        f16x8 hh;
        hh[0]=(f16)a.x;  hh[1]=(f16)a.y;  hh[2]=(f16)a.z;  hh[3]=(f16)a.w;
        hh[4]=(f16)bb.x; hh[5]=(f16)bb.y; hh[6]=(f16)bb.z; hh[7]=(f16)bb.w;
        *(f16x8*)(&lX[srow * XR128 + c * 32 + sch * 8]) = hh;
    }

    f32x4 acc[4][5];
    #pragma unroll
    for (int nf = 0; nf < 4; ++nf)
        #pragma unroll
        for (int u = 0; u < 5; ++u) acc[nf][u] = f32x4{0.f,0.f,0.f,0.f};

    __syncthreads();

    for (int kgo = 0; kgo < 4; ++kgo) {
        // issue next outer-step's x loads early (land under this step's 64-144 MFMAs)
        float4 nxa[4], nxb[4];
        if (kgo < 3) {
            #pragma unroll
            for (int c = 0; c < 4; ++c) {
                nxa[c] = *(const float4*)(sbase + (kgo + 1) * 128 + c * 32);
                nxb[c] = *(const float4*)(sbase + (kgo + 1) * 128 + c * 32 + 4);
            }
        }

        const f16* xbuf = lX + (kgo & 1) * (64 * XR128);
        #pragma unroll
        for (int kk = 0; kk < 4; ++kk) {
            const int kg = kgo * 4 + kk;
            const f16* wb = wfr + ((size_t)(kg*4 + (h >> 1)) * 9 + (size_t)(h & 1) * 4) * 512
                                + (size_t)lane * 8;
            f16x8 bf[4];
            #pragma unroll
            for (int j = 0; j < 4; ++j) bf[j] = *(const f16x8*)(wb + j * 512);
            f16x8 bfy;
            if (hgrp == 0)
                bfy = *(const f16x8*)(wfr + ((size_t)(kg*4 + wave) * 9 + 8) * 512 + (size_t)lane * 8);

            f16x8 af[4];
            #pragma unroll
            for (int nf = 0; nf < 4; ++nf)
                af[nf] = *(const f16x8*)(xbuf + (nf*16 + col) * XR128 + kk * 32 + quad * 8);

            #pragma unroll
            for (int nf = 0; nf < 4; ++nf)
                #pragma unroll
                for (int j = 0; j < 4; ++j)
                    acc[nf][j] = __builtin_amdgcn_mfma_f32_16x16x32_f16(af[nf], bf[j], acc[nf][j], 0, 0, 0);
            if (hgrp == 0) {
                #pragma unroll
                for (int nf = 0; nf < 4; ++nf)
                    acc[nf][4] = __builtin_amdgcn_mfma_f32_16x16x32_f16(af[nf], bfy, acc[nf][4], 0, 0, 0);
            }
        }

        // write staged x into the other buffer (readers of it finished at last barrier)
        if (kgo < 3) {
            f16* dstb = lX + ((kgo + 1) & 1) * (64 * XR128);
            #pragma unroll
            for (int c = 0; c < 4; ++c) {
                f16x8 hh;
                hh[0]=(f16)nxa[c].x; hh[1]=(f16)nxa[c].y; hh[2]=(f16)nxa[c].z; hh[3]=(f16)nxa[c].w;
                hh[4]=(f16)nxb[c].x; hh[5]=(f16)nxb[c].y; hh[6]=(f16)nxb[c].z; hh[7]=(f16)nxb[c].w;
                *(f16x8*)(&dstb[srow * XR128 + c * 32 + sch * 8]) = hh;
            }
        }
        __syncthreads();
    }

    // ---- bias + temperature (one head per wave) ----
    #pragma unroll
    for (int j = 0; j < 4; ++j) {
        float bb = bsl[h*64 + j*16 + col];
        #pragma unroll
        for (int nf = 0; nf < 4; ++nf)
            #pragma unroll
            for (int r = 0; r < 4; ++r) acc[nf][j][r] += bb;
    }
    float tv = temperature[h];
    tv = fminf(fmaxf(tv, 0.1f), 5.0f);
    const float invt = 1.0f / tv;

    // ---- softmax over M=64 (4 frags x 16 cols); wT staged to LDS ----
    #pragma unroll
    for (int nf = 0; nf < 4; ++nf) {
        const int nloc = nf*16 + quad*4;
        float mx[4];
        #pragma unroll
        for (int r = 0; r < 4; ++r) {
            float m01 = fmaxf(acc[nf][0][r], acc[nf][1][r]);
            float m23 = fmaxf(acc[nf][2][r], acc[nf][3][r]);
            mx[r] = fmaxf(m01, m23);
        }
        #pragma unroll
        for (int d = 1; d < 16; d <<= 1)
            #pragma unroll
            for (int r = 0; r < 4; ++r) mx[r] = fmaxf(mx[r], __shfl_xor(mx[r], d));
        float sm[4] = {0.f, 0.f, 0.f, 0.f};
        #pragma unroll
        for (int j = 0; j < 4; ++j)
            #pragma unroll
            for (int r = 0; r < 4; ++r) {
                float ev = __expf((acc[nf][j][r] - mx[r]) * invt);
                acc[nf][j][r] = ev;
                sm[r] += ev;
            }
        #pragma unroll
        for (int d = 1; d < 16; d <<= 1)
            #pragma unroll
            for (int r = 0; r < 4; ++r) sm[r] += __shfl_xor(sm[r], d);
        #pragma unroll
        for (int r = 0; r < 4; ++r) sm[r] = 1.0f / sm[r];
        #pragma unroll
        for (int j = 0; j < 4; ++j) {
            f16x4 pk;
            #pragma unroll
            for (int r = 0; r < 4; ++r) {
                int n = n0 + nloc + r;
                float wv = (n < N_TOK) ? acc[nf][j][r] * sm[r] : 0.0f;
                pk[r] = (f16)wv;
            }
            int e_loc = wave*64 + j*16 + col;        // local e within block's 256
            *(f16x4*)(lT + (size_t)e_loc*TPITCH + nloc) = pk;
        }
        if (hgrp == 0) {
            f16x4 pk;
            #pragma unroll
            for (int r = 0; r < 4; ++r) {
                int n = n0 + nloc + r;
                pk[r] = (n < N_TOK) ? (f16)acc[nf][4][r] : (f16)0.f;
            }
            *(f16x4*)(yT + (size_t)(wave*16 + col) * NPAD + n0 + nloc) = pk;
        }
    }
    __syncthreads();

    // ---- coalesced wT store: 256 e-rows x 64 n ----
    #pragma unroll
    for (int i = 0; i < 8; ++i) {
        int id = tid + i*256;                 // 2048 = 256 rows x 8 chunks(8 f16)
        int e = id >> 3, p = id & 7;
        f16x8 v = *(const f16x8*)(lT + (size_t)e*TPITCH + p*8);
        *(f16x8*)(wT + (size_t)(hgrp*256 + e)*NPAD + n0 + p*8) = v;
    }
}

// ---------------- K2: s_pre = sum_n w[n,e]*y[n,d]  (contiguous split-K x e-quarter) ----------------
#define K2_LOAD(AF, BF, kss)                                                         \
    {   int nb_ = (kss)*32 + quad*8;                                                 \
        _Pragma("unroll")                                                            \
        for (int v = 0; v < 4; ++v)                                                  \
            BF[v] = *(const f16x8*)(yT + (size_t)(v*16 + col)*NPAD + nb_);           \
        _Pragma("unroll")                                                            \
        for (int u = 0; u < 2; ++u)                                                  \
            AF[u] = *(const f16x8*)(wT + (size_t)(ebase + u*16 + col)*NPAD + nb_);   \
    }
#define K2_MFMA(AF, BF)                                                              \
    {   _Pragma("unroll")                                                            \
        for (int u = 0; u < 2; ++u) {                                                \
            _Pragma("unroll")                                                        \
            for (int v = 0; v < 4; ++v)                                              \
                acc[u][v] = __builtin_amdgcn_mfma_f32_16x16x32_f16(AF[u], BF[v], acc[u][v], 0, 0, 0); \
            float s_ = 0.f;                                                          \
            _Pragma("unroll")                                                        \
            for (int j = 0; j < 8; ++j) s_ += (float)AF[u][j];                       \
            dac[u] += s_;                                                            \
        }                                                                            \
    }
__launch_bounds__(256, 4)
__global__ void k2_spre(const f16* __restrict__ wT, const f16* __restrict__ yT,
                        float* __restrict__ spp, float* __restrict__ dpp) {
    const int tid = threadIdx.x, wave = tid >> 6, lane = tid & 63;
    const int quad = lane >> 4, col = lane & 15;
    const int slot = blockIdx.x >> 2, equad = blockIdx.x & 3;
    const int ebase = equad * 128 + wave * 32;

    const int ks0 = (slot * KSTEPS) >> 7;
    const int ks1 = ((slot + 1) * KSTEPS) >> 7;

    f32x4 acc[2][4];
    float dac[2];
    #pragma unroll
    for (int u = 0; u < 2; ++u) {
        dac[u] = 0.f;
        #pragma unroll
        for (int v = 0; v < 4; ++v) acc[u][v] = f32x4{0.f,0.f,0.f,0.f};
    }

    f16x8 afA[2], bfA[4], afB[2], bfB[4];
    K2_LOAD(afA, bfA, ks0)
    int ks = ks0;
    for (; ks + 2 <= ks1; ks += 2) {
        K2_LOAD(afB, bfB, ks + 1)
        K2_MFMA(afA, bfA)
        K2_LOAD(afA, bfA, ks + 2)   // one-step overread stays inside workspace; unused
        K2_MFMA(afB, bfB)
    }
    if (ks < ks1) K2_MFMA(afA, bfA)

    #pragma unroll
    for (int u = 0; u < 2; ++u) {
        dac[u] += __shfl_xor(dac[u], 16);
        dac[u] += __shfl_xor(dac[u], 32);
    }
    if (quad == 0) {
        #pragma unroll
        for (int u = 0; u < 2; ++u)
            dpp[slot*512 + ebase + u*16 + col] = dac[u];
    }
    float* dst = spp + (size_t)slot * 32768 + (size_t)equad * 8192;
    #pragma unroll
    for (int u = 0; u < 2; ++u)
        #pragma unroll
        for (int v = 0; v < 4; ++v)
            *(f32x4*)(dst + (size_t)((wave*2 + u)*4 + v)*256 + (size_t)lane*4) = acc[u][v];
}

// ---------------- K2r: reduce partials, de-swizzle frag order ----------------
__global__ void k2r_reduce(const float* __restrict__ spp, const float* __restrict__ dpp,
                           float* __restrict__ spre, float* __restrict__ dstd) {
    int i = blockIdx.x*256 + threadIdx.x;   // 32768
    float s = 0.f;
    for (int p = 0; p < K2SPL; ++p) s += spp[(size_t)p*32768 + i];
    int r = i & 3, L = (i >> 2) & 63, v = (i >> 8) & 3, g = (i >> 10) & 7, eq = (i >> 13) & 3;
    int e = eq*128 + (g >> 1)*32 + (g & 1)*16 + (L >> 4)*4 + r;
    int d = v*16 + (L & 15);
    spre[e*64 + d] = s;
    if (i < 512) {
        float tt = 0.f;
        for (int p = 0; p < K2SPL; ++p) tt += dpp[p*512 + i];
        dstd[i] = tt;
    }
}

// ---------------- K3: per-head middle block, m-split 8 ways (grid 64) ----------------
__global__ void k3_attn(const float* __restrict__ spre, const float* __restrict__ dstd,
                        const float* __restrict__ b1, const float* __restrict__ wq,
                        const float* __restrict__ wk, const float* __restrict__ wv,
                        const float* __restrict__ w3, const float* __restrict__ b3,
                        f16* __restrict__ sout) {
    __shared__ float wa[64][65], wb[64][65], wc[64][65];   // wq,wk,wv; wa reused for w3
    __shared__ float ss[64][65], kk[64][65], vv[64][65];
    __shared__ float qq[8][65], sc[8][65];                 // slice-local (8 m-rows)
    const int h = blockIdx.x >> 3, ms = blockIdx.x & 7, tid = threadIdx.x;

    for (int i = tid; i < 4096; i += 256) {
        int r = i >> 6, c = i & 63;
        wa[r][c] = wq[i];
        wb[r][c] = wk[i];
        wc[r][c] = wv[i];
        ss[r][c] = spre[h*4096 + i] / (dstd[h*64 + r] + 1e-5f) + b1[c];
    }
    __syncthreads();

    // k, v full (64 rows)
    #pragma unroll
    for (int it = 0; it < 16; ++it) {
        int m = it*4 + (tid >> 6), e = tid & 63;
        float ak = 0.f, av = 0.f;
        #pragma unroll 8
        for (int d = 0; d < 64; ++d) {
            float sv = ss[m][d];
            ak += sv * wb[e][d];
            av += sv * wc[e][d];
        }
        kk[m][e] = ak; vv[m][e] = av;
    }
    // q: slice only (8 rows)
    #pragma unroll
    for (int it = 0; it < 2; ++it) {
        int ml = it*4 + (tid >> 6), e = tid & 63;
        float aq = 0.f;
        #pragma unroll 8
        for (int d = 0; d < 64; ++d) aq += ss[ms*8 + ml][d] * wa[e][d];
        qq[ml][e] = aq;
    }
    __syncthreads();

    // scores (slice); stage w3 into wa (wq dead after qq)
    for (int i = tid; i < 4096; i += 256) wa[i >> 6][i & 63] = w3[i];
    #pragma unroll
    for (int it = 0; it < 2; ++it) {
        int ml = it*4 + (tid >> 6), l = tid & 63;
        float a = 0.f;
        #pragma unroll 8
        for (int e = 0; e < 64; ++e) a += qq[ml][e] * kk[l][e];
        sc[ml][l] = a * 0.125f;
    }
    __syncthreads();

    if (tid < 8) {
        int ml = tid;
        float mx = -1e30f;
        #pragma unroll 8
        for (int l = 0; l < 64; ++l) mx = fmaxf(mx, sc[ml][l]);
        float sm = 0.f;
        #pragma unroll 8
        for (int l = 0; l < 64; ++l) { float ev = __expf(sc[ml][l] - mx); sc[ml][l] = ev; sm += ev; }
        float rs = 1.0f / sm;
        #pragma unroll 8
        for (int l = 0; l < 64; ++l) sc[ml][l] *= rs;
    }
    __syncthreads();

    // s_att (slice) -> qq
    #pragma unroll
    for (int it = 0; it < 2; ++it) {
        int ml = it*4 + (tid >> 6), e = tid & 63;
        float a = 0.f;
        #pragma unroll 8
        for (int l = 0; l < 64; ++l) a += sc[ml][l] * vv[l][e];
        qq[ml][e] = a;
    }
    __syncthreads();

    // s_out^T slice: all 64 d, 8 m
    #pragma unroll
    for (int it = 0; it < 2; ++it) {
        int d = it*32 + (tid >> 3), ml = tid & 7;
        float a = b3[d];
        #pragma unroll 8
        for (int e = 0; e < 64; ++e) a += qq[ml][e] * wa[d][e];
        sout[(h*64 + d)*64 + ms*8 + ml] = (f16)a;
    }
}

// ---------------- K4: deslice x_out = w @ s_out (wT gather, XCD-swizzled, coalesced stores) ----------------
#define K4PITCH 36                               // f16; 72 B rows, <=2-way LDS banks
__launch_bounds__(256, 4)
__global__ void k4_deslice(const f16* __restrict__ wT, const f16* __restrict__ sout,
                           float* __restrict__ out) {
    __shared__ __align__(16) char lmem[512 * K4PITCH * 2];   // 36864 B, aliased
    f16*   ldsW = (f16*)lmem;                    // [512][K4PITCH] gather stage
    float* ldsO = (float*)lmem;                  // [16][516] f32 store stage (33024 B)

    const int tid = threadIdx.x, wave = tid >> 6, lane = tid & 63;
    const int quad = lane >> 4, col = lane & 15;

    // bijective XCD swizzle (nwg = 3126 = 8*390 + 6): neighbors share wT lines
    const int bid = blockIdx.x;
    const int xcd = bid & 7, idx = bid >> 3;
    const int q = KSTEPS >> 3, r = KSTEPS & 7;   // 390, 6
    const int swz = (xcd < r ? xcd*(q+1) : r*(q+1) + (xcd - r)*q) + idx;
    const int n0 = swz * 32;

    // stage wT[:, n0:n0+32] -> ldsW[e][nlocal]
    #pragma unroll
    for (int i = 0; i < 8; ++i) {
        int id = tid + i*256;               // 2048 = 512 rows x 4 chunks(8 f16 = 16 B)
        int e = id >> 2, p = id & 3;
        f16x8 v = *(const f16x8*)(wT + (size_t)e*NPAD + n0 + p*8);
        *(f16x8*)(ldsW + (size_t)e*K4PITCH + p*8) = v;
    }
    __syncthreads();

    f32x4 acc[2][2][4];
    #pragma unroll
    for (int hh = 0; hh < 2; ++hh)
        #pragma unroll
        for (int t = 0; t < 2; ++t)
            #pragma unroll
            for (int v = 0; v < 4; ++v) acc[hh][t][v] = f32x4{0.f,0.f,0.f,0.f};

    #pragma unroll
    for (int hh = 0; hh < 2; ++hh) {
        int h = wave*2 + hh;
        #pragma unroll
        for (int ks = 0; ks < 2; ++ks) {
            f16x8 af[2], bf[4];
            #pragma unroll
            for (int t = 0; t < 2; ++t) {
                f16x8 a;
                #pragma unroll
                for (int j = 0; j < 8; ++j)
                    a[j] = ldsW[(size_t)(h*64 + ks*32 + quad*8 + j)*K4PITCH + t*16 + col];
                af[t] = a;
            }
            #pragma unroll
            for (int v = 0; v < 4; ++v)
                bf[v] = *(const f16x8*)(sout + (size_t)(h*64 + v*16 + col)*64 + ks*32 + quad*8);
            #pragma unroll
            for (int t = 0; t < 2; ++t)
                #pragma unroll
                for (int v = 0; v < 4; ++v)
                    acc[hh][t][v] = __builtin_amdgcn_mfma_f32_16x16x32_f16(af[t], bf[v], acc[hh][t][v], 0, 0, 0);
        }
    }

    // ---- epilogue: LDS transpose -> fully coalesced 2 KB-row stores (2 passes of 16 n) ----
    #pragma unroll
    for (int p = 0; p < 2; ++p) {
        __syncthreads();                         // p0: ldsW reads done; p1: p0 stores done
        #pragma unroll
        for (int hh = 0; hh < 2; ++hh) {
            int h = wave*2 + hh;
            #pragma unroll
            for (int v = 0; v < 4; ++v)
                #pragma unroll
                for (int r2 = 0; r2 < 4; ++r2)
                    ldsO[(size_t)(quad*4 + r2)*516 + h*64 + v*16 + col] = acc[hh][p][v][r2];
        }
        __syncthreads();
        #pragma unroll
        for (int it = 0; it < 8; ++it) {
            int id = tid + it*256;               // 2048 chunks of 16 B (16 rows x 128)
            int row = id >> 7, ch = id & 127;
            int n = n0 + p*16 + row;
            if (n < N_TOK) {
                float4 v4 = *(const float4*)(ldsO + (size_t)row*516 + ch*4);
                *(float4*)(out + (size_t)n*512 + ch*4) = v4;
            }
        }
    }
}

// ---------------- launcher ----------------
extern "C" void kernel_launch(void* const* d_in, const int* in_sizes, int n_in,
                              void* d_out, int out_size, void* d_ws, size_t ws_size,
                              hipStream_t stream) {
    const float* x           = (const float*)d_in[0];
    const float* temperature = (const float*)d_in[1];
    const float* w_slice     = (const float*)d_in[2];
    const float* b_slice     = (const float*)d_in[3];
    const float* w1          = (const float*)d_in[4];
    const float* b1          = (const float*)d_in[5];
    const float* wq          = (const float*)d_in[6];
    const float* wk          = (const float*)d_in[7];
    const float* wv          = (const float*)d_in[8];
    const float* w3          = (const float*)d_in[9];
    const float* b3          = (const float*)d_in[10];
    float* out = (float*)d_out;
    char*  ws  = (char*)d_ws;

    f16*   wT    = (f16*)(ws + O_WT);
    f16*   yT    = (f16*)(ws + O_YT);
    f16*   wfr   = (f16*)(ws + O_WFR);
    float* spp   = (float*)(ws + O_SPP);
    float* dpp   = (float*)(ws + O_DPP);
    float* spre  = (float*)(ws + O_SPRE);
    float* dstd  = (float*)(ws + O_DSTD);
    f16*   sout  = (f16*)(ws + O_SOUT);

    k0_pack<<<144, 256, 0, stream>>>(w_slice, w1, wfr);
    k1_slice<<<NT1*2, 256, 0, stream>>>(x, temperature, wfr, b_slice, wT, yT);
    k2_spre<<<K2SPL*4, 256, 0, stream>>>(wT, yT, spp, dpp);
    k2r_reduce<<<128, 256, 0, stream>>>(spp, dpp, spre, dstd);
    k3_attn<<<64, 256, 0, stream>>>(spre, dstd, b1, wq, wk, wv, w3, b3, sout);
    k4_deslice<<<KSTEPS, 256, 0, stream>>>(wT, sout, out);
}

// Round 9
// 546.000 us; speedup vs baseline: 1.0792x; 1.0762x over previous
//
#include <hip/hip_runtime.h>

typedef _Float16 f16;
typedef _Float16 f16x8 __attribute__((ext_vector_type(8)));
typedef _Float16 f16x4 __attribute__((ext_vector_type(4)));
typedef float    f32x4 __attribute__((ext_vector_type(4)));

#define N_TOK   100000
#define NPAD    100032         // 3126 * 32 = 1563 * 64
#define NT1     1563           // 64-row n-tiles
#define CDIM    512
#define KSTEPS  (NPAD/32)      // 3126
#define K2SPL   128            // split-K slots

// ---------------- workspace layout (bytes) ----------------
// wTf: frag-linear w fp16 [KSTEPS][32 e-frags][64 lanes][8]  (102.4 MB)
// yTf: frag-linear y fp16 [KSTEPS][4 d-frags][64 lanes][8]   (12.8 MB)
#define O_WT     ((size_t)0)
#define SZ_WT    ((size_t)512*NPAD*2)
#define O_YT     (O_WT + SZ_WT)
#define SZ_YT    ((size_t)64*NPAD*2)
#define O_WFR    (O_YT + SZ_YT)                    // frag-linear W+w1 fp16
#define SZ_WFR   ((size_t)16*4*9*64*8*2)
#define O_SPP    (O_WFR + SZ_WFR)                  // s_pre partials [128][32768] f32
#define SZ_SPP   ((size_t)K2SPL*32768*4)
#define O_DPP    (O_SPP + SZ_SPP)                  // d partials [128][512] f32
#define SZ_DPP   ((size_t)K2SPL*512*4)
#define O_SPRE   (O_DPP + SZ_DPP)                  // s_pre [512][64] f32
#define SZ_SPRE  ((size_t)32768*4)
#define O_DSTD   (O_SPRE + SZ_SPRE)                // d [512] f32
#define SZ_DSTD  ((size_t)512*4)
#define O_SOUT   (O_DSTD + SZ_DSTD)                // s_out^T fp16 [8][64dh][64m]
#define SZ_SOUT  ((size_t)8*64*64*2)

// ---------------- K0: pack W = [w_slice; w1] (576x512) into MFMA-fragment-linear fp16 ----------------
__global__ void k0_pack(const float* __restrict__ wsf, const float* __restrict__ w1f,
                        f16* __restrict__ wfr) {
    int c = blockIdx.x * 256 + threadIdx.x;      // 36864 chunks total
    int lane = c & 63, g = c >> 6;               // g in 0..575
    int u  = g % 9,  r = g / 9;                  // r in 0..63
    int we = r & 3,  kg = r >> 2;
    int col = lane & 15, quad = lane >> 4;
    int k = kg * 32 + quad * 8;
    const float* src;
    if (u < 8) src = wsf + (size_t)(we*128 + u*16 + col) * CDIM + k;
    else       src = w1f + (size_t)(we*16  + col) * CDIM + k;
    float4 a = *(const float4*)(src);
    float4 b = *(const float4*)(src + 4);
    f16x8 h;
    h[0]=(f16)a.x; h[1]=(f16)a.y; h[2]=(f16)a.z; h[3]=(f16)a.w;
    h[4]=(f16)b.x; h[5]=(f16)b.y; h[6]=(f16)b.z; h[7]=(f16)b.w;
    *(f16x8*)(wfr + (size_t)c * 8) = h;
}

// ---------------- K1: slice GEMM + softmax + y GEMM (r5 proven loop; frag-linear emit) ----------------
// grid = 2*NT1: bid = nt*2 + hgrp; block = 4 waves, wave owns head hgrp*4+wave.
// Epilogue emits wTf/yTf in MFMA-fragment-linear layout so K2/K4 loads are
// wave-contiguous 16B/lane (fixes their 16-way scattered w reads).
#define XROW 40
#define TPITCH 72
__launch_bounds__(256, 3)
__global__ void k1_slice(const float* __restrict__ x, const float* __restrict__ temperature,
                         const f16* __restrict__ wfr, const float* __restrict__ bsl,
                         f16* __restrict__ wTf, f16* __restrict__ yTf) {
    __shared__ f16 smem[320 * TPITCH];           // 46080 B: lT [256][72] + lY [64][72]; lX aliases lT
    f16* lX = smem;                               // [2][64*XROW] = 10240 B
    f16* lT = smem;                               // [256][72]
    f16* lY = smem + 256 * TPITCH;                // [64][72]

    const int tid  = threadIdx.x;
    const int wave = tid >> 6;
    const int lane = tid & 63;
    const int quad = lane >> 4;
    const int col  = lane & 15;
    const int hgrp = blockIdx.x & 1;
    const int nt   = blockIdx.x >> 1;
    const int n0   = nt * 64;
    const int h    = hgrp * 4 + wave;            // head owned by this wave

    const int srow = tid >> 2, sch = tid & 3;
    int snr = n0 + srow; if (snr > N_TOK - 1) snr = N_TOK - 1;
    const float* sbase = x + (size_t)snr * CDIM + sch * 8;

    {
        float4 a = *(const float4*)(sbase);
        float4 bb = *(const float4*)(sbase + 4);
        f16x8 hh;
        hh[0]=(f16)a.x; hh[1]=(f16)a.y; hh[2]=(f16)a.z; hh[3]=(f16)a.w;
        hh[4]=(f16)bb.x; hh[5]=(f16)bb.y; hh[6]=(f16)bb.z; hh[7]=(f16)bb.w;
        *(f16x8*)(&lX[srow * XROW + sch * 8]) = hh;
    }

    f32x4 acc[4][5];
    #pragma unroll
    for (int nf = 0; nf < 4; ++nf)
        #pragma unroll
        for (int u = 0; u < 5; ++u) acc[nf][u] = f32x4{0.f,0.f,0.f,0.f};

    __syncthreads();

    #pragma unroll 2
    for (int kg = 0; kg < 16; ++kg) {
        const f16* wb = wfr + ((size_t)(kg*4 + (h >> 1)) * 9 + (size_t)(h & 1) * 4) * 512
                            + (size_t)lane * 8;
        f16x8 bf[4];
        #pragma unroll
        for (int j = 0; j < 4; ++j) bf[j] = *(const f16x8*)(wb + j * 512);
        f16x8 bfy;
        if (hgrp == 0)
            bfy = *(const f16x8*)(wfr + ((size_t)(kg*4 + wave) * 9 + 8) * 512 + (size_t)lane * 8);

        float4 xa, xb;
        if (kg < 15) {
            xa = *(const float4*)(sbase + (kg + 1) * 32);
            xb = *(const float4*)(sbase + (kg + 1) * 32 + 4);
        }

        const f16* xbuf = lX + (kg & 1) * (64 * XROW);
        f16x8 af[4];
        #pragma unroll
        for (int nf = 0; nf < 4; ++nf)
            af[nf] = *(const f16x8*)(xbuf + (nf*16 + col) * XROW + quad * 8);

        #pragma unroll
        for (int nf = 0; nf < 4; ++nf)
            #pragma unroll
            for (int j = 0; j < 4; ++j)
                acc[nf][j] = __builtin_amdgcn_mfma_f32_16x16x32_f16(af[nf], bf[j], acc[nf][j], 0, 0, 0);
        if (hgrp == 0) {
            #pragma unroll
            for (int nf = 0; nf < 4; ++nf)
                acc[nf][4] = __builtin_amdgcn_mfma_f32_16x16x32_f16(af[nf], bfy, acc[nf][4], 0, 0, 0);
        }

        if (kg < 15) {
            f16x8 hh;
            hh[0]=(f16)xa.x; hh[1]=(f16)xa.y; hh[2]=(f16)xa.z; hh[3]=(f16)xa.w;
            hh[4]=(f16)xb.x; hh[5]=(f16)xb.y; hh[6]=(f16)xb.z; hh[7]=(f16)xb.w;
            *(f16x8*)(&lX[((kg + 1) & 1) * (64 * XROW) + srow * XROW + sch * 8]) = hh;
        }
        __syncthreads();
    }

    // ---- bias + temperature (one head per wave) ----
    #pragma unroll
    for (int j = 0; j < 4; ++j) {
        float bb = bsl[h*64 + j*16 + col];
        #pragma unroll
        for (int nf = 0; nf < 4; ++nf)
            #pragma unroll
            for (int r = 0; r < 4; ++r) acc[nf][j][r] += bb;
    }
    float tv = temperature[h];
    tv = fminf(fmaxf(tv, 0.1f), 5.0f);
    const float invt = 1.0f / tv;

    // ---- softmax over M=64 (4 frags x 16 cols); w -> lT, y -> lY ----
    #pragma unroll
    for (int nf = 0; nf < 4; ++nf) {
        const int nloc = nf*16 + quad*4;
        float mx[4];
        #pragma unroll
        for (int r = 0; r < 4; ++r) {
            float m01 = fmaxf(acc[nf][0][r], acc[nf][1][r]);
            float m23 = fmaxf(acc[nf][2][r], acc[nf][3][r]);
            mx[r] = fmaxf(m01, m23);
        }
        #pragma unroll
        for (int d = 1; d < 16; d <<= 1)
            #pragma unroll
            for (int r = 0; r < 4; ++r) mx[r] = fmaxf(mx[r], __shfl_xor(mx[r], d));
        float sm[4] = {0.f, 0.f, 0.f, 0.f};
        #pragma unroll
        for (int j = 0; j < 4; ++j)
            #pragma unroll
            for (int r = 0; r < 4; ++r) {
                float ev = __expf((acc[nf][j][r] - mx[r]) * invt);
                acc[nf][j][r] = ev;
                sm[r] += ev;
            }
        #pragma unroll
        for (int d = 1; d < 16; d <<= 1)
            #pragma unroll
            for (int r = 0; r < 4; ++r) sm[r] += __shfl_xor(sm[r], d);
        #pragma unroll
        for (int r = 0; r < 4; ++r) sm[r] = 1.0f / sm[r];
        #pragma unroll
        for (int j = 0; j < 4; ++j) {
            f16x4 pk;
            #pragma unroll
            for (int r = 0; r < 4; ++r) {
                int n = n0 + nloc + r;
                float wv = (n < N_TOK) ? acc[nf][j][r] * sm[r] : 0.0f;
                pk[r] = (f16)wv;
            }
            int e_loc = wave*64 + j*16 + col;        // local e within block's 256
            *(f16x4*)(lT + (size_t)e_loc*TPITCH + nloc) = pk;
        }
        if (hgrp == 0) {
            f16x4 pk;
            #pragma unroll
            for (int r = 0; r < 4; ++r) {
                int n = n0 + nloc + r;
                pk[r] = (n < N_TOK) ? (f16)acc[nf][4][r] : (f16)0.f;
            }
            *(f16x4*)(lY + (size_t)(wave*16 + col)*TPITCH + nloc) = pk;
        }
    }
    __syncthreads();

    // ---- frag-linear wTf emit: [ks][f][lane][8], fully coalesced 4KB bursts ----
    // wTf[(ks*32+f)*512 + laneL*8 + j] = w[e=f*16+colL][n=ks*32+quadL*8+j]
    #pragma unroll
    for (int i = 0; i < 8; ++i) {
        int gid = tid + i*256;
        int laneL = gid & 63, chunk = gid >> 6;      // chunk 0..31
        int ks_loc = chunk >> 4, floc = chunk & 15;
        f16x8 v = *(const f16x8*)(lT + (size_t)(floc*16 + (laneL & 15))*TPITCH
                                     + ks_loc*32 + (laneL >> 4)*8);
        *(f16x8*)(wTf + ((size_t)((nt*2 + ks_loc)*32 + hgrp*16 + floc))*512
                       + (size_t)laneL*8) = v;
    }
    // ---- frag-linear yTf emit (hgrp==0): [ks][v][lane][8] ----
    if (hgrp == 0) {
        #pragma unroll
        for (int i = 0; i < 2; ++i) {
            int gid = tid + i*256;
            int laneL = gid & 63, chunk = gid >> 6;  // chunk 0..7
            int ks_loc = chunk >> 2, v4 = chunk & 3;
            f16x8 vv = *(const f16x8*)(lY + (size_t)(v4*16 + (laneL & 15))*TPITCH
                                          + ks_loc*32 + (laneL >> 4)*8);
            *(f16x8*)(yTf + ((size_t)((nt*2 + ks_loc)*4 + v4))*512
                           + (size_t)laneL*8) = vv;
        }
    }
}

// ---------------- K2: s_pre = sum_n w[n,e]*y[n,d]  (frag-linear coalesced loads) ----------------
#define K2_LOAD(AF, BF, kss)                                                         \
    {   _Pragma("unroll")                                                            \
        for (int v = 0; v < 4; ++v)                                                  \
            BF[v] = *(const f16x8*)(yTf + ((size_t)((kss)*4 + v))*512 + (size_t)lane*8); \
        _Pragma("unroll")                                                            \
        for (int u = 0; u < 2; ++u)                                                  \
            AF[u] = *(const f16x8*)(wTf + ((size_t)((kss)*32 + fbase + u))*512 + (size_t)lane*8); \
    }
#define K2_MFMA(AF, BF)                                                              \
    {   _Pragma("unroll")                                                            \
        for (int u = 0; u < 2; ++u) {                                                \
            _Pragma("unroll")                                                        \
            for (int v = 0; v < 4; ++v)                                              \
                acc[u][v] = __builtin_amdgcn_mfma_f32_16x16x32_f16(AF[u], BF[v], acc[u][v], 0, 0, 0); \
            float s_ = 0.f;                                                          \
            _Pragma("unroll")                                                        \
            for (int j = 0; j < 8; ++j) s_ += (float)AF[u][j];                       \
            dac[u] += s_;                                                            \
        }                                                                            \
    }
__launch_bounds__(256, 4)
__global__ void k2_spre(const f16* __restrict__ wTf, const f16* __restrict__ yTf,
                        float* __restrict__ spp, float* __restrict__ dpp) {
    const int tid = threadIdx.x, wave = tid >> 6, lane = tid & 63;
    const int quad = lane >> 4, col = lane & 15;
    const int slot = blockIdx.x >> 2, equad = blockIdx.x & 3;
    const int ebase = equad * 128 + wave * 32;
    const int fbase = equad * 8 + wave * 2;      // e-frag base = ebase/16

    const int ks0 = (slot * KSTEPS) >> 7;
    const int ks1 = ((slot + 1) * KSTEPS) >> 7;

    f32x4 acc[2][4];
    float dac[2];
    #pragma unroll
    for (int u = 0; u < 2; ++u) {
        dac[u] = 0.f;
        #pragma unroll
        for (int v = 0; v < 4; ++v) acc[u][v] = f32x4{0.f,0.f,0.f,0.f};
    }

    f16x8 afA[2], bfA[4], afB[2], bfB[4];
    K2_LOAD(afA, bfA, ks0)
    int ks = ks0;
    for (; ks + 2 <= ks1; ks += 2) {
        K2_LOAD(afB, bfB, ks + 1)
        K2_MFMA(afA, bfA)
        K2_LOAD(afA, bfA, ks + 2)   // one-step overread stays inside workspace; unused
        K2_MFMA(afB, bfB)
    }
    if (ks < ks1) K2_MFMA(afA, bfA)

    #pragma unroll
    for (int u = 0; u < 2; ++u) {
        dac[u] += __shfl_xor(dac[u], 16);
        dac[u] += __shfl_xor(dac[u], 32);
    }
    if (quad == 0) {
        #pragma unroll
        for (int u = 0; u < 2; ++u)
            dpp[slot*512 + ebase + u*16 + col] = dac[u];
    }
    float* dst = spp + (size_t)slot * 32768 + (size_t)equad * 8192;
    #pragma unroll
    for (int u = 0; u < 2; ++u)
        #pragma unroll
        for (int v = 0; v < 4; ++v)
            *(f32x4*)(dst + (size_t)((wave*2 + u)*4 + v)*256 + (size_t)lane*4) = acc[u][v];
}

// ---------------- K2r: reduce partials, de-swizzle frag order ----------------
__global__ void k2r_reduce(const float* __restrict__ spp, const float* __restrict__ dpp,
                           float* __restrict__ spre, float* __restrict__ dstd) {
    int i = blockIdx.x*256 + threadIdx.x;   // 32768
    float s = 0.f;
    for (int p = 0; p < K2SPL; ++p) s += spp[(size_t)p*32768 + i];
    int r = i & 3, L = (i >> 2) & 63, v = (i >> 8) & 3, g = (i >> 10) & 7, eq = (i >> 13) & 3;
    int e = eq*128 + (g >> 1)*32 + (g & 1)*16 + (L >> 4)*4 + r;
    int d = v*16 + (L & 15);
    spre[e*64 + d] = s;
    if (i < 512) {
        float tt = 0.f;
        for (int p = 0; p < K2SPL; ++p) tt += dpp[p*512 + i];
        dstd[i] = tt;
    }
}

// ---------------- K3: per-head middle block, m-split 8 ways (grid 64) ----------------
__global__ void k3_attn(const float* __restrict__ spre, const float* __restrict__ dstd,
                        const float* __restrict__ b1, const float* __restrict__ wq,
                        const float* __restrict__ wk, const float* __restrict__ wv,
                        const float* __restrict__ w3, const float* __restrict__ b3,
                        f16* __restrict__ sout) {
    __shared__ float wa[64][65], wb[64][65], wc[64][65];   // wq,wk,wv; wa reused for w3
    __shared__ float ss[64][65], kk[64][65], vv[64][65];
    __shared__ float qq[8][65], sc[8][65];                 // slice-local (8 m-rows)
    const int h = blockIdx.x >> 3, ms = blockIdx.x & 7, tid = threadIdx.x;

    for (int i = tid; i < 4096; i += 256) {
        int r = i >> 6, c = i & 63;
        wa[r][c] = wq[i];
        wb[r][c] = wk[i];
        wc[r][c] = wv[i];
        ss[r][c] = spre[h*4096 + i] / (dstd[h*64 + r] + 1e-5f) + b1[c];
    }
    __syncthreads();

    // k, v full (64 rows)
    #pragma unroll
    for (int it = 0; it < 16; ++it) {
        int m = it*4 + (tid >> 6), e = tid & 63;
        float ak = 0.f, av = 0.f;
        #pragma unroll 8
        for (int d = 0; d < 64; ++d) {
            float sv = ss[m][d];
            ak += sv * wb[e][d];
            av += sv * wc[e][d];
        }
        kk[m][e] = ak; vv[m][e] = av;
    }
    // q: slice only (8 rows)
    #pragma unroll
    for (int it = 0; it < 2; ++it) {
        int ml = it*4 + (tid >> 6), e = tid & 63;
        float aq = 0.f;
        #pragma unroll 8
        for (int d = 0; d < 64; ++d) aq += ss[ms*8 + ml][d] * wa[e][d];
        qq[ml][e] = aq;
    }
    __syncthreads();

    // scores (slice); stage w3 into wa (wq dead after qq)
    for (int i = tid; i < 4096; i += 256) wa[i >> 6][i & 63] = w3[i];
    #pragma unroll
    for (int it = 0; it < 2; ++it) {
        int ml = it*4 + (tid >> 6), l = tid & 63;
        float a = 0.f;
        #pragma unroll 8
        for (int e = 0; e < 64; ++e) a += qq[ml][e] * kk[l][e];
        sc[ml][l] = a * 0.125f;
    }
    __syncthreads();

    if (tid < 8) {
        int ml = tid;
        float mx = -1e30f;
        #pragma unroll 8
        for (int l = 0; l < 64; ++l) mx = fmaxf(mx, sc[ml][l]);
        float sm = 0.f;
        #pragma unroll 8
        for (int l = 0; l < 64; ++l) { float ev = __expf(sc[ml][l] - mx); sc[ml][l] = ev; sm += ev; }
        float rs = 1.0f / sm;
        #pragma unroll 8
        for (int l = 0; l < 64; ++l) sc[ml][l] *= rs;
    }
    __syncthreads();

    // s_att (slice) -> qq
    #pragma unroll
    for (int it = 0; it < 2; ++it) {
        int ml = it*4 + (tid >> 6), e = tid & 63;
        float a = 0.f;
        #pragma unroll 8
        for (int l = 0; l < 64; ++l) a += sc[ml][l] * vv[l][e];
        qq[ml][e] = a;
    }
    __syncthreads();

    // s_out^T slice: all 64 d, 8 m
    #pragma unroll
    for (int it = 0; it < 2; ++it) {
        int d = it*32 + (tid >> 3), ml = tid & 7;
        float a = b3[d];
        #pragma unroll 8
        for (int e = 0; e < 64; ++e) a += qq[ml][e] * wa[d][e];
        sout[(h*64 + d)*64 + ms*8 + ml] = (f16)a;
    }
}

// ---------------- K4: deslice x_out = w @ s_out (frag-linear contiguous stage + coalesced stores) ----------------
__launch_bounds__(256, 4)
__global__ void k4_deslice(const f16* __restrict__ wTf, const f16* __restrict__ sout,
                           float* __restrict__ out) {
    __shared__ __align__(16) char lmem[36864];   // ldsW 32768 B / ldsO 33024 B, aliased
    f16*   ldsW = (f16*)lmem;                    // [16384] frag-linear w block (ks = this tile)
    float* ldsO = (float*)lmem;                  // [16][516] f32 store stage

    const int tid = threadIdx.x, wave = tid >> 6, lane = tid & 63;
    const int quad = lane >> 4, col = lane & 15;

    // bijective XCD swizzle (nwg = 3126 = 8*390 + 6)
    const int bid = blockIdx.x;
    const int xcd = bid & 7, idx = bid >> 3;
    const int q = KSTEPS >> 3, r = KSTEPS & 7;   // 390, 6
    const int swz = (xcd < r ? xcd*(q+1) : r*(q+1) + (xcd - r)*q) + idx;
    const int n0 = swz * 32;

    // stage: ONE contiguous 32 KB block (frag-linear tile for ks = swz)
    const f16* srcW = wTf + (size_t)swz * 16384;
    #pragma unroll
    for (int i = 0; i < 8; ++i) {
        int id = tid + i*256;
        *(f16x8*)(ldsW + (size_t)id*8) = *(const f16x8*)(srcW + (size_t)id*8);
    }
    __syncthreads();

    f32x4 acc[2][2][4];
    #pragma unroll
    for (int hh = 0; hh < 2; ++hh)
        #pragma unroll
        for (int t = 0; t < 2; ++t)
            #pragma unroll
            for (int v = 0; v < 4; ++v) acc[hh][t][v] = f32x4{0.f,0.f,0.f,0.f};

    #pragma unroll
    for (int hh = 0; hh < 2; ++hh) {
        int h = wave*2 + hh;
        #pragma unroll
        for (int ks = 0; ks < 2; ++ks) {
            f16x8 af[2], bf[4];
            // af[t][j] = w[e=h*64+ks*32+quad*8+j][n=n0+t*16+col], from frag-linear image:
            // idx = (h*4+ks*2+(quad>>1))*512 + (t*2+(col>>3))*128 + (quad&1)*64 + j*8 + (col&7)
            #pragma unroll
            for (int t = 0; t < 2; ++t) {
                const int fb = (h*4 + ks*2 + (quad >> 1))*512
                             + (t*2 + (col >> 3))*128 + (quad & 1)*64 + (col & 7);
                f16x8 a;
                #pragma unroll
                for (int j = 0; j < 8; ++j)
                    a[j] = ldsW[fb + j*8];
                af[t] = a;
            }
            #pragma unroll
            for (int v = 0; v < 4; ++v)
                bf[v] = *(const f16x8*)(sout + (size_t)(h*64 + v*16 + col)*64 + ks*32 + quad*8);
            #pragma unroll
            for (int t = 0; t < 2; ++t)
                #pragma unroll
                for (int v = 0; v < 4; ++v)
                    acc[hh][t][v] = __builtin_amdgcn_mfma_f32_16x16x32_f16(af[t], bf[v], acc[hh][t][v], 0, 0, 0);
        }
    }

    // ---- epilogue: LDS transpose -> fully coalesced 2 KB-row stores (2 passes of 16 n) ----
    #pragma unroll
    for (int p = 0; p < 2; ++p) {
        __syncthreads();                         // p0: ldsW reads done; p1: p0 stores done
        #pragma unroll
        for (int hh = 0; hh < 2; ++hh) {
            int h = wave*2 + hh;
            #pragma unroll
            for (int v = 0; v < 4; ++v)
                #pragma unroll
                for (int r2 = 0; r2 < 4; ++r2)
                    ldsO[(size_t)(quad*4 + r2)*516 + h*64 + v*16 + col] = acc[hh][p][v][r2];
        }
        __syncthreads();
        #pragma unroll
        for (int it = 0; it < 8; ++it) {
            int id = tid + it*256;               // 2048 chunks of 16 B (16 rows x 128)
            int row = id >> 7, ch = id & 127;
            int n = n0 + p*16 + row;
            if (n < N_TOK) {
                float4 v4 = *(const float4*)(ldsO + (size_t)row*516 + ch*4);
                *(float4*)(out + (size_t)n*512 + ch*4) = v4;
            }
        }
    }
}

// ---------------- launcher ----------------
extern "C" void kernel_launch(void* const* d_in, const int* in_sizes, int n_in,
                              void* d_out, int out_size, void* d_ws, size_t ws_size,
                              hipStream_t stream) {
    const float* x           = (const float*)d_in[0];
    const float* temperature = (const float*)d_in[1];
    const float* w_slice     = (const float*)d_in[2];
    const float* b_slice     = (const float*)d_in[3];
    const float* w1          = (const float*)d_in[4];
    const float* b1          = (const float*)d_in[5];
    const float* wq          = (const float*)d_in[6];
    const float* wk          = (const float*)d_in[7];
    const float* wv          = (const float*)d_in[8];
    const float* w3          = (const float*)d_in[9];
    const float* b3          = (const float*)d_in[10];
    float* out = (float*)d_out;
    char*  ws  = (char*)d_ws;

    f16*   wTf   = (f16*)(ws + O_WT);
    f16*   yTf   = (f16*)(ws + O_YT);
    f16*   wfr   = (f16*)(ws + O_WFR);
    float* spp   = (float*)(ws + O_SPP);
    float* dpp   = (float*)(ws + O_DPP);
    float* spre  = (float*)(ws + O_SPRE);
    float* dstd  = (float*)(ws + O_DSTD);
    f16*   sout  = (f16*)(ws + O_SOUT);

    k0_pack<<<144, 256, 0, stream>>>(w_slice, w1, wfr);
    k1_slice<<<NT1*2, 256, 0, stream>>>(x, temperature, wfr, b_slice, wTf, yTf);
    k2_spre<<<K2SPL*4, 256, 0, stream>>>(wTf, yTf, spp, dpp);
    k2r_reduce<<<128, 256, 0, stream>>>(spp, dpp, spre, dstd);
    k3_attn<<<64, 256, 0, stream>>>(spre, dstd, b1, wq, wk, wv, w3, b3, sout);
    k4_deslice<<<KSTEPS, 256, 0, stream>>>(wTf, sout, out);
}

// Round 10
// 544.007 us; speedup vs baseline: 1.0832x; 1.0037x over previous
//
#include <hip/hip_runtime.h>

typedef _Float16 f16;
typedef _Float16 f16x8 __attribute__((ext_vector_type(8)));
typedef _Float16 f16x4 __attribute__((ext_vector_type(4)));
typedef float    f32x4 __attribute__((ext_vector_type(4)));

#define N_TOK   100000
#define NPAD    100032         // 3126 * 32 = 1563 * 64
#define NT1     1563           // 64-row n-tiles
#define CDIM    512
#define KSTEPS  (NPAD/32)      // 3126
#define K2SPL   128            // split-K slots

// ---------------- workspace layout (bytes) ----------------
// wTf: frag-linear w fp16 [KSTEPS][32 e-frags][64 lanes][8]  (102.4 MB)
// yTf: frag-linear y fp16 [KSTEPS][4 d-frags][64 lanes][8]   (12.8 MB)
#define O_WT     ((size_t)0)
#define SZ_WT    ((size_t)512*NPAD*2)
#define O_YT     (O_WT + SZ_WT)
#define SZ_YT    ((size_t)64*NPAD*2)
#define O_WFR    (O_YT + SZ_YT)                    // frag-linear W+w1 fp16
#define SZ_WFR   ((size_t)16*4*9*64*8*2)
#define O_SPP    (O_WFR + SZ_WFR)                  // s_pre partials [128][32768] f32
#define SZ_SPP   ((size_t)K2SPL*32768*4)
#define O_DPP    (O_SPP + SZ_SPP)                  // d partials [128][512] f32
#define SZ_DPP   ((size_t)K2SPL*512*4)
#define O_SPRE   (O_DPP + SZ_DPP)                  // s_pre [512][64] f32
#define SZ_SPRE  ((size_t)32768*4)
#define O_DSTD   (O_SPRE + SZ_SPRE)                // d [512] f32
#define SZ_DSTD  ((size_t)512*4)
#define O_SOUT   (O_DSTD + SZ_DSTD)                // s_out^T fp16 [8][64dh][64m]
#define SZ_SOUT  ((size_t)8*64*64*2)

// ---------------- K0: pack W = [w_slice; w1] (576x512) into MFMA-fragment-linear fp16 ----------------
__global__ void k0_pack(const float* __restrict__ wsf, const float* __restrict__ w1f,
                        f16* __restrict__ wfr) {
    int c = blockIdx.x * 256 + threadIdx.x;      // 36864 chunks total
    int lane = c & 63, g = c >> 6;               // g in 0..575
    int u  = g % 9,  r = g / 9;                  // r in 0..63
    int we = r & 3,  kg = r >> 2;
    int col = lane & 15, quad = lane >> 4;
    int k = kg * 32 + quad * 8;
    const float* src;
    if (u < 8) src = wsf + (size_t)(we*128 + u*16 + col) * CDIM + k;
    else       src = w1f + (size_t)(we*16  + col) * CDIM + k;
    float4 a = *(const float4*)(src);
    float4 b = *(const float4*)(src + 4);
    f16x8 h;
    h[0]=(f16)a.x; h[1]=(f16)a.y; h[2]=(f16)a.z; h[3]=(f16)a.w;
    h[4]=(f16)b.x; h[5]=(f16)b.y; h[6]=(f16)b.z; h[7]=(f16)b.w;
    *(f16x8*)(wfr + (size_t)c * 8) = h;
}

// ---------------- K1: slice GEMM + softmax + y GEMM (r9 structure + rotated bf prefetch) ----------------
// grid = 2*NT1: bid = nt*2 + hgrp; block = 4 waves, wave owns head hgrp*4+wave.
// bf/bfy fragments for step kg+1 are loaded at the TAIL of step kg (pre-barrier):
// their L3 latency overlaps x-write + barrier drain + next step's af reads.
// Same registers (live range tail->MFMAs), so no pressure change vs r9.
#define XROW 40
#define TPITCH 72
__launch_bounds__(256, 3)
__global__ void k1_slice(const float* __restrict__ x, const float* __restrict__ temperature,
                         const f16* __restrict__ wfr, const float* __restrict__ bsl,
                         f16* __restrict__ wTf, f16* __restrict__ yTf) {
    __shared__ f16 smem[320 * TPITCH];           // 46080 B: lT [256][72] + lY [64][72]; lX aliases lT
    f16* lX = smem;                               // [2][64*XROW] = 10240 B
    f16* lT = smem;                               // [256][72]
    f16* lY = smem + 256 * TPITCH;                // [64][72]

    const int tid  = threadIdx.x;
    const int wave = tid >> 6;
    const int lane = tid & 63;
    const int quad = lane >> 4;
    const int col  = lane & 15;
    const int hgrp = blockIdx.x & 1;
    const int nt   = blockIdx.x >> 1;
    const int n0   = nt * 64;
    const int h    = hgrp * 4 + wave;            // head owned by this wave

    const int srow = tid >> 2, sch = tid & 3;
    int snr = n0 + srow; if (snr > N_TOK - 1) snr = N_TOK - 1;
    const float* sbase = x + (size_t)snr * CDIM + sch * 8;

    // per-wave wfr bases (advance by constant per kg)
    const f16* wbase  = wfr + ((size_t)(h >> 1) * 9 + (size_t)(h & 1) * 4) * 512 + (size_t)lane * 8;
    const f16* wybase = wfr + ((size_t)wave * 9 + 8) * 512 + (size_t)lane * 8;
    const size_t KGSTR = (size_t)4 * 9 * 512;    // wfr elements per kg

    {
        float4 a = *(const float4*)(sbase);
        float4 bb = *(const float4*)(sbase + 4);
        f16x8 hh;
        hh[0]=(f16)a.x; hh[1]=(f16)a.y; hh[2]=(f16)a.z; hh[3]=(f16)a.w;
        hh[4]=(f16)bb.x; hh[5]=(f16)bb.y; hh[6]=(f16)bb.z; hh[7]=(f16)bb.w;
        *(f16x8*)(&lX[srow * XROW + sch * 8]) = hh;
    }

    f32x4 acc[4][5];
    #pragma unroll
    for (int nf = 0; nf < 4; ++nf)
        #pragma unroll
        for (int u = 0; u < 5; ++u) acc[nf][u] = f32x4{0.f,0.f,0.f,0.f};

    // prologue: bf/bfy for kg=0 (latency overlaps x-stage barrier)
    f16x8 bf[4];
    #pragma unroll
    for (int j = 0; j < 4; ++j) bf[j] = *(const f16x8*)(wbase + j * 512);
    f16x8 bfy;
    if (hgrp == 0) bfy = *(const f16x8*)(wybase);

    __syncthreads();

    #pragma unroll 2
    for (int kg = 0; kg < 16; ++kg) {
        float4 xa, xb;
        if (kg < 15) {
            xa = *(const float4*)(sbase + (kg + 1) * 32);
            xb = *(const float4*)(sbase + (kg + 1) * 32 + 4);
        }

        const f16* xbuf = lX + (kg & 1) * (64 * XROW);
        f16x8 af[4];
        #pragma unroll
        for (int nf = 0; nf < 4; ++nf)
            af[nf] = *(const f16x8*)(xbuf + (nf*16 + col) * XROW + quad * 8);

        #pragma unroll
        for (int nf = 0; nf < 4; ++nf)
            #pragma unroll
            for (int j = 0; j < 4; ++j)
                acc[nf][j] = __builtin_amdgcn_mfma_f32_16x16x32_f16(af[nf], bf[j], acc[nf][j], 0, 0, 0);
        if (hgrp == 0) {
            #pragma unroll
            for (int nf = 0; nf < 4; ++nf)
                acc[nf][4] = __builtin_amdgcn_mfma_f32_16x16x32_f16(af[nf], bfy, acc[nf][4], 0, 0, 0);
        }

        // rotated prefetch: bf/bfy for kg+1, issued pre-barrier (same registers)
        if (kg < 15) {
            const f16* wb = wbase + (size_t)(kg + 1) * KGSTR;
            #pragma unroll
            for (int j = 0; j < 4; ++j) bf[j] = *(const f16x8*)(wb + j * 512);
            if (hgrp == 0) bfy = *(const f16x8*)(wybase + (size_t)(kg + 1) * KGSTR);
        }

        if (kg < 15) {
            f16x8 hh;
            hh[0]=(f16)xa.x; hh[1]=(f16)xa.y; hh[2]=(f16)xa.z; hh[3]=(f16)xa.w;
            hh[4]=(f16)xb.x; hh[5]=(f16)xb.y; hh[6]=(f16)xb.z; hh[7]=(f16)xb.w;
            *(f16x8*)(&lX[((kg + 1) & 1) * (64 * XROW) + srow * XROW + sch * 8]) = hh;
        }
        __syncthreads();
    }

    // ---- bias + temperature (one head per wave) ----
    #pragma unroll
    for (int j = 0; j < 4; ++j) {
        float bb = bsl[h*64 + j*16 + col];
        #pragma unroll
        for (int nf = 0; nf < 4; ++nf)
            #pragma unroll
            for (int r = 0; r < 4; ++r) acc[nf][j][r] += bb;
    }
    float tv = temperature[h];
    tv = fminf(fmaxf(tv, 0.1f), 5.0f);
    const float invt = 1.0f / tv;

    // ---- softmax over M=64 (4 frags x 16 cols); w -> lT, y -> lY ----
    #pragma unroll
    for (int nf = 0; nf < 4; ++nf) {
        const int nloc = nf*16 + quad*4;
        float mx[4];
        #pragma unroll
        for (int r = 0; r < 4; ++r) {
            float m01 = fmaxf(acc[nf][0][r], acc[nf][1][r]);
            float m23 = fmaxf(acc[nf][2][r], acc[nf][3][r]);
            mx[r] = fmaxf(m01, m23);
        }
        #pragma unroll
        for (int d = 1; d < 16; d <<= 1)
            #pragma unroll
            for (int r = 0; r < 4; ++r) mx[r] = fmaxf(mx[r], __shfl_xor(mx[r], d));
        float sm[4] = {0.f, 0.f, 0.f, 0.f};
        #pragma unroll
        for (int j = 0; j < 4; ++j)
            #pragma unroll
            for (int r = 0; r < 4; ++r) {
                float ev = __expf((acc[nf][j][r] - mx[r]) * invt);
                acc[nf][j][r] = ev;
                sm[r] += ev;
            }
        #pragma unroll
        for (int d = 1; d < 16; d <<= 1)
            #pragma unroll
            for (int r = 0; r < 4; ++r) sm[r] += __shfl_xor(sm[r], d);
        #pragma unroll
        for (int r = 0; r < 4; ++r) sm[r] = 1.0f / sm[r];
        #pragma unroll
        for (int j = 0; j < 4; ++j) {
            f16x4 pk;
            #pragma unroll
            for (int r = 0; r < 4; ++r) {
                int n = n0 + nloc + r;
                float wv = (n < N_TOK) ? acc[nf][j][r] * sm[r] : 0.0f;
                pk[r] = (f16)wv;
            }
            int e_loc = wave*64 + j*16 + col;        // local e within block's 256
            *(f16x4*)(lT + (size_t)e_loc*TPITCH + nloc) = pk;
        }
        if (hgrp == 0) {
            f16x4 pk;
            #pragma unroll
            for (int r = 0; r < 4; ++r) {
                int n = n0 + nloc + r;
                pk[r] = (n < N_TOK) ? (f16)acc[nf][4][r] : (f16)0.f;
            }
            *(f16x4*)(lY + (size_t)(wave*16 + col)*TPITCH + nloc) = pk;
        }
    }
    __syncthreads();

    // ---- frag-linear wTf emit: [ks][f][lane][8], fully coalesced 4KB bursts ----
    #pragma unroll
    for (int i = 0; i < 8; ++i) {
        int gid = tid + i*256;
        int laneL = gid & 63, chunk = gid >> 6;      // chunk 0..31
        int ks_loc = chunk >> 4, floc = chunk & 15;
        f16x8 v = *(const f16x8*)(lT + (size_t)(floc*16 + (laneL & 15))*TPITCH
                                     + ks_loc*32 + (laneL >> 4)*8);
        *(f16x8*)(wTf + ((size_t)((nt*2 + ks_loc)*32 + hgrp*16 + floc))*512
                       + (size_t)laneL*8) = v;
    }
    // ---- frag-linear yTf emit (hgrp==0): [ks][v][lane][8] ----
    if (hgrp == 0) {
        #pragma unroll
        for (int i = 0; i < 2; ++i) {
            int gid = tid + i*256;
            int laneL = gid & 63, chunk = gid >> 6;  // chunk 0..7
            int ks_loc = chunk >> 2, v4 = chunk & 3;
            f16x8 vv = *(const f16x8*)(lY + (size_t)(v4*16 + (laneL & 15))*TPITCH
                                          + ks_loc*32 + (laneL >> 4)*8);
            *(f16x8*)(yTf + ((size_t)((nt*2 + ks_loc)*4 + v4))*512
                           + (size_t)laneL*8) = vv;
        }
    }
}

// ---------------- K2: s_pre = sum_n w[n,e]*y[n,d]  (frag-linear coalesced loads) ----------------
#define K2_LOAD(AF, BF, kss)                                                         \
    {   _Pragma("unroll")                                                            \
        for (int v = 0; v < 4; ++v)                                                  \
            BF[v] = *(const f16x8*)(yTf + ((size_t)((kss)*4 + v))*512 + (size_t)lane*8); \
        _Pragma("unroll")                                                            \
        for (int u = 0; u < 2; ++u)                                                  \
            AF[u] = *(const f16x8*)(wTf + ((size_t)((kss)*32 + fbase + u))*512 + (size_t)lane*8); \
    }
#define K2_MFMA(AF, BF)                                                              \
    {   _Pragma("unroll")                                                            \
        for (int u = 0; u < 2; ++u) {                                                \
            _Pragma("unroll")                                                        \
            for (int v = 0; v < 4; ++v)                                              \
                acc[u][v] = __builtin_amdgcn_mfma_f32_16x16x32_f16(AF[u], BF[v], acc[u][v], 0, 0, 0); \
            float s_ = 0.f;                                                          \
            _Pragma("unroll")                                                        \
            for (int j = 0; j < 8; ++j) s_ += (float)AF[u][j];                       \
            dac[u] += s_;                                                            \
        }                                                                            \
    }
__launch_bounds__(256, 4)
__global__ void k2_spre(const f16* __restrict__ wTf, const f16* __restrict__ yTf,
                        float* __restrict__ spp, float* __restrict__ dpp) {
    const int tid = threadIdx.x, wave = tid >> 6, lane = tid & 63;
    const int quad = lane >> 4, col = lane & 15;
    const int slot = blockIdx.x >> 2, equad = blockIdx.x & 3;
    const int ebase = equad * 128 + wave * 32;
    const int fbase = equad * 8 + wave * 2;      // e-frag base = ebase/16

    const int ks0 = (slot * KSTEPS) >> 7;
    const int ks1 = ((slot + 1) * KSTEPS) >> 7;

    f32x4 acc[2][4];
    float dac[2];
    #pragma unroll
    for (int u = 0; u < 2; ++u) {
        dac[u] = 0.f;
        #pragma unroll
        for (int v = 0; v < 4; ++v) acc[u][v] = f32x4{0.f,0.f,0.f,0.f};
    }

    f16x8 afA[2], bfA[4], afB[2], bfB[4];
    K2_LOAD(afA, bfA, ks0)
    int ks = ks0;
    for (; ks + 2 <= ks1; ks += 2) {
        K2_LOAD(afB, bfB, ks + 1)
        K2_MFMA(afA, bfA)
        K2_LOAD(afA, bfA, ks + 2)   // one-step overread stays inside workspace; unused
        K2_MFMA(afB, bfB)
    }
    if (ks < ks1) K2_MFMA(afA, bfA)

    #pragma unroll
    for (int u = 0; u < 2; ++u) {
        dac[u] += __shfl_xor(dac[u], 16);
        dac[u] += __shfl_xor(dac[u], 32);
    }
    if (quad == 0) {
        #pragma unroll
        for (int u = 0; u < 2; ++u)
            dpp[slot*512 + ebase + u*16 + col] = dac[u];
    }
    float* dst = spp + (size_t)slot * 32768 + (size_t)equad * 8192;
    #pragma unroll
    for (int u = 0; u < 2; ++u)
        #pragma unroll
        for (int v = 0; v < 4; ++v)
            *(f32x4*)(dst + (size_t)((wave*2 + u)*4 + v)*256 + (size_t)lane*4) = acc[u][v];
}

// ---------------- K2r: reduce partials, de-swizzle frag order ----------------
__global__ void k2r_reduce(const float* __restrict__ spp, const float* __restrict__ dpp,
                           float* __restrict__ spre, float* __restrict__ dstd) {
    int i = blockIdx.x*256 + threadIdx.x;   // 32768
    float s = 0.f;
    for (int p = 0; p < K2SPL; ++p) s += spp[(size_t)p*32768 + i];
    int r = i & 3, L = (i >> 2) & 63, v = (i >> 8) & 3, g = (i >> 10) & 7, eq = (i >> 13) & 3;
    int e = eq*128 + (g >> 1)*32 + (g & 1)*16 + (L >> 4)*4 + r;
    int d = v*16 + (L & 15);
    spre[e*64 + d] = s;
    if (i < 512) {
        float tt = 0.f;
        for (int p = 0; p < K2SPL; ++p) tt += dpp[p*512 + i];
        dstd[i] = tt;
    }
}

// ---------------- K3: per-head middle block, m-split 8 ways (grid 64) ----------------
__global__ void k3_attn(const float* __restrict__ spre, const float* __restrict__ dstd,
                        const float* __restrict__ b1, const float* __restrict__ wq,
                        const float* __restrict__ wk, const float* __restrict__ wv,
                        const float* __restrict__ w3, const float* __restrict__ b3,
                        f16* __restrict__ sout) {
    __shared__ float wa[64][65], wb[64][65], wc[64][65];   // wq,wk,wv; wa reused for w3
    __shared__ float ss[64][65], kk[64][65], vv[64][65];
    __shared__ float qq[8][65], sc[8][65];                 // slice-local (8 m-rows)
    const int h = blockIdx.x >> 3, ms = blockIdx.x & 7, tid = threadIdx.x;

    for (int i = tid; i < 4096; i += 256) {
        int r = i >> 6, c = i & 63;
        wa[r][c] = wq[i];
        wb[r][c] = wk[i];
        wc[r][c] = wv[i];
        ss[r][c] = spre[h*4096 + i] / (dstd[h*64 + r] + 1e-5f) + b1[c];
    }
    __syncthreads();

    // k, v full (64 rows)
    #pragma unroll
    for (int it = 0; it < 16; ++it) {
        int m = it*4 + (tid >> 6), e = tid & 63;
        float ak = 0.f, av = 0.f;
        #pragma unroll 8
        for (int d = 0; d < 64; ++d) {
            float sv = ss[m][d];
            ak += sv * wb[e][d];
            av += sv * wc[e][d];
        }
        kk[m][e] = ak; vv[m][e] = av;
    }
    // q: slice only (8 rows)
    #pragma unroll
    for (int it = 0; it < 2; ++it) {
        int ml = it*4 + (tid >> 6), e = tid & 63;
        float aq = 0.f;
        #pragma unroll 8
        for (int d = 0; d < 64; ++d) aq += ss[ms*8 + ml][d] * wa[e][d];
        qq[ml][e] = aq;
    }
    __syncthreads();

    // scores (slice); stage w3 into wa (wq dead after qq)
    for (int i = tid; i < 4096; i += 256) wa[i >> 6][i & 63] = w3[i];
    #pragma unroll
    for (int it = 0; it < 2; ++it) {
        int ml = it*4 + (tid >> 6), l = tid & 63;
        float a = 0.f;
        #pragma unroll 8
        for (int e = 0; e < 64; ++e) a += qq[ml][e] * kk[l][e];
        sc[ml][l] = a * 0.125f;
    }
    __syncthreads();

    if (tid < 8) {
        int ml = tid;
        float mx = -1e30f;
        #pragma unroll 8
        for (int l = 0; l < 64; ++l) mx = fmaxf(mx, sc[ml][l]);
        float sm = 0.f;
        #pragma unroll 8
        for (int l = 0; l < 64; ++l) { float ev = __expf(sc[ml][l] - mx); sc[ml][l] = ev; sm += ev; }
        float rs = 1.0f / sm;
        #pragma unroll 8
        for (int l = 0; l < 64; ++l) sc[ml][l] *= rs;
    }
    __syncthreads();

    // s_att (slice) -> qq
    #pragma unroll
    for (int it = 0; it < 2; ++it) {
        int ml = it*4 + (tid >> 6), e = tid & 63;
        float a = 0.f;
        #pragma unroll 8
        for (int l = 0; l < 64; ++l) a += sc[ml][l] * vv[l][e];
        qq[ml][e] = a;
    }
    __syncthreads();

    // s_out^T slice: all 64 d, 8 m
    #pragma unroll
    for (int it = 0; it < 2; ++it) {
        int d = it*32 + (tid >> 3), ml = tid & 7;
        float a = b3[d];
        #pragma unroll 8
        for (int e = 0; e < 64; ++e) a += qq[ml][e] * wa[d][e];
        sout[(h*64 + d)*64 + ms*8 + ml] = (f16)a;
    }
}

// ---------------- K4: deslice x_out = w @ s_out (frag-linear contiguous stage + coalesced stores) ----------------
__launch_bounds__(256, 4)
__global__ void k4_deslice(const f16* __restrict__ wTf, const f16* __restrict__ sout,
                           float* __restrict__ out) {
    __shared__ __align__(16) char lmem[36864];   // ldsW 32768 B / ldsO 33024 B, aliased
    f16*   ldsW = (f16*)lmem;                    // [16384] frag-linear w block (ks = this tile)
    float* ldsO = (float*)lmem;                  // [16][516] f32 store stage

    const int tid = threadIdx.x, wave = tid >> 6, lane = tid & 63;
    const int quad = lane >> 4, col = lane & 15;

    // bijective XCD swizzle (nwg = 3126 = 8*390 + 6)
    const int bid = blockIdx.x;
    const int xcd = bid & 7, idx = bid >> 3;
    const int q = KSTEPS >> 3, r = KSTEPS & 7;   // 390, 6
    const int swz = (xcd < r ? xcd*(q+1) : r*(q+1) + (xcd - r)*q) + idx;
    const int n0 = swz * 32;

    // stage: ONE contiguous 32 KB block (frag-linear tile for ks = swz)
    const f16* srcW = wTf + (size_t)swz * 16384;
    #pragma unroll
    for (int i = 0; i < 8; ++i) {
        int id = tid + i*256;
        *(f16x8*)(ldsW + (size_t)id*8) = *(const f16x8*)(srcW + (size_t)id*8);
    }
    __syncthreads();

    f32x4 acc[2][2][4];
    #pragma unroll
    for (int hh = 0; hh < 2; ++hh)
        #pragma unroll
        for (int t = 0; t < 2; ++t)
            #pragma unroll
            for (int v = 0; v < 4; ++v) acc[hh][t][v] = f32x4{0.f,0.f,0.f,0.f};

    #pragma unroll
    for (int hh = 0; hh < 2; ++hh) {
        int h = wave*2 + hh;
        #pragma unroll
        for (int ks = 0; ks < 2; ++ks) {
            f16x8 af[2], bf[4];
            // af[t][j] = w[e=h*64+ks*32+quad*8+j][n=n0+t*16+col], from frag-linear image:
            // idx = (h*4+ks*2+(quad>>1))*512 + (t*2+(col>>3))*128 + (quad&1)*64 + j*8 + (col&7)
            #pragma unroll
            for (int t = 0; t < 2; ++t) {
                const int fb = (h*4 + ks*2 + (quad >> 1))*512
                             + (t*2 + (col >> 3))*128 + (quad & 1)*64 + (col & 7);
                f16x8 a;
                #pragma unroll
                for (int j = 0; j < 8; ++j)
                    a[j] = ldsW[fb + j*8];
                af[t] = a;
            }
            #pragma unroll
            for (int v = 0; v < 4; ++v)
                bf[v] = *(const f16x8*)(sout + (size_t)(h*64 + v*16 + col)*64 + ks*32 + quad*8);
            #pragma unroll
            for (int t = 0; t < 2; ++t)
                #pragma unroll
                for (int v = 0; v < 4; ++v)
                    acc[hh][t][v] = __builtin_amdgcn_mfma_f32_16x16x32_f16(af[t], bf[v], acc[hh][t][v], 0, 0, 0);
        }
    }

    // ---- epilogue: LDS transpose -> fully coalesced 2 KB-row stores (2 passes of 16 n) ----
    #pragma unroll
    for (int p = 0; p < 2; ++p) {
        __syncthreads();                         // p0: ldsW reads done; p1: p0 stores done
        #pragma unroll
        for (int hh = 0; hh < 2; ++hh) {
            int h = wave*2 + hh;
            #pragma unroll
            for (int v = 0; v < 4; ++v)
                #pragma unroll
                for (int r2 = 0; r2 < 4; ++r2)
                    ldsO[(size_t)(quad*4 + r2)*516 + h*64 + v*16 + col] = acc[hh][p][v][r2];
        }
        __syncthreads();
        #pragma unroll
        for (int it = 0; it < 8; ++it) {
            int id = tid + it*256;               // 2048 chunks of 16 B (16 rows x 128)
            int row = id >> 7, ch = id & 127;
            int n = n0 + p*16 + row;
            if (n < N_TOK) {
                float4 v4 = *(const float4*)(ldsO + (size_t)row*516 + ch*4);
                *(float4*)(out + (size_t)n*512 + ch*4) = v4;
            }
        }
    }
}

// ---------------- launcher ----------------
extern "C" void kernel_launch(void* const* d_in, const int* in_sizes, int n_in,
                              void* d_out, int out_size, void* d_ws, size_t ws_size,
                              hipStream_t stream) {
    const float* x           = (const float*)d_in[0];
    const float* temperature = (const float*)d_in[1];
    const float* w_slice     = (const float*)d_in[2];
    const float* b_slice     = (const float*)d_in[3];
    const float* w1          = (const float*)d_in[4];
    const float* b1          = (const float*)d_in[5];
    const float* wq          = (const float*)d_in[6];
    const float* wk          = (const float*)d_in[7];
    const float* wv          = (const float*)d_in[8];
    const float* w3          = (const float*)d_in[9];
    const float* b3          = (const float*)d_in[10];
    float* out = (float*)d_out;
    char*  ws  = (char*)d_ws;

    f16*   wTf   = (f16*)(ws + O_WT);
    f16*   yTf   = (f16*)(ws + O_YT);
    f16*   wfr   = (f16*)(ws + O_WFR);
    float* spp   = (float*)(ws + O_SPP);
    float* dpp   = (float*)(ws + O_DPP);
    float* spre  = (float*)(ws + O_SPRE);
    float* dstd  = (float*)(ws + O_DSTD);
    f16*   sout  = (f16*)(ws + O_SOUT);

    k0_pack<<<144, 256, 0, stream>>>(w_slice, w1, wfr);
    k1_slice<<<NT1*2, 256, 0, stream>>>(x, temperature, wfr, b_slice, wTf, yTf);
    k2_spre<<<K2SPL*4, 256, 0, stream>>>(wTf, yTf, spp, dpp);
    k2r_reduce<<<128, 256, 0, stream>>>(spp, dpp, spre, dstd);
    k3_attn<<<64, 256, 0, stream>>>(spre, dstd, b1, wq, wk, wv, w3, b3, sout);
    k4_deslice<<<KSTEPS, 256, 0, stream>>>(wTf, sout, out);
}

// Round 12
// 531.042 us; speedup vs baseline: 1.1096x; 1.0244x over previous
//
#include <hip/hip_runtime.h>

typedef _Float16 f16;
typedef _Float16 f16x8 __attribute__((ext_vector_type(8)));
typedef _Float16 f16x4 __attribute__((ext_vector_type(4)));
typedef float    f32x4 __attribute__((ext_vector_type(4)));

#define N_TOK   100000
#define NPAD    100032         // 3126 * 32 = 1563 * 64
#define NT1     1563           // 64-row n-tiles
#define CDIM    512
#define KSTEPS  (NPAD/32)      // 3126
#define K2SPL   256            // split-K slots (was 128: 2x occupancy, half-length chains)

// ---------------- workspace layout (bytes) ----------------
// wTf: frag-linear w fp16 [KSTEPS][32 e-frags][64 lanes][8]  (102.4 MB)
// yTf: frag-linear y fp16 [KSTEPS][4 d-frags][64 lanes][8]   (12.8 MB)
#define O_WT     ((size_t)0)
#define SZ_WT    ((size_t)512*NPAD*2)
#define O_YT     (O_WT + SZ_WT)
#define SZ_YT    ((size_t)64*NPAD*2)
#define O_WFR    (O_YT + SZ_YT)                    // frag-linear W+w1 fp16
#define SZ_WFR   ((size_t)16*4*9*64*8*2)
#define O_SPP    (O_WFR + SZ_WFR)                  // s_pre partials [K2SPL][32768] f32
#define SZ_SPP   ((size_t)K2SPL*32768*4)
#define O_DPP    (O_SPP + SZ_SPP)                  // d partials [K2SPL][512] f32
#define SZ_DPP   ((size_t)K2SPL*512*4)
#define O_SPRE   (O_DPP + SZ_DPP)                  // s_pre [512][64] f32
#define SZ_SPRE  ((size_t)32768*4)
#define O_DSTD   (O_SPRE + SZ_SPRE)                // d [512] f32
#define SZ_DSTD  ((size_t)512*4)
#define O_SOUT   (O_DSTD + SZ_DSTD)                // s_out^T fp16 [8][64dh][64m]
#define SZ_SOUT  ((size_t)8*64*64*2)

// ---------------- K0: pack W = [w_slice; w1] (576x512) into MFMA-fragment-linear fp16 ----------------
__global__ void k0_pack(const float* __restrict__ wsf, const float* __restrict__ w1f,
                        f16* __restrict__ wfr) {
    int c = blockIdx.x * 256 + threadIdx.x;      // 36864 chunks total
    int lane = c & 63, g = c >> 6;               // g in 0..575
    int u  = g % 9,  r = g / 9;                  // r in 0..63
    int we = r & 3,  kg = r >> 2;
    int col = lane & 15, quad = lane >> 4;
    int k = kg * 32 + quad * 8;
    const float* src;
    if (u < 8) src = wsf + (size_t)(we*128 + u*16 + col) * CDIM + k;
    else       src = w1f + (size_t)(we*16  + col) * CDIM + k;
    float4 a = *(const float4*)(src);
    float4 b = *(const float4*)(src + 4);
    f16x8 h;
    h[0]=(f16)a.x; h[1]=(f16)a.y; h[2]=(f16)a.z; h[3]=(f16)a.w;
    h[4]=(f16)b.x; h[5]=(f16)b.y; h[6]=(f16)b.z; h[7]=(f16)b.w;
    *(f16x8*)(wfr + (size_t)c * 8) = h;
}

// ---------------- K1: slice GEMM + softmax + y GEMM (double-buffered early bf prefetch) ----------------
// grid = 2*NT1: bid = nt*2 + hgrp; block = 4 waves, wave owns head hgrp*4+wave.
// Explicit unroll-2 body: next step's bf/bfy loads issue BEFORE this step's MFMA
// cluster (~320 cyc of MFMA issue covers their L3 latency), so the barrier's
// vmcnt(0) drain finds them complete. bf0/bf1 double-buffered (+20 VGPR).
#define XROW 40
#define TPITCH 72
__launch_bounds__(256, 3)
__global__ void k1_slice(const float* __restrict__ x, const float* __restrict__ temperature,
                         const f16* __restrict__ wfr, const float* __restrict__ bsl,
                         f16* __restrict__ wTf, f16* __restrict__ yTf) {
    __shared__ f16 smem[320 * TPITCH];           // 46080 B: lT [256][72] + lY [64][72]; lX aliases lT
    f16* lX = smem;                               // [2][64*XROW] = 10240 B
    f16* lT = smem;                               // [256][72]
    f16* lY = smem + 256 * TPITCH;                // [64][72]

    const int tid  = threadIdx.x;
    const int wave = tid >> 6;
    const int lane = tid & 63;
    const int quad = lane >> 4;
    const int col  = lane & 15;
    const int hgrp = blockIdx.x & 1;
    const int nt   = blockIdx.x >> 1;
    const int n0   = nt * 64;
    const int h    = hgrp * 4 + wave;            // head owned by this wave

    const int srow = tid >> 2, sch = tid & 3;
    int snr = n0 + srow; if (snr > N_TOK - 1) snr = N_TOK - 1;
    const float* sbase = x + (size_t)snr * CDIM + sch * 8;

    // per-wave wfr bases (advance by constant per kg)
    const f16* wbase  = wfr + ((size_t)(h >> 1) * 9 + (size_t)(h & 1) * 4) * 512 + (size_t)lane * 8;
    const f16* wybase = wfr + ((size_t)wave * 9 + 8) * 512 + (size_t)lane * 8;
    const size_t KGSTR = (size_t)4 * 9 * 512;    // wfr elements per kg

    {
        float4 a = *(const float4*)(sbase);
        float4 bb = *(const float4*)(sbase + 4);
        f16x8 hh;
        hh[0]=(f16)a.x; hh[1]=(f16)a.y; hh[2]=(f16)a.z; hh[3]=(f16)a.w;
        hh[4]=(f16)bb.x; hh[5]=(f16)bb.y; hh[6]=(f16)bb.z; hh[7]=(f16)bb.w;
        *(f16x8*)(&lX[srow * XROW + sch * 8]) = hh;
    }

    f32x4 acc[4][5];
    #pragma unroll
    for (int nf = 0; nf < 4; ++nf)
        #pragma unroll
        for (int u = 0; u < 5; ++u) acc[nf][u] = f32x4{0.f,0.f,0.f,0.f};

    // prologue: bf0/bfy0 for kg=0 (latency overlaps x-stage barrier)
    f16x8 bf0[4], bf1[4], bfy0, bfy1;
    #pragma unroll
    for (int j = 0; j < 4; ++j) bf0[j] = *(const f16x8*)(wbase + j * 512);
    if (hgrp == 0) bfy0 = *(const f16x8*)(wybase);

    __syncthreads();

    #pragma unroll 1
    for (int kgp = 0; kgp < 8; ++kgp) {
        // ======== even step: kg = 2*kgp (reads buf0, consumes bf0, prefetches bf1) ========
        {
            const int kg = kgp * 2;
            f16x8 af[4];
            #pragma unroll
            for (int nf = 0; nf < 4; ++nf)
                af[nf] = *(const f16x8*)(lX + (nf*16 + col) * XROW + quad * 8);

            // EARLY prefetch for kg+1 (always exists: kg+1 <= 15)
            {
                const f16* wb = wbase + (size_t)(kg + 1) * KGSTR;
                #pragma unroll
                for (int j = 0; j < 4; ++j) bf1[j] = *(const f16x8*)(wb + j * 512);
                if (hgrp == 0) bfy1 = *(const f16x8*)(wybase + (size_t)(kg + 1) * KGSTR);
            }
            float4 xa = *(const float4*)(sbase + (kg + 1) * 32);
            float4 xb = *(const float4*)(sbase + (kg + 1) * 32 + 4);

            #pragma unroll
            for (int nf = 0; nf < 4; ++nf)
                #pragma unroll
                for (int j = 0; j < 4; ++j)
                    acc[nf][j] = __builtin_amdgcn_mfma_f32_16x16x32_f16(af[nf], bf0[j], acc[nf][j], 0, 0, 0);
            if (hgrp == 0) {
                #pragma unroll
                for (int nf = 0; nf < 4; ++nf)
                    acc[nf][4] = __builtin_amdgcn_mfma_f32_16x16x32_f16(af[nf], bfy0, acc[nf][4], 0, 0, 0);
            }

            f16x8 hh;
            hh[0]=(f16)xa.x; hh[1]=(f16)xa.y; hh[2]=(f16)xa.z; hh[3]=(f16)xa.w;
            hh[4]=(f16)xb.x; hh[5]=(f16)xb.y; hh[6]=(f16)xb.z; hh[7]=(f16)xb.w;
            *(f16x8*)(&lX[64*XROW + srow * XROW + sch * 8]) = hh;
            __syncthreads();
        }
        // ======== odd step: kg = 2*kgp+1 (reads buf1, consumes bf1, prefetches bf0) ========
        {
            const int kg = kgp * 2 + 1;
            f16x8 af[4];
            #pragma unroll
            for (int nf = 0; nf < 4; ++nf)
                af[nf] = *(const f16x8*)(lX + 64*XROW + (nf*16 + col) * XROW + quad * 8);

            float4 xa, xb;
            if (kgp < 7) {
                const f16* wb = wbase + (size_t)(kg + 1) * KGSTR;
                #pragma unroll
                for (int j = 0; j < 4; ++j) bf0[j] = *(const f16x8*)(wb + j * 512);
                if (hgrp == 0) bfy0 = *(const f16x8*)(wybase + (size_t)(kg + 1) * KGSTR);
                xa = *(const float4*)(sbase + (kg + 1) * 32);
                xb = *(const float4*)(sbase + (kg + 1) * 32 + 4);
            }

            #pragma unroll
            for (int nf = 0; nf < 4; ++nf)
                #pragma unroll
                for (int j = 0; j < 4; ++j)
                    acc[nf][j] = __builtin_amdgcn_mfma_f32_16x16x32_f16(af[nf], bf1[j], acc[nf][j], 0, 0, 0);
            if (hgrp == 0) {
                #pragma unroll
                for (int nf = 0; nf < 4; ++nf)
                    acc[nf][4] = __builtin_amdgcn_mfma_f32_16x16x32_f16(af[nf], bfy1, acc[nf][4], 0, 0, 0);
            }

            if (kgp < 7) {
                f16x8 hh;
                hh[0]=(f16)xa.x; hh[1]=(f16)xa.y; hh[2]=(f16)xa.z; hh[3]=(f16)xa.w;
                hh[4]=(f16)xb.x; hh[5]=(f16)xb.y; hh[6]=(f16)xb.z; hh[7]=(f16)xb.w;
                *(f16x8*)(&lX[srow * XROW + sch * 8]) = hh;
            }
            __syncthreads();
        }
    }

    // ---- bias + temperature (one head per wave) ----
    #pragma unroll
    for (int j = 0; j < 4; ++j) {
        float bb = bsl[h*64 + j*16 + col];
        #pragma unroll
        for (int nf = 0; nf < 4; ++nf)
            #pragma unroll
            for (int r = 0; r < 4; ++r) acc[nf][j][r] += bb;
    }
    float tv = temperature[h];
    tv = fminf(fmaxf(tv, 0.1f), 5.0f);
    const float invt = 1.0f / tv;

    // ---- softmax over M=64 (4 frags x 16 cols); w -> lT, y -> lY ----
    #pragma unroll
    for (int nf = 0; nf < 4; ++nf) {
        const int nloc = nf*16 + quad*4;
        float mx[4];
        #pragma unroll
        for (int r = 0; r < 4; ++r) {
            float m01 = fmaxf(acc[nf][0][r], acc[nf][1][r]);
            float m23 = fmaxf(acc[nf][2][r], acc[nf][3][r]);
            mx[r] = fmaxf(m01, m23);
        }
        #pragma unroll
        for (int d = 1; d < 16; d <<= 1)
            #pragma unroll
            for (int r = 0; r < 4; ++r) mx[r] = fmaxf(mx[r], __shfl_xor(mx[r], d));
        float sm[4] = {0.f, 0.f, 0.f, 0.f};
        #pragma unroll
        for (int j = 0; j < 4; ++j)
            #pragma unroll
            for (int r = 0; r < 4; ++r) {
                float ev = __expf((acc[nf][j][r] - mx[r]) * invt);
                acc[nf][j][r] = ev;
                sm[r] += ev;
            }
        #pragma unroll
        for (int d = 1; d < 16; d <<= 1)
            #pragma unroll
            for (int r = 0; r < 4; ++r) sm[r] += __shfl_xor(sm[r], d);
        #pragma unroll
        for (int r = 0; r < 4; ++r) sm[r] = 1.0f / sm[r];
        #pragma unroll
        for (int j = 0; j < 4; ++j) {
            f16x4 pk;
            #pragma unroll
            for (int r = 0; r < 4; ++r) {
                int n = n0 + nloc + r;
                float wv = (n < N_TOK) ? acc[nf][j][r] * sm[r] : 0.0f;
                pk[r] = (f16)wv;
            }
            int e_loc = wave*64 + j*16 + col;        // local e within block's 256
            *(f16x4*)(lT + (size_t)e_loc*TPITCH + nloc) = pk;
        }
        if (hgrp == 0) {
            f16x4 pk;
            #pragma unroll
            for (int r = 0; r < 4; ++r) {
                int n = n0 + nloc + r;
                pk[r] = (n < N_TOK) ? (f16)acc[nf][4][r] : (f16)0.f;
            }
            *(f16x4*)(lY + (size_t)(wave*16 + col)*TPITCH + nloc) = pk;
        }
    }
    __syncthreads();

    // ---- frag-linear wTf emit: [ks][f][lane][8], fully coalesced 4KB bursts ----
    #pragma unroll
    for (int i = 0; i < 8; ++i) {
        int gid = tid + i*256;
        int laneL = gid & 63, chunk = gid >> 6;      // chunk 0..31
        int ks_loc = chunk >> 4, floc = chunk & 15;
        f16x8 v = *(const f16x8*)(lT + (size_t)(floc*16 + (laneL & 15))*TPITCH
                                     + ks_loc*32 + (laneL >> 4)*8);
        *(f16x8*)(wTf + ((size_t)((nt*2 + ks_loc)*32 + hgrp*16 + floc))*512
                       + (size_t)laneL*8) = v;
    }
    // ---- frag-linear yTf emit (hgrp==0): [ks][v][lane][8] ----
    if (hgrp == 0) {
        #pragma unroll
        for (int i = 0; i < 2; ++i) {
            int gid = tid + i*256;
            int laneL = gid & 63, chunk = gid >> 6;  // chunk 0..7
            int ks_loc = chunk >> 2, v4 = chunk & 3;
            f16x8 vv = *(const f16x8*)(lY + (size_t)(v4*16 + (laneL & 15))*TPITCH
                                          + ks_loc*32 + (laneL >> 4)*8);
            *(f16x8*)(yTf + ((size_t)((nt*2 + ks_loc)*4 + v4))*512
                           + (size_t)laneL*8) = vv;
        }
    }
}

// ---------------- K2: s_pre = sum_n w[n,e]*y[n,d]  (frag-linear coalesced loads) ----------------
#define K2_LOAD(AF, BF, kss)                                                         \
    {   _Pragma("unroll")                                                            \
        for (int v = 0; v < 4; ++v)                                                  \
            BF[v] = *(const f16x8*)(yTf + ((size_t)((kss)*4 + v))*512 + (size_t)lane*8); \
        _Pragma("unroll")                                                            \
        for (int u = 0; u < 2; ++u)                                                  \
            AF[u] = *(const f16x8*)(wTf + ((size_t)((kss)*32 + fbase + u))*512 + (size_t)lane*8); \
    }
#define K2_MFMA(AF, BF)                                                              \
    {   _Pragma("unroll")                                                            \
        for (int u = 0; u < 2; ++u) {                                                \
            _Pragma("unroll")                                                        \
            for (int v = 0; v < 4; ++v)                                              \
                acc[u][v] = __builtin_amdgcn_mfma_f32_16x16x32_f16(AF[u], BF[v], acc[u][v], 0, 0, 0); \
            float s_ = 0.f;                                                          \
            _Pragma("unroll")                                                        \
            for (int j = 0; j < 8; ++j) s_ += (float)AF[u][j];                       \
            dac[u] += s_;                                                            \
        }                                                                            \
    }
__launch_bounds__(256, 4)
__global__ void k2_spre(const f16* __restrict__ wTf, const f16* __restrict__ yTf,
                        float* __restrict__ spp, float* __restrict__ dpp) {
    const int tid = threadIdx.x, wave = tid >> 6, lane = tid & 63;
    const int quad = lane >> 4, col = lane & 15;
    const int slot = blockIdx.x >> 2, equad = blockIdx.x & 3;
    const int ebase = equad * 128 + wave * 32;
    const int fbase = equad * 8 + wave * 2;      // e-frag base = ebase/16

    const int ks0 = (int)(((long long)slot * KSTEPS) / K2SPL);
    const int ks1 = (int)(((long long)(slot + 1) * KSTEPS) / K2SPL);

    f32x4 acc[2][4];
    float dac[2];
    #pragma unroll
    for (int u = 0; u < 2; ++u) {
        dac[u] = 0.f;
        #pragma unroll
        for (int v = 0; v < 4; ++v) acc[u][v] = f32x4{0.f,0.f,0.f,0.f};
    }

    f16x8 afA[2], bfA[4], afB[2], bfB[4];
    K2_LOAD(afA, bfA, ks0)
    int ks = ks0;
    for (; ks + 2 <= ks1; ks += 2) {
        K2_LOAD(afB, bfB, ks + 1)
        K2_MFMA(afA, bfA)
        K2_LOAD(afA, bfA, ks + 2)   // one-step overread stays inside workspace; unused
        K2_MFMA(afB, bfB)
    }
    if (ks < ks1) K2_MFMA(afA, bfA)

    #pragma unroll
    for (int u = 0; u < 2; ++u) {
        dac[u] += __shfl_xor(dac[u], 16);
        dac[u] += __shfl_xor(dac[u], 32);
    }
    if (quad == 0) {
        #pragma unroll
        for (int u = 0; u < 2; ++u)
            dpp[slot*512 + ebase + u*16 + col] = dac[u];
    }
    float* dst = spp + (size_t)slot * 32768 + (size_t)equad * 8192;
    #pragma unroll
    for (int u = 0; u < 2; ++u)
        #pragma unroll
        for (int v = 0; v < 4; ++v)
            *(f32x4*)(dst + (size_t)((wave*2 + u)*4 + v)*256 + (size_t)lane*4) = acc[u][v];
}

// ---------------- K2r: reduce partials, de-swizzle frag order ----------------
__global__ void k2r_reduce(const float* __restrict__ spp, const float* __restrict__ dpp,
                           float* __restrict__ spre, float* __restrict__ dstd) {
    int i = blockIdx.x*256 + threadIdx.x;   // 32768
    float s = 0.f;
    for (int p = 0; p < K2SPL; ++p) s += spp[(size_t)p*32768 + i];
    int r = i & 3, L = (i >> 2) & 63, v = (i >> 8) & 3, g = (i >> 10) & 7, eq = (i >> 13) & 3;
    int e = eq*128 + (g >> 1)*32 + (g & 1)*16 + (L >> 4)*4 + r;
    int d = v*16 + (L & 15);
    spre[e*64 + d] = s;
    if (i < 512) {
        float tt = 0.f;
        for (int p = 0; p < K2SPL; ++p) tt += dpp[p*512 + i];
        dstd[i] = tt;
    }
}

// ---------------- K3: per-head middle block, m-split 8 ways (grid 64) ----------------
__global__ void k3_attn(const float* __restrict__ spre, const float* __restrict__ dstd,
                        const float* __restrict__ b1, const float* __restrict__ wq,
                        const float* __restrict__ wk, const float* __restrict__ wv,
                        const float* __restrict__ w3, const float* __restrict__ b3,
                        f16* __restrict__ sout) {
    __shared__ float wa[64][65], wb[64][65], wc[64][65];   // wq,wk,wv; wa reused for w3
    __shared__ float ss[64][65], kk[64][65], vv[64][65];
    __shared__ float qq[8][65], sc[8][65];                 // slice-local (8 m-rows)
    const int h = blockIdx.x >> 3, ms = blockIdx.x & 7, tid = threadIdx.x;

    for (int i = tid; i < 4096; i += 256) {
        int r = i >> 6, c = i & 63;
        wa[r][c] = wq[i];
        wb[r][c] = wk[i];
        wc[r][c] = wv[i];
        ss[r][c] = spre[h*4096 + i] / (dstd[h*64 + r] + 1e-5f) + b1[c];
    }
    __syncthreads();

    // k, v full (64 rows)
    #pragma unroll
    for (int it = 0; it < 16; ++it) {
        int m = it*4 + (tid >> 6), e = tid & 63;
        float ak = 0.f, av = 0.f;
        #pragma unroll 8
        for (int d = 0; d < 64; ++d) {
            float sv = ss[m][d];
            ak += sv * wb[e][d];
            av += sv * wc[e][d];
        }
        kk[m][e] = ak; vv[m][e] = av;
    }
    // q: slice only (8 rows)
    #pragma unroll
    for (int it = 0; it < 2; ++it) {
        int ml = it*4 + (tid >> 6), e = tid & 63;
        float aq = 0.f;
        #pragma unroll 8
        for (int d = 0; d < 64; ++d) aq += ss[ms*8 + ml][d] * wa[e][d];
        qq[ml][e] = aq;
    }
    __syncthreads();

    // scores (slice); stage w3 into wa (wq dead after qq)
    for (int i = tid; i < 4096; i += 256) wa[i >> 6][i & 63] = w3[i];
    #pragma unroll
    for (int it = 0; it < 2; ++it) {
        int ml = it*4 + (tid >> 6), l = tid & 63;
        float a = 0.f;
        #pragma unroll 8
        for (int e = 0; e < 64; ++e) a += qq[ml][e] * kk[l][e];
        sc[ml][l] = a * 0.125f;
    }
    __syncthreads();

    if (tid < 8) {
        int ml = tid;
        float mx = -1e30f;
        #pragma unroll 8
        for (int l = 0; l < 64; ++l) mx = fmaxf(mx, sc[ml][l]);
        float sm = 0.f;
        #pragma unroll 8
        for (int l = 0; l < 64; ++l) { float ev = __expf(sc[ml][l] - mx); sc[ml][l] = ev; sm += ev; }
        float rs = 1.0f / sm;
        #pragma unroll 8
        for (int l = 0; l < 64; ++l) sc[ml][l] *= rs;
    }
    __syncthreads();

    // s_att (slice) -> qq
    #pragma unroll
    for (int it = 0; it < 2; ++it) {
        int ml = it*4 + (tid >> 6), e = tid & 63;
        float a = 0.f;
        #pragma unroll 8
        for (int l = 0; l < 64; ++l) a += sc[ml][l] * vv[l][e];
        qq[ml][e] = a;
    }
    __syncthreads();

    // s_out^T slice: all 64 d, 8 m
    #pragma unroll
    for (int it = 0; it < 2; ++it) {
        int d = it*32 + (tid >> 3), ml = tid & 7;
        float a = b3[d];
        #pragma unroll 8
        for (int e = 0; e < 64; ++e) a += qq[ml][e] * wa[d][e];
        sout[(h*64 + d)*64 + ms*8 + ml] = (f16)a;
    }
}

// ---------------- K4: deslice x_out = w @ s_out (frag-linear stage, nontemporal stores) ----------------
__launch_bounds__(256, 4)
__global__ void k4_deslice(const f16* __restrict__ wTf, const f16* __restrict__ sout,
                           float* __restrict__ out) {
    __shared__ __align__(16) char lmem[36864];   // ldsW 32768 B / ldsO 33024 B, aliased
    f16*   ldsW = (f16*)lmem;                    // [16384] frag-linear w block (ks = this tile)
    float* ldsO = (float*)lmem;                  // [16][516] f32 store stage

    const int tid = threadIdx.x, wave = tid >> 6, lane = tid & 63;
    const int quad = lane >> 4, col = lane & 15;

    // bijective XCD swizzle (nwg = 3126 = 8*390 + 6)
    const int bid = blockIdx.x;
    const int xcd = bid & 7, idx = bid >> 3;
    const int q = KSTEPS >> 3, r = KSTEPS & 7;   // 390, 6
    const int swz = (xcd < r ? xcd*(q+1) : r*(q+1) + (xcd - r)*q) + idx;
    const int n0 = swz * 32;

    // stage: ONE contiguous 32 KB block (frag-linear tile for ks = swz)
    const f16* srcW = wTf + (size_t)swz * 16384;
    #pragma unroll
    for (int i = 0; i < 8; ++i) {
        int id = tid + i*256;
        *(f16x8*)(ldsW + (size_t)id*8) = *(const f16x8*)(srcW + (size_t)id*8);
    }
    __syncthreads();

    f32x4 acc[2][2][4];
    #pragma unroll
    for (int hh = 0; hh < 2; ++hh)
        #pragma unroll
        for (int t = 0; t < 2; ++t)
            #pragma unroll
            for (int v = 0; v < 4; ++v) acc[hh][t][v] = f32x4{0.f,0.f,0.f,0.f};

    #pragma unroll
    for (int hh = 0; hh < 2; ++hh) {
        int h = wave*2 + hh;
        #pragma unroll
        for (int ks = 0; ks < 2; ++ks) {
            f16x8 af[2], bf[4];
            // af[t][j] = w[e=h*64+ks*32+quad*8+j][n=n0+t*16+col], from frag-linear image
            #pragma unroll
            for (int t = 0; t < 2; ++t) {
                const int fb = (h*4 + ks*2 + (quad >> 1))*512
                             + (t*2 + (col >> 3))*128 + (quad & 1)*64 + (col & 7);
                f16x8 a;
                #pragma unroll
                for (int j = 0; j < 8; ++j)
                    a[j] = ldsW[fb + j*8];
                af[t] = a;
            }
            #pragma unroll
            for (int v = 0; v < 4; ++v)
                bf[v] = *(const f16x8*)(sout + (size_t)(h*64 + v*16 + col)*64 + ks*32 + quad*8);
            #pragma unroll
            for (int t = 0; t < 2; ++t)
                #pragma unroll
                for (int v = 0; v < 4; ++v)
                    acc[hh][t][v] = __builtin_amdgcn_mfma_f32_16x16x32_f16(af[t], bf[v], acc[hh][t][v], 0, 0, 0);
        }
    }

    // ---- epilogue: LDS transpose -> coalesced 2 KB-row NONTEMPORAL stores (2 passes of 16 n) ----
    #pragma unroll
    for (int p = 0; p < 2; ++p) {
        __syncthreads();                         // p0: ldsW reads done; p1: p0 stores done
        #pragma unroll
        for (int hh = 0; hh < 2; ++hh) {
            int h = wave*2 + hh;
            #pragma unroll
            for (int v = 0; v < 4; ++v)
                #pragma unroll
                for (int r2 = 0; r2 < 4; ++r2)
                    ldsO[(size_t)(quad*4 + r2)*516 + h*64 + v*16 + col] = acc[hh][p][v][r2];
        }
        __syncthreads();
        #pragma unroll
        for (int it = 0; it < 8; ++it) {
            int id = tid + it*256;               // 2048 chunks of 16 B (16 rows x 128)
            int row = id >> 7, ch = id & 127;
            int n = n0 + p*16 + row;
            if (n < N_TOK) {
                f32x4 v4 = *(const f32x4*)(ldsO + (size_t)row*516 + ch*4);
                __builtin_nontemporal_store(v4, (f32x4*)(out + (size_t)n*512 + ch*4));
            }
        }
    }
}

// ---------------- launcher ----------------
extern "C" void kernel_launch(void* const* d_in, const int* in_sizes, int n_in,
                              void* d_out, int out_size, void* d_ws, size_t ws_size,
                              hipStream_t stream) {
    const float* x           = (const float*)d_in[0];
    const float* temperature = (const float*)d_in[1];
    const float* w_slice     = (const float*)d_in[2];
    const float* b_slice     = (const float*)d_in[3];
    const float* w1          = (const float*)d_in[4];
    const float* b1          = (const float*)d_in[5];
    const float* wq          = (const float*)d_in[6];
    const float* wk          = (const float*)d_in[7];
    const float* wv          = (const float*)d_in[8];
    const float* w3          = (const float*)d_in[9];
    const float* b3          = (const float*)d_in[10];
    float* out = (float*)d_out;
    char*  ws  = (char*)d_ws;

    f16*   wTf   = (f16*)(ws + O_WT);
    f16*   yTf   = (f16*)(ws + O_YT);
    f16*   wfr   = (f16*)(ws + O_WFR);
    float* spp   = (float*)(ws + O_SPP);
    float* dpp   = (float*)(ws + O_DPP);
    float* spre  = (float*)(ws + O_SPRE);
    float* dstd  = (float*)(ws + O_DSTD);
    f16*   sout  = (f16*)(ws + O_SOUT);

    k0_pack<<<144, 256, 0, stream>>>(w_slice, w1, wfr);
    k1_slice<<<NT1*2, 256, 0, stream>>>(x, temperature, wfr, b_slice, wTf, yTf);
    k2_spre<<<K2SPL*4, 256, 0, stream>>>(wTf, yTf, spp, dpp);
    k2r_reduce<<<128, 256, 0, stream>>>(spp, dpp, spre, dstd);
    k3_attn<<<64, 256, 0, stream>>>(spre, dstd, b1, wq, wk, wv, w3, b3, sout);
    k4_deslice<<<KSTEPS, 256, 0, stream>>>(wTf, sout, out);
}

// Round 13
// 516.840 us; speedup vs baseline: 1.1401x; 1.0275x over previous
//
#include <hip/hip_runtime.h>

typedef _Float16 f16;
typedef _Float16 f16x8 __attribute__((ext_vector_type(8)));
typedef _Float16 f16x4 __attribute__((ext_vector_type(4)));
typedef float    f32x4 __attribute__((ext_vector_type(4)));

#define N_TOK   100000
#define NPAD    100032         // 3126 * 32 = 1563 * 64
#define NT1     1563           // 64-row n-tiles
#define CDIM    512
#define KSTEPS  (NPAD/32)      // 3126
#define K2SPL   256            // split-K slots

// ---------------- workspace layout (bytes) ----------------
// wTf: frag-linear w fp16 [KSTEPS][32 e-frags][64 lanes][8]  (102.4 MB)
// yTf: frag-linear y fp16 [KSTEPS][4 d-frags][64 lanes][8]   (12.8 MB)
#define O_WT     ((size_t)0)
#define SZ_WT    ((size_t)512*NPAD*2)
#define O_YT     (O_WT + SZ_WT)
#define SZ_YT    ((size_t)64*NPAD*2)
#define O_WFR    (O_YT + SZ_YT)                    // frag-linear W+w1 fp16
#define SZ_WFR   ((size_t)16*4*9*64*8*2)
#define O_SPP    (O_WFR + SZ_WFR)                  // s_pre partials [K2SPL][32768] f32
#define SZ_SPP   ((size_t)K2SPL*32768*4)
#define O_DPP    (O_SPP + SZ_SPP)                  // d partials [K2SPL][512] f32
#define SZ_DPP   ((size_t)K2SPL*512*4)
#define O_SPRE   (O_DPP + SZ_DPP)                  // s_pre [512][64] f32
#define SZ_SPRE  ((size_t)32768*4)
#define O_DSTD   (O_SPRE + SZ_SPRE)                // d [512] f32
#define SZ_DSTD  ((size_t)512*4)
#define O_SOUT   (O_DSTD + SZ_DSTD)                // s_out^T fp16 [8][64dh][64m]
#define SZ_SOUT  ((size_t)8*64*64*2)

// ---------------- K0: pack W = [w_slice; w1] (576x512) into MFMA-fragment-linear fp16 ----------------
__global__ void k0_pack(const float* __restrict__ wsf, const float* __restrict__ w1f,
                        f16* __restrict__ wfr) {
    int c = blockIdx.x * 256 + threadIdx.x;      // 36864 chunks total
    int lane = c & 63, g = c >> 6;               // g in 0..575
    int u  = g % 9,  r = g / 9;                  // r in 0..63
    int we = r & 3,  kg = r >> 2;
    int col = lane & 15, quad = lane >> 4;
    int k = kg * 32 + quad * 8;
    const float* src;
    if (u < 8) src = wsf + (size_t)(we*128 + u*16 + col) * CDIM + k;
    else       src = w1f + (size_t)(we*16  + col) * CDIM + k;
    float4 a = *(const float4*)(src);
    float4 b = *(const float4*)(src + 4);
    f16x8 h;
    h[0]=(f16)a.x; h[1]=(f16)a.y; h[2]=(f16)a.z; h[3]=(f16)a.w;
    h[4]=(f16)b.x; h[5]=(f16)b.y; h[6]=(f16)b.z; h[7]=(f16)b.w;
    *(f16x8*)(wfr + (size_t)c * 8) = h;
}

// ---------------- K1: slice GEMM + softmax + y GEMM (r10 proven: rotated bf prefetch) ----------------
// grid = 2*NT1: bid = nt*2 + hgrp; block = 4 waves, wave owns head hgrp*4+wave.
// bf/bfy fragments for step kg+1 are loaded at the TAIL of step kg (pre-barrier):
// their L3 latency overlaps x-write + barrier drain + next step's af reads.
#define XROW 40
#define TPITCH 72
__launch_bounds__(256, 3)
__global__ void k1_slice(const float* __restrict__ x, const float* __restrict__ temperature,
                         const f16* __restrict__ wfr, const float* __restrict__ bsl,
                         f16* __restrict__ wTf, f16* __restrict__ yTf) {
    __shared__ f16 smem[320 * TPITCH];           // 46080 B: lT [256][72] + lY [64][72]; lX aliases lT
    f16* lX = smem;                               // [2][64*XROW] = 10240 B
    f16* lT = smem;                               // [256][72]
    f16* lY = smem + 256 * TPITCH;                // [64][72]

    const int tid  = threadIdx.x;
    const int wave = tid >> 6;
    const int lane = tid & 63;
    const int quad = lane >> 4;
    const int col  = lane & 15;
    const int hgrp = blockIdx.x & 1;
    const int nt   = blockIdx.x >> 1;
    const int n0   = nt * 64;
    const int h    = hgrp * 4 + wave;            // head owned by this wave

    const int srow = tid >> 2, sch = tid & 3;
    int snr = n0 + srow; if (snr > N_TOK - 1) snr = N_TOK - 1;
    const float* sbase = x + (size_t)snr * CDIM + sch * 8;

    // per-wave wfr bases (advance by constant per kg)
    const f16* wbase  = wfr + ((size_t)(h >> 1) * 9 + (size_t)(h & 1) * 4) * 512 + (size_t)lane * 8;
    const f16* wybase = wfr + ((size_t)wave * 9 + 8) * 512 + (size_t)lane * 8;
    const size_t KGSTR = (size_t)4 * 9 * 512;    // wfr elements per kg

    {
        float4 a = *(const float4*)(sbase);
        float4 bb = *(const float4*)(sbase + 4);
        f16x8 hh;
        hh[0]=(f16)a.x; hh[1]=(f16)a.y; hh[2]=(f16)a.z; hh[3]=(f16)a.w;
        hh[4]=(f16)bb.x; hh[5]=(f16)bb.y; hh[6]=(f16)bb.z; hh[7]=(f16)bb.w;
        *(f16x8*)(&lX[srow * XROW + sch * 8]) = hh;
    }

    f32x4 acc[4][5];
    #pragma unroll
    for (int nf = 0; nf < 4; ++nf)
        #pragma unroll
        for (int u = 0; u < 5; ++u) acc[nf][u] = f32x4{0.f,0.f,0.f,0.f};

    // prologue: bf/bfy for kg=0 (latency overlaps x-stage barrier)
    f16x8 bf[4];
    #pragma unroll
    for (int j = 0; j < 4; ++j) bf[j] = *(const f16x8*)(wbase + j * 512);
    f16x8 bfy;
    if (hgrp == 0) bfy = *(const f16x8*)(wybase);

    __syncthreads();

    #pragma unroll 2
    for (int kg = 0; kg < 16; ++kg) {
        float4 xa, xb;
        if (kg < 15) {
            xa = *(const float4*)(sbase + (kg + 1) * 32);
            xb = *(const float4*)(sbase + (kg + 1) * 32 + 4);
        }

        const f16* xbuf = lX + (kg & 1) * (64 * XROW);
        f16x8 af[4];
        #pragma unroll
        for (int nf = 0; nf < 4; ++nf)
            af[nf] = *(const f16x8*)(xbuf + (nf*16 + col) * XROW + quad * 8);

        #pragma unroll
        for (int nf = 0; nf < 4; ++nf)
            #pragma unroll
            for (int j = 0; j < 4; ++j)
                acc[nf][j] = __builtin_amdgcn_mfma_f32_16x16x32_f16(af[nf], bf[j], acc[nf][j], 0, 0, 0);
        if (hgrp == 0) {
            #pragma unroll
            for (int nf = 0; nf < 4; ++nf)
                acc[nf][4] = __builtin_amdgcn_mfma_f32_16x16x32_f16(af[nf], bfy, acc[nf][4], 0, 0, 0);
        }

        // rotated prefetch: bf/bfy for kg+1, issued pre-barrier (same registers)
        if (kg < 15) {
            const f16* wb = wbase + (size_t)(kg + 1) * KGSTR;
            #pragma unroll
            for (int j = 0; j < 4; ++j) bf[j] = *(const f16x8*)(wb + j * 512);
            if (hgrp == 0) bfy = *(const f16x8*)(wybase + (size_t)(kg + 1) * KGSTR);
        }

        if (kg < 15) {
            f16x8 hh;
            hh[0]=(f16)xa.x; hh[1]=(f16)xa.y; hh[2]=(f16)xa.z; hh[3]=(f16)xa.w;
            hh[4]=(f16)xb.x; hh[5]=(f16)xb.y; hh[6]=(f16)xb.z; hh[7]=(f16)xb.w;
            *(f16x8*)(&lX[((kg + 1) & 1) * (64 * XROW) + srow * XROW + sch * 8]) = hh;
        }
        __syncthreads();
    }

    // ---- bias + temperature (one head per wave) ----
    #pragma unroll
    for (int j = 0; j < 4; ++j) {
        float bb = bsl[h*64 + j*16 + col];
        #pragma unroll
        for (int nf = 0; nf < 4; ++nf)
            #pragma unroll
            for (int r = 0; r < 4; ++r) acc[nf][j][r] += bb;
    }
    float tv = temperature[h];
    tv = fminf(fmaxf(tv, 0.1f), 5.0f);
    const float invt = 1.0f / tv;

    // ---- softmax over M=64 (4 frags x 16 cols); w -> lT, y -> lY ----
    #pragma unroll
    for (int nf = 0; nf < 4; ++nf) {
        const int nloc = nf*16 + quad*4;
        float mx[4];
        #pragma unroll
        for (int r = 0; r < 4; ++r) {
            float m01 = fmaxf(acc[nf][0][r], acc[nf][1][r]);
            float m23 = fmaxf(acc[nf][2][r], acc[nf][3][r]);
            mx[r] = fmaxf(m01, m23);
        }
        #pragma unroll
        for (int d = 1; d < 16; d <<= 1)
            #pragma unroll
            for (int r = 0; r < 4; ++r) mx[r] = fmaxf(mx[r], __shfl_xor(mx[r], d));
        float sm[4] = {0.f, 0.f, 0.f, 0.f};
        #pragma unroll
        for (int j = 0; j < 4; ++j)
            #pragma unroll
            for (int r = 0; r < 4; ++r) {
                float ev = __expf((acc[nf][j][r] - mx[r]) * invt);
                acc[nf][j][r] = ev;
                sm[r] += ev;
            }
        #pragma unroll
        for (int d = 1; d < 16; d <<= 1)
            #pragma unroll
            for (int r = 0; r < 4; ++r) sm[r] += __shfl_xor(sm[r], d);
        #pragma unroll
        for (int r = 0; r < 4; ++r) sm[r] = 1.0f / sm[r];
        #pragma unroll
        for (int j = 0; j < 4; ++j) {
            f16x4 pk;
            #pragma unroll
            for (int r = 0; r < 4; ++r) {
                int n = n0 + nloc + r;
                float wv = (n < N_TOK) ? acc[nf][j][r] * sm[r] : 0.0f;
                pk[r] = (f16)wv;
            }
            int e_loc = wave*64 + j*16 + col;        // local e within block's 256
            *(f16x4*)(lT + (size_t)e_loc*TPITCH + nloc) = pk;
        }
        if (hgrp == 0) {
            f16x4 pk;
            #pragma unroll
            for (int r = 0; r < 4; ++r) {
                int n = n0 + nloc + r;
                pk[r] = (n < N_TOK) ? (f16)acc[nf][4][r] : (f16)0.f;
            }
            *(f16x4*)(lY + (size_t)(wave*16 + col)*TPITCH + nloc) = pk;
        }
    }
    __syncthreads();

    // ---- frag-linear wTf emit: [ks][f][lane][8], fully coalesced 4KB bursts ----
    #pragma unroll
    for (int i = 0; i < 8; ++i) {
        int gid = tid + i*256;
        int laneL = gid & 63, chunk = gid >> 6;      // chunk 0..31
        int ks_loc = chunk >> 4, floc = chunk & 15;
        f16x8 v = *(const f16x8*)(lT + (size_t)(floc*16 + (laneL & 15))*TPITCH
                                     + ks_loc*32 + (laneL >> 4)*8);
        *(f16x8*)(wTf + ((size_t)((nt*2 + ks_loc)*32 + hgrp*16 + floc))*512
                       + (size_t)laneL*8) = v;
    }
    // ---- frag-linear yTf emit (hgrp==0): [ks][v][lane][8] ----
    if (hgrp == 0) {
        #pragma unroll
        for (int i = 0; i < 2; ++i) {
            int gid = tid + i*256;
            int laneL = gid & 63, chunk = gid >> 6;  // chunk 0..7
            int ks_loc = chunk >> 2, v4 = chunk & 3;
            f16x8 vv = *(const f16x8*)(lY + (size_t)(v4*16 + (laneL & 15))*TPITCH
                                          + ks_loc*32 + (laneL >> 4)*8);
            *(f16x8*)(yTf + ((size_t)((nt*2 + ks_loc)*4 + v4))*512
                           + (size_t)laneL*8) = vv;
        }
    }
}

// ---------------- K2: s_pre = sum_n w[n,e]*y[n,d]  (frag-linear coalesced loads) ----------------
#define K2_LOAD(AF, BF, kss)                                                         \
    {   _Pragma("unroll")                                                            \
        for (int v = 0; v < 4; ++v)                                                  \
            BF[v] = *(const f16x8*)(yTf + ((size_t)((kss)*4 + v))*512 + (size_t)lane*8); \
        _Pragma("unroll")                                                            \
        for (int u = 0; u < 2; ++u)                                                  \
            AF[u] = *(const f16x8*)(wTf + ((size_t)((kss)*32 + fbase + u))*512 + (size_t)lane*8); \
    }
#define K2_MFMA(AF, BF)                                                              \
    {   _Pragma("unroll")                                                            \
        for (int u = 0; u < 2; ++u) {                                                \
            _Pragma("unroll")                                                        \
            for (int v = 0; v < 4; ++v)                                              \
                acc[u][v] = __builtin_amdgcn_mfma_f32_16x16x32_f16(AF[u], BF[v], acc[u][v], 0, 0, 0); \
            float s_ = 0.f;                                                          \
            _Pragma("unroll")                                                        \
            for (int j = 0; j < 8; ++j) s_ += (float)AF[u][j];                       \
            dac[u] += s_;                                                            \
        }                                                                            \
    }
__launch_bounds__(256, 4)
__global__ void k2_spre(const f16* __restrict__ wTf, const f16* __restrict__ yTf,
                        float* __restrict__ spp, float* __restrict__ dpp) {
    const int tid = threadIdx.x, wave = tid >> 6, lane = tid & 63;
    const int quad = lane >> 4, col = lane & 15;
    const int slot = blockIdx.x >> 2, equad = blockIdx.x & 3;
    const int ebase = equad * 128 + wave * 32;
    const int fbase = equad * 8 + wave * 2;      // e-frag base = ebase/16

    const int ks0 = (int)(((long long)slot * KSTEPS) / K2SPL);
    const int ks1 = (int)(((long long)(slot + 1) * KSTEPS) / K2SPL);

    f32x4 acc[2][4];
    float dac[2];
    #pragma unroll
    for (int u = 0; u < 2; ++u) {
        dac[u] = 0.f;
        #pragma unroll
        for (int v = 0; v < 4; ++v) acc[u][v] = f32x4{0.f,0.f,0.f,0.f};
    }

    f16x8 afA[2], bfA[4], afB[2], bfB[4];
    K2_LOAD(afA, bfA, ks0)
    int ks = ks0;
    for (; ks + 2 <= ks1; ks += 2) {
        K2_LOAD(afB, bfB, ks + 1)
        K2_MFMA(afA, bfA)
        K2_LOAD(afA, bfA, ks + 2)   // one-step overread stays inside workspace; unused
        K2_MFMA(afB, bfB)
    }
    if (ks < ks1) K2_MFMA(afA, bfA)

    #pragma unroll
    for (int u = 0; u < 2; ++u) {
        dac[u] += __shfl_xor(dac[u], 16);
        dac[u] += __shfl_xor(dac[u], 32);
    }
    if (quad == 0) {
        #pragma unroll
        for (int u = 0; u < 2; ++u)
            dpp[slot*512 + ebase + u*16 + col] = dac[u];
    }
    float* dst = spp + (size_t)slot * 32768 + (size_t)equad * 8192;
    #pragma unroll
    for (int u = 0; u < 2; ++u)
        #pragma unroll
        for (int v = 0; v < 4; ++v)
            *(f32x4*)(dst + (size_t)((wave*2 + u)*4 + v)*256 + (size_t)lane*4) = acc[u][v];
}

// ---------------- K2r: reduce partials (grid 512, 4 waves split the p-range) ----------------
__global__ void k2r_reduce(const float* __restrict__ spp, const float* __restrict__ dpp,
                           float* __restrict__ spre, float* __restrict__ dstd) {
    __shared__ float red[4][64];
    __shared__ float rdp[4][64];
    const int lane = threadIdx.x & 63, wave = threadIdx.x >> 6;
    const int i = blockIdx.x * 64 + lane;        // i in [0, 32768)
    float s = 0.f;
    const int p0 = wave * (K2SPL / 4);
    for (int p = p0; p < p0 + K2SPL/4; ++p) s += spp[(size_t)p*32768 + i];
    red[wave][lane] = s;
    float tt = 0.f;
    if (i < 512) {
        for (int p = p0; p < p0 + K2SPL/4; ++p) tt += dpp[p*512 + i];
    }
    rdp[wave][lane] = tt;
    __syncthreads();
    if (wave == 0) {
        float sum = red[0][lane] + red[1][lane] + red[2][lane] + red[3][lane];
        int r = i & 3, L = (i >> 2) & 63, v = (i >> 8) & 3, g = (i >> 10) & 7, eq = (i >> 13) & 3;
        int e = eq*128 + (g >> 1)*32 + (g & 1)*16 + (L >> 4)*4 + r;
        int d = v*16 + (L & 15);
        spre[e*64 + d] = sum;
        if (i < 512)
            dstd[i] = rdp[0][lane] + rdp[1][lane] + rdp[2][lane] + rdp[3][lane];
    }
}

// ---------------- K3: per-head middle block, m-split 8 ways (grid 64) ----------------
__global__ void k3_attn(const float* __restrict__ spre, const float* __restrict__ dstd,
                        const float* __restrict__ b1, const float* __restrict__ wq,
                        const float* __restrict__ wk, const float* __restrict__ wv,
                        const float* __restrict__ w3, const float* __restrict__ b3,
                        f16* __restrict__ sout) {
    __shared__ float wa[64][65], wb[64][65], wc[64][65];   // wq,wk,wv; wa reused for w3
    __shared__ float ss[64][65], kk[64][65], vv[64][65];
    __shared__ float qq[8][65], sc[8][65];                 // slice-local (8 m-rows)
    const int h = blockIdx.x >> 3, ms = blockIdx.x & 7, tid = threadIdx.x;

    for (int i = tid; i < 4096; i += 256) {
        int r = i >> 6, c = i & 63;
        wa[r][c] = wq[i];
        wb[r][c] = wk[i];
        wc[r][c] = wv[i];
        ss[r][c] = spre[h*4096 + i] / (dstd[h*64 + r] + 1e-5f) + b1[c];
    }
    __syncthreads();

    // k, v full (64 rows)
    #pragma unroll
    for (int it = 0; it < 16; ++it) {
        int m = it*4 + (tid >> 6), e = tid & 63;
        float ak = 0.f, av = 0.f;
        #pragma unroll 8
        for (int d = 0; d < 64; ++d) {
            float sv = ss[m][d];
            ak += sv * wb[e][d];
            av += sv * wc[e][d];
        }
        kk[m][e] = ak; vv[m][e] = av;
    }
    // q: slice only (8 rows)
    #pragma unroll
    for (int it = 0; it < 2; ++it) {
        int ml = it*4 + (tid >> 6), e = tid & 63;
        float aq = 0.f;
        #pragma unroll 8
        for (int d = 0; d < 64; ++d) aq += ss[ms*8 + ml][d] * wa[e][d];
        qq[ml][e] = aq;
    }
    __syncthreads();

    // scores (slice); stage w3 into wa (wq dead after qq)
    for (int i = tid; i < 4096; i += 256) wa[i >> 6][i & 63] = w3[i];
    #pragma unroll
    for (int it = 0; it < 2; ++it) {
        int ml = it*4 + (tid >> 6), l = tid & 63;
        float a = 0.f;
        #pragma unroll 8
        for (int e = 0; e < 64; ++e) a += qq[ml][e] * kk[l][e];
        sc[ml][l] = a * 0.125f;
    }
    __syncthreads();

    if (tid < 8) {
        int ml = tid;
        float mx = -1e30f;
        #pragma unroll 8
        for (int l = 0; l < 64; ++l) mx = fmaxf(mx, sc[ml][l]);
        float sm = 0.f;
        #pragma unroll 8
        for (int l = 0; l < 64; ++l) { float ev = __expf(sc[ml][l] - mx); sc[ml][l] = ev; sm += ev; }
        float rs = 1.0f / sm;
        #pragma unroll 8
        for (int l = 0; l < 64; ++l) sc[ml][l] *= rs;
    }
    __syncthreads();

    // s_att (slice) -> qq
    #pragma unroll
    for (int it = 0; it < 2; ++it) {
        int ml = it*4 + (tid >> 6), e = tid & 63;
        float a = 0.f;
        #pragma unroll 8
        for (int l = 0; l < 64; ++l) a += sc[ml][l] * vv[l][e];
        qq[ml][e] = a;
    }
    __syncthreads();

    // s_out^T slice: all 64 d, 8 m
    #pragma unroll
    for (int it = 0; it < 2; ++it) {
        int d = it*32 + (tid >> 3), ml = tid & 7;
        float a = b3[d];
        #pragma unroll 8
        for (int e = 0; e < 64; ++e) a += qq[ml][e] * wa[d][e];
        sout[(h*64 + d)*64 + ms*8 + ml] = (f16)a;
    }
}

// ---------------- K4: deslice x_out = w @ s_out (frag-linear stage, nontemporal stores) ----------------
__launch_bounds__(256, 4)
__global__ void k4_deslice(const f16* __restrict__ wTf, const f16* __restrict__ sout,
                           float* __restrict__ out) {
    __shared__ __align__(16) char lmem[36864];   // ldsW 32768 B / ldsO 33024 B, aliased
    f16*   ldsW = (f16*)lmem;                    // [16384] frag-linear w block (ks = this tile)
    float* ldsO = (float*)lmem;                  // [16][516] f32 store stage

    const int tid = threadIdx.x, wave = tid >> 6, lane = tid & 63;
    const int quad = lane >> 4, col = lane & 15;

    // bijective XCD swizzle (nwg = 3126 = 8*390 + 6)
    const int bid = blockIdx.x;
    const int xcd = bid & 7, idx = bid >> 3;
    const int q = KSTEPS >> 3, r = KSTEPS & 7;   // 390, 6
    const int swz = (xcd < r ? xcd*(q+1) : r*(q+1) + (xcd - r)*q) + idx;
    const int n0 = swz * 32;

    // stage: ONE contiguous 32 KB block (frag-linear tile for ks = swz)
    const f16* srcW = wTf + (size_t)swz * 16384;
    #pragma unroll
    for (int i = 0; i < 8; ++i) {
        int id = tid + i*256;
        *(f16x8*)(ldsW + (size_t)id*8) = *(const f16x8*)(srcW + (size_t)id*8);
    }
    __syncthreads();

    f32x4 acc[2][2][4];
    #pragma unroll
    for (int hh = 0; hh < 2; ++hh)
        #pragma unroll
        for (int t = 0; t < 2; ++t)
            #pragma unroll
            for (int v = 0; v < 4; ++v) acc[hh][t][v] = f32x4{0.f,0.f,0.f,0.f};

    #pragma unroll
    for (int hh = 0; hh < 2; ++hh) {
        int h = wave*2 + hh;
        #pragma unroll
        for (int ks = 0; ks < 2; ++ks) {
            f16x8 af[2], bf[4];
            // af[t][j] = w[e=h*64+ks*32+quad*8+j][n=n0+t*16+col], from frag-linear image
            #pragma unroll
            for (int t = 0; t < 2; ++t) {
                const int fb = (h*4 + ks*2 + (quad >> 1))*512
                             + (t*2 + (col >> 3))*128 + (quad & 1)*64 + (col & 7);
                f16x8 a;
                #pragma unroll
                for (int j = 0; j < 8; ++j)
                    a[j] = ldsW[fb + j*8];
                af[t] = a;
            }
            #pragma unroll
            for (int v = 0; v < 4; ++v)
                bf[v] = *(const f16x8*)(sout + (size_t)(h*64 + v*16 + col)*64 + ks*32 + quad*8);
            #pragma unroll
            for (int t = 0; t < 2; ++t)
                #pragma unroll
                for (int v = 0; v < 4; ++v)
                    acc[hh][t][v] = __builtin_amdgcn_mfma_f32_16x16x32_f16(af[t], bf[v], acc[hh][t][v], 0, 0, 0);
        }
    }

    // ---- epilogue: LDS transpose -> coalesced 2 KB-row NONTEMPORAL stores (2 passes of 16 n) ----
    #pragma unroll
    for (int p = 0; p < 2; ++p) {
        __syncthreads();                         // p0: ldsW reads done; p1: p0 stores done
        #pragma unroll
        for (int hh = 0; hh < 2; ++hh) {
            int h = wave*2 + hh;
            #pragma unroll
            for (int v = 0; v < 4; ++v)
                #pragma unroll
                for (int r2 = 0; r2 < 4; ++r2)
                    ldsO[(size_t)(quad*4 + r2)*516 + h*64 + v*16 + col] = acc[hh][p][v][r2];
        }
        __syncthreads();
        #pragma unroll
        for (int it = 0; it < 8; ++it) {
            int id = tid + it*256;               // 2048 chunks of 16 B (16 rows x 128)
            int row = id >> 7, ch = id & 127;
            int n = n0 + p*16 + row;
            if (n < N_TOK) {
                f32x4 v4 = *(const f32x4*)(ldsO + (size_t)row*516 + ch*4);
                __builtin_nontemporal_store(v4, (f32x4*)(out + (size_t)n*512 + ch*4));
            }
        }
    }
}

// ---------------- launcher ----------------
extern "C" void kernel_launch(void* const* d_in, const int* in_sizes, int n_in,
                              void* d_out, int out_size, void* d_ws, size_t ws_size,
                              hipStream_t stream) {
    const float* x           = (const float*)d_in[0];
    const float* temperature = (const float*)d_in[1];
    const float* w_slice     = (const float*)d_in[2];
    const float* b_slice     = (const float*)d_in[3];
    const float* w1          = (const float*)d_in[4];
    const float* b1          = (const float*)d_in[5];
    const float* wq          = (const float*)d_in[6];
    const float* wk          = (const float*)d_in[7];
    const float* wv          = (const float*)d_in[8];
    const float* w3          = (const float*)d_in[9];
    const float* b3          = (const float*)d_in[10];
    float* out = (float*)d_out;
    char*  ws  = (char*)d_ws;

    f16*   wTf   = (f16*)(ws + O_WT);
    f16*   yTf   = (f16*)(ws + O_YT);
    f16*   wfr   = (f16*)(ws + O_WFR);
    float* spp   = (float*)(ws + O_SPP);
    float* dpp   = (float*)(ws + O_DPP);
    float* spre  = (float*)(ws + O_SPRE);
    float* dstd  = (float*)(ws + O_DSTD);
    f16*   sout  = (f16*)(ws + O_SOUT);

    k0_pack<<<144, 256, 0, stream>>>(w_slice, w1, wfr);
    k1_slice<<<NT1*2, 256, 0, stream>>>(x, temperature, wfr, b_slice, wTf, yTf);
    k2_spre<<<K2SPL*4, 256, 0, stream>>>(wTf, yTf, spp, dpp);
    k2r_reduce<<<512, 256, 0, stream>>>(spp, dpp, spre, dstd);
    k3_attn<<<64, 256, 0, stream>>>(spre, dstd, b1, wq, wk, wv, w3, b3, sout);
    k4_deslice<<<KSTEPS, 256, 0, stream>>>(wTf, sout, out);
}

// Round 14
// 516.233 us; speedup vs baseline: 1.1415x; 1.0012x over previous
//
#include <hip/hip_runtime.h>

typedef _Float16 f16;
typedef _Float16 f16x8 __attribute__((ext_vector_type(8)));
typedef _Float16 f16x4 __attribute__((ext_vector_type(4)));
typedef float    f32x4 __attribute__((ext_vector_type(4)));

#define N_TOK   100000
#define NPAD    100032         // 3126 * 32 = 1563 * 64
#define NT1     1563           // 64-row n-tiles
#define CDIM    512
#define KSTEPS  (NPAD/32)      // 3126
#define K2SPL   256            // split-K slots

// ---------------- workspace layout (bytes) ----------------
#define O_WT     ((size_t)0)
#define SZ_WT    ((size_t)512*NPAD*2)
#define O_YT     (O_WT + SZ_WT)
#define SZ_YT    ((size_t)64*NPAD*2)
#define O_WFR    (O_YT + SZ_YT)                    // frag-linear W+w1 fp16
#define SZ_WFR   ((size_t)16*4*9*64*8*2)
#define O_SPP    (O_WFR + SZ_WFR)                  // s_pre partials [K2SPL][32768] f32
#define SZ_SPP   ((size_t)K2SPL*32768*4)
#define O_DPP    (O_SPP + SZ_SPP)                  // d partials [K2SPL][512] f32
#define SZ_DPP   ((size_t)K2SPL*512*4)
#define O_SPRE   (O_DPP + SZ_DPP)                  // s_pre [512][64] f32
#define SZ_SPRE  ((size_t)32768*4)
#define O_DSTD   (O_SPRE + SZ_SPRE)                // d [512] f32
#define SZ_DSTD  ((size_t)512*4)
#define O_SOUT   (O_DSTD + SZ_DSTD)                // s_out^T fp16 [8][64dh][64m]
#define SZ_SOUT  ((size_t)8*64*64*2)

// ---------------- K0: pack W = [w_slice; w1] (576x512) into MFMA-fragment-linear fp16 ----------------
__global__ void k0_pack(const float* __restrict__ wsf, const float* __restrict__ w1f,
                        f16* __restrict__ wfr) {
    int c = blockIdx.x * 256 + threadIdx.x;      // 36864 chunks total
    int lane = c & 63, g = c >> 6;               // g in 0..575
    int u  = g % 9,  r = g / 9;                  // r in 0..63
    int we = r & 3,  kg = r >> 2;
    int col = lane & 15, quad = lane >> 4;
    int k = kg * 32 + quad * 8;
    const float* src;
    if (u < 8) src = wsf + (size_t)(we*128 + u*16 + col) * CDIM + k;
    else       src = w1f + (size_t)(we*16  + col) * CDIM + k;
    float4 a = *(const float4*)(src);
    float4 b = *(const float4*)(src + 4);
    f16x8 h;
    h[0]=(f16)a.x; h[1]=(f16)a.y; h[2]=(f16)a.z; h[3]=(f16)a.w;
    h[4]=(f16)b.x; h[5]=(f16)b.y; h[6]=(f16)b.z; h[7]=(f16)b.w;
    *(f16x8*)(wfr + (size_t)c * 8) = h;
}

// ---------------- K1: slice GEMM + softmax + y GEMM (rotated bf AND x-stage pipeline) ----------------
// grid = 2*NT1: bid = nt*2 + hgrp; block = 4 waves, wave owns head hgrp*4+wave.
// bf/bfy for step kg+1 load at the tail of step kg (proven r10).
// NEW (T14): x[kg+1] is held in regs ACROSS a barrier — loaded during step kg-1,
// ds_written during step kg, so the write never waits on HBM latency; x[kg+2]
// loads issue pre-barrier with a full step of slack.
#define XROW 40
#define TPITCH 72
__launch_bounds__(256, 3)
__global__ void k1_slice(const float* __restrict__ x, const float* __restrict__ temperature,
                         const f16* __restrict__ wfr, const float* __restrict__ bsl,
                         f16* __restrict__ wTf, f16* __restrict__ yTf) {
    __shared__ f16 smem[320 * TPITCH];           // 46080 B: lT [256][72] + lY [64][72]; lX aliases lT
    f16* lX = smem;                               // [2][64*XROW] = 10240 B
    f16* lT = smem;                               // [256][72]
    f16* lY = smem + 256 * TPITCH;                // [64][72]

    const int tid  = threadIdx.x;
    const int wave = tid >> 6;
    const int lane = tid & 63;
    const int quad = lane >> 4;
    const int col  = lane & 15;
    const int hgrp = blockIdx.x & 1;
    const int nt   = blockIdx.x >> 1;
    const int n0   = nt * 64;
    const int h    = hgrp * 4 + wave;            // head owned by this wave

    const int srow = tid >> 2, sch = tid & 3;
    int snr = n0 + srow; if (snr > N_TOK - 1) snr = N_TOK - 1;
    const float* sbase = x + (size_t)snr * CDIM + sch * 8;

    const f16* wbase  = wfr + ((size_t)(h >> 1) * 9 + (size_t)(h & 1) * 4) * 512 + (size_t)lane * 8;
    const f16* wybase = wfr + ((size_t)wave * 9 + 8) * 512 + (size_t)lane * 8;
    const size_t KGSTR = (size_t)4 * 9 * 512;    // wfr elements per kg

    // prologue: stage x[0] into buf0; preload x[1] into held regs; bf for kg=0
    {
        float4 a = *(const float4*)(sbase);
        float4 bb = *(const float4*)(sbase + 4);
        f16x8 hh;
        hh[0]=(f16)a.x; hh[1]=(f16)a.y; hh[2]=(f16)a.z; hh[3]=(f16)a.w;
        hh[4]=(f16)bb.x; hh[5]=(f16)bb.y; hh[6]=(f16)bb.z; hh[7]=(f16)bb.w;
        *(f16x8*)(&lX[srow * XROW + sch * 8]) = hh;
    }
    float4 xa = *(const float4*)(sbase + 32);
    float4 xb = *(const float4*)(sbase + 36);

    f32x4 acc[4][5];
    #pragma unroll
    for (int nf = 0; nf < 4; ++nf)
        #pragma unroll
        for (int u = 0; u < 5; ++u) acc[nf][u] = f32x4{0.f,0.f,0.f,0.f};

    f16x8 bf[4];
    #pragma unroll
    for (int j = 0; j < 4; ++j) bf[j] = *(const f16x8*)(wbase + j * 512);
    f16x8 bfy;
    if (hgrp == 0) bfy = *(const f16x8*)(wybase);

    __syncthreads();

    #pragma unroll 2
    for (int kg = 0; kg < 16; ++kg) {
        const f16* xbuf = lX + (kg & 1) * (64 * XROW);
        f16x8 af[4];
        #pragma unroll
        for (int nf = 0; nf < 4; ++nf)
            af[nf] = *(const f16x8*)(xbuf + (nf*16 + col) * XROW + quad * 8);

        #pragma unroll
        for (int nf = 0; nf < 4; ++nf)
            #pragma unroll
            for (int j = 0; j < 4; ++j)
                acc[nf][j] = __builtin_amdgcn_mfma_f32_16x16x32_f16(af[nf], bf[j], acc[nf][j], 0, 0, 0);
        if (hgrp == 0) {
            #pragma unroll
            for (int nf = 0; nf < 4; ++nf)
                acc[nf][4] = __builtin_amdgcn_mfma_f32_16x16x32_f16(af[nf], bfy, acc[nf][4], 0, 0, 0);
        }

        // rotated bf prefetch for kg+1 (same registers, pre-barrier)
        if (kg < 15) {
            const f16* wb = wbase + (size_t)(kg + 1) * KGSTR;
            #pragma unroll
            for (int j = 0; j < 4; ++j) bf[j] = *(const f16x8*)(wb + j * 512);
            if (hgrp == 0) bfy = *(const f16x8*)(wybase + (size_t)(kg + 1) * KGSTR);
        }

        // write HELD x[kg+1] (loaded a full step ago -> no HBM wait)
        if (kg < 15) {
            f16x8 hh;
            hh[0]=(f16)xa.x; hh[1]=(f16)xa.y; hh[2]=(f16)xa.z; hh[3]=(f16)xa.w;
            hh[4]=(f16)xb.x; hh[5]=(f16)xb.y; hh[6]=(f16)xb.z; hh[7]=(f16)xb.w;
            *(f16x8*)(&lX[((kg + 1) & 1) * (64 * XROW) + srow * XROW + sch * 8]) = hh;
        }
        // issue x[kg+2] loads (full step of latency slack before their write)
        if (kg < 14) {
            xa = *(const float4*)(sbase + (kg + 2) * 32);
            xb = *(const float4*)(sbase + (kg + 2) * 32 + 4);
        }
        __syncthreads();
    }

    // ---- bias + temperature (one head per wave) ----
    #pragma unroll
    for (int j = 0; j < 4; ++j) {
        float bb = bsl[h*64 + j*16 + col];
        #pragma unroll
        for (int nf = 0; nf < 4; ++nf)
            #pragma unroll
            for (int r = 0; r < 4; ++r) acc[nf][j][r] += bb;
    }
    float tv = temperature[h];
    tv = fminf(fmaxf(tv, 0.1f), 5.0f);
    const float invt = 1.0f / tv;

    // ---- softmax over M=64 (4 frags x 16 cols); w -> lT, y -> lY ----
    #pragma unroll
    for (int nf = 0; nf < 4; ++nf) {
        const int nloc = nf*16 + quad*4;
        float mx[4];
        #pragma unroll
        for (int r = 0; r < 4; ++r) {
            float m01 = fmaxf(acc[nf][0][r], acc[nf][1][r]);
            float m23 = fmaxf(acc[nf][2][r], acc[nf][3][r]);
            mx[r] = fmaxf(m01, m23);
        }
        #pragma unroll
        for (int d = 1; d < 16; d <<= 1)
            #pragma unroll
            for (int r = 0; r < 4; ++r) mx[r] = fmaxf(mx[r], __shfl_xor(mx[r], d));
        float sm[4] = {0.f, 0.f, 0.f, 0.f};
        #pragma unroll
        for (int j = 0; j < 4; ++j)
            #pragma unroll
            for (int r = 0; r < 4; ++r) {
                float ev = __expf((acc[nf][j][r] - mx[r]) * invt);
                acc[nf][j][r] = ev;
                sm[r] += ev;
            }
        #pragma unroll
        for (int d = 1; d < 16; d <<= 1)
            #pragma unroll
            for (int r = 0; r < 4; ++r) sm[r] += __shfl_xor(sm[r], d);
        #pragma unroll
        for (int r = 0; r < 4; ++r) sm[r] = 1.0f / sm[r];
        #pragma unroll
        for (int j = 0; j < 4; ++j) {
            f16x4 pk;
            #pragma unroll
            for (int r = 0; r < 4; ++r) {
                int n = n0 + nloc + r;
                float wv = (n < N_TOK) ? acc[nf][j][r] * sm[r] : 0.0f;
                pk[r] = (f16)wv;
            }
            int e_loc = wave*64 + j*16 + col;        // local e within block's 256
            *(f16x4*)(lT + (size_t)e_loc*TPITCH + nloc) = pk;
        }
        if (hgrp == 0) {
            f16x4 pk;
            #pragma unroll
            for (int r = 0; r < 4; ++r) {
                int n = n0 + nloc + r;
                pk[r] = (n < N_TOK) ? (f16)acc[nf][4][r] : (f16)0.f;
            }
            *(f16x4*)(lY + (size_t)(wave*16 + col)*TPITCH + nloc) = pk;
        }
    }
    __syncthreads();

    // ---- frag-linear wTf emit: [ks][f][lane][8], fully coalesced 4KB bursts ----
    #pragma unroll
    for (int i = 0; i < 8; ++i) {
        int gid = tid + i*256;
        int laneL = gid & 63, chunk = gid >> 6;      // chunk 0..31
        int ks_loc = chunk >> 4, floc = chunk & 15;
        f16x8 v = *(const f16x8*)(lT + (size_t)(floc*16 + (laneL & 15))*TPITCH
                                     + ks_loc*32 + (laneL >> 4)*8);
        *(f16x8*)(wTf + ((size_t)((nt*2 + ks_loc)*32 + hgrp*16 + floc))*512
                       + (size_t)laneL*8) = v;
    }
    // ---- frag-linear yTf emit (hgrp==0): [ks][v][lane][8] ----
    if (hgrp == 0) {
        #pragma unroll
        for (int i = 0; i < 2; ++i) {
            int gid = tid + i*256;
            int laneL = gid & 63, chunk = gid >> 6;  // chunk 0..7
            int ks_loc = chunk >> 2, v4 = chunk & 3;
            f16x8 vv = *(const f16x8*)(lY + (size_t)(v4*16 + (laneL & 15))*TPITCH
                                          + ks_loc*32 + (laneL >> 4)*8);
            *(f16x8*)(yTf + ((size_t)((nt*2 + ks_loc)*4 + v4))*512
                           + (size_t)laneL*8) = vv;
        }
    }
}

// ---------------- K2: s_pre = sum_n w[n,e]*y[n,d]  (frag-linear, XCD-grouped equads) ----------------
#define K2_LOAD(AF, BF, kss)                                                         \
    {   _Pragma("unroll")                                                            \
        for (int v = 0; v < 4; ++v)                                                  \
            BF[v] = *(const f16x8*)(yTf + ((size_t)((kss)*4 + v))*512 + (size_t)lane*8); \
        _Pragma("unroll")                                                            \
        for (int u = 0; u < 2; ++u)                                                  \
            AF[u] = *(const f16x8*)(wTf + ((size_t)((kss)*32 + fbase + u))*512 + (size_t)lane*8); \
    }
#define K2_MFMA(AF, BF)                                                              \
    {   _Pragma("unroll")                                                            \
        for (int u = 0; u < 2; ++u) {                                                \
            _Pragma("unroll")                                                        \
            for (int v = 0; v < 4; ++v)                                              \
                acc[u][v] = __builtin_amdgcn_mfma_f32_16x16x32_f16(AF[u], BF[v], acc[u][v], 0, 0, 0); \
            float s_ = 0.f;                                                          \
            _Pragma("unroll")                                                        \
            for (int j = 0; j < 8; ++j) s_ += (float)AF[u][j];                       \
            dac[u] += s_;                                                            \
        }                                                                            \
    }
__launch_bounds__(256, 4)
__global__ void k2_spre(const f16* __restrict__ wTf, const f16* __restrict__ yTf,
                        float* __restrict__ spp, float* __restrict__ dpp) {
    const int tid = threadIdx.x, wave = tid >> 6, lane = tid & 63;
    const int quad = lane >> 4, col = lane & 15;
    // XCD-group: the 4 equad blocks of one slot land 8 apart (same XCD under %8
    // round-robin) so they share the slot's wTf/yTf k-chunk in that XCD's L2.
    const int b = blockIdx.x;                    // 1024
    const int g = b >> 5, rr = b & 31;
    const int slot = g * 8 + (rr & 7);
    const int equad = rr >> 3;
    const int ebase = equad * 128 + wave * 32;
    const int fbase = equad * 8 + wave * 2;      // e-frag base = ebase/16

    const int ks0 = (int)(((long long)slot * KSTEPS) / K2SPL);
    const int ks1 = (int)(((long long)(slot + 1) * KSTEPS) / K2SPL);

    f32x4 acc[2][4];
    float dac[2];
    #pragma unroll
    for (int u = 0; u < 2; ++u) {
        dac[u] = 0.f;
        #pragma unroll
        for (int v = 0; v < 4; ++v) acc[u][v] = f32x4{0.f,0.f,0.f,0.f};
    }

    f16x8 afA[2], bfA[4], afB[2], bfB[4];
    K2_LOAD(afA, bfA, ks0)
    int ks = ks0;
    for (; ks + 2 <= ks1; ks += 2) {
        K2_LOAD(afB, bfB, ks + 1)
        K2_MFMA(afA, bfA)
        K2_LOAD(afA, bfA, ks + 2)   // one-step overread stays inside workspace; unused
        K2_MFMA(afB, bfB)
    }
    if (ks < ks1) K2_MFMA(afA, bfA)

    #pragma unroll
    for (int u = 0; u < 2; ++u) {
        dac[u] += __shfl_xor(dac[u], 16);
        dac[u] += __shfl_xor(dac[u], 32);
    }
    if (quad == 0) {
        #pragma unroll
        for (int u = 0; u < 2; ++u)
            dpp[slot*512 + ebase + u*16 + col] = dac[u];
    }
    float* dst = spp + (size_t)slot * 32768 + (size_t)equad * 8192;
    #pragma unroll
    for (int u = 0; u < 2; ++u)
        #pragma unroll
        for (int v = 0; v < 4; ++v)
            *(f32x4*)(dst + (size_t)((wave*2 + u)*4 + v)*256 + (size_t)lane*4) = acc[u][v];
}

// ---------------- K2r: reduce partials (grid 512, 4 waves split the p-range) ----------------
__global__ void k2r_reduce(const float* __restrict__ spp, const float* __restrict__ dpp,
                           float* __restrict__ spre, float* __restrict__ dstd) {
    __shared__ float red[4][64];
    __shared__ float rdp[4][64];
    const int lane = threadIdx.x & 63, wave = threadIdx.x >> 6;
    const int i = blockIdx.x * 64 + lane;        // i in [0, 32768)
    float s = 0.f;
    const int p0 = wave * (K2SPL / 4);
    for (int p = p0; p < p0 + K2SPL/4; ++p) s += spp[(size_t)p*32768 + i];
    red[wave][lane] = s;
    float tt = 0.f;
    if (i < 512) {
        for (int p = p0; p < p0 + K2SPL/4; ++p) tt += dpp[p*512 + i];
    }
    rdp[wave][lane] = tt;
    __syncthreads();
    if (wave == 0) {
        float sum = red[0][lane] + red[1][lane] + red[2][lane] + red[3][lane];
        int r = i & 3, L = (i >> 2) & 63, v = (i >> 8) & 3, g = (i >> 10) & 7, eq = (i >> 13) & 3;
        int e = eq*128 + (g >> 1)*32 + (g & 1)*16 + (L >> 4)*4 + r;
        int d = v*16 + (L & 15);
        spre[e*64 + d] = sum;
        if (i < 512)
            dstd[i] = rdp[0][lane] + rdp[1][lane] + rdp[2][lane] + rdp[3][lane];
    }
}

// ---------------- K3: per-head middle block, m-split 8 ways (grid 64) ----------------
__global__ void k3_attn(const float* __restrict__ spre, const float* __restrict__ dstd,
                        const float* __restrict__ b1, const float* __restrict__ wq,
                        const float* __restrict__ wk, const float* __restrict__ wv,
                        const float* __restrict__ w3, const float* __restrict__ b3,
                        f16* __restrict__ sout) {
    __shared__ float wa[64][65], wb[64][65], wc[64][65];   // wq,wk,wv; wa reused for w3
    __shared__ float ss[64][65], kk[64][65], vv[64][65];
    __shared__ float qq[8][65], sc[8][65];                 // slice-local (8 m-rows)
    const int h = blockIdx.x >> 3, ms = blockIdx.x & 7, tid = threadIdx.x;

    for (int i = tid; i < 4096; i += 256) {
        int r = i >> 6, c = i & 63;
        wa[r][c] = wq[i];
        wb[r][c] = wk[i];
        wc[r][c] = wv[i];
        ss[r][c] = spre[h*4096 + i] / (dstd[h*64 + r] + 1e-5f) + b1[c];
    }
    __syncthreads();

    // k, v full (64 rows)
    #pragma unroll
    for (int it = 0; it < 16; ++it) {
        int m = it*4 + (tid >> 6), e = tid & 63;
        float ak = 0.f, av = 0.f;
        #pragma unroll 8
        for (int d = 0; d < 64; ++d) {
            float sv = ss[m][d];
            ak += sv * wb[e][d];
            av += sv * wc[e][d];
        }
        kk[m][e] = ak; vv[m][e] = av;
    }
    // q: slice only (8 rows)
    #pragma unroll
    for (int it = 0; it < 2; ++it) {
        int ml = it*4 + (tid >> 6), e = tid & 63;
        float aq = 0.f;
        #pragma unroll 8
        for (int d = 0; d < 64; ++d) aq += ss[ms*8 + ml][d] * wa[e][d];
        qq[ml][e] = aq;
    }
    __syncthreads();

    // scores (slice); stage w3 into wa (wq dead after qq)
    for (int i = tid; i < 4096; i += 256) wa[i >> 6][i & 63] = w3[i];
    #pragma unroll
    for (int it = 0; it < 2; ++it) {
        int ml = it*4 + (tid >> 6), l = tid & 63;
        float a = 0.f;
        #pragma unroll 8
        for (int e = 0; e < 64; ++e) a += qq[ml][e] * kk[l][e];
        sc[ml][l] = a * 0.125f;
    }
    __syncthreads();

    if (tid < 8) {
        int ml = tid;
        float mx = -1e30f;
        #pragma unroll 8
        for (int l = 0; l < 64; ++l) mx = fmaxf(mx, sc[ml][l]);
        float sm = 0.f;
        #pragma unroll 8
        for (int l = 0; l < 64; ++l) { float ev = __expf(sc[ml][l] - mx); sc[ml][l] = ev; sm += ev; }
        float rs = 1.0f / sm;
        #pragma unroll 8
        for (int l = 0; l < 64; ++l) sc[ml][l] *= rs;
    }
    __syncthreads();

    // s_att (slice) -> qq
    #pragma unroll
    for (int it = 0; it < 2; ++it) {
        int ml = it*4 + (tid >> 6), e = tid & 63;
        float a = 0.f;
        #pragma unroll 8
        for (int l = 0; l < 64; ++l) a += sc[ml][l] * vv[l][e];
        qq[ml][e] = a;
    }
    __syncthreads();

    // s_out^T slice: all 64 d, 8 m
    #pragma unroll
    for (int it = 0; it < 2; ++it) {
        int d = it*32 + (tid >> 3), ml = tid & 7;
        float a = b3[d];
        #pragma unroll 8
        for (int e = 0; e < 64; ++e) a += qq[ml][e] * wa[d][e];
        sout[(h*64 + d)*64 + ms*8 + ml] = (f16)a;
    }
}

// ---------------- K4: deslice x_out = w @ s_out (frag-linear stage, nontemporal stores) ----------------
__launch_bounds__(256, 4)
__global__ void k4_deslice(const f16* __restrict__ wTf, const f16* __restrict__ sout,
                           float* __restrict__ out) {
    __shared__ __align__(16) char lmem[36864];   // ldsW 32768 B / ldsO 33024 B, aliased
    f16*   ldsW = (f16*)lmem;                    // [16384] frag-linear w block (ks = this tile)
    float* ldsO = (float*)lmem;                  // [16][516] f32 store stage

    const int tid = threadIdx.x, wave = tid >> 6, lane = tid & 63;
    const int quad = lane >> 4, col = lane & 15;

    // bijective XCD swizzle (nwg = 3126 = 8*390 + 6)
    const int bid = blockIdx.x;
    const int xcd = bid & 7, idx = bid >> 3;
    const int q = KSTEPS >> 3, r = KSTEPS & 7;   // 390, 6
    const int swz = (xcd < r ? xcd*(q+1) : r*(q+1) + (xcd - r)*q) + idx;
    const int n0 = swz * 32;

    // stage: ONE contiguous 32 KB block (frag-linear tile for ks = swz)
    const f16* srcW = wTf + (size_t)swz * 16384;
    #pragma unroll
    for (int i = 0; i < 8; ++i) {
        int id = tid + i*256;
        *(f16x8*)(ldsW + (size_t)id*8) = *(const f16x8*)(srcW + (size_t)id*8);
    }
    __syncthreads();

    f32x4 acc[2][2][4];
    #pragma unroll
    for (int hh = 0; hh < 2; ++hh)
        #pragma unroll
        for (int t = 0; t < 2; ++t)
            #pragma unroll
            for (int v = 0; v < 4; ++v) acc[hh][t][v] = f32x4{0.f,0.f,0.f,0.f};

    #pragma unroll
    for (int hh = 0; hh < 2; ++hh) {
        int h = wave*2 + hh;
        #pragma unroll
        for (int ks = 0; ks < 2; ++ks) {
            f16x8 af[2], bf[4];
            // af[t][j] = w[e=h*64+ks*32+quad*8+j][n=n0+t*16+col], from frag-linear image
            #pragma unroll
            for (int t = 0; t < 2; ++t) {
                const int fb = (h*4 + ks*2 + (quad >> 1))*512
                             + (t*2 + (col >> 3))*128 + (quad & 1)*64 + (col & 7);
                f16x8 a;
                #pragma unroll
                for (int j = 0; j < 8; ++j)
                    a[j] = ldsW[fb + j*8];
                af[t] = a;
            }
            #pragma unroll
            for (int v = 0; v < 4; ++v)
                bf[v] = *(const f16x8*)(sout + (size_t)(h*64 + v*16 + col)*64 + ks*32 + quad*8);
            #pragma unroll
            for (int t = 0; t < 2; ++t)
                #pragma unroll
                for (int v = 0; v < 4; ++v)
                    acc[hh][t][v] = __builtin_amdgcn_mfma_f32_16x16x32_f16(af[t], bf[v], acc[hh][t][v], 0, 0, 0);
        }
    }

    // ---- epilogue: LDS transpose -> coalesced 2 KB-row NONTEMPORAL stores (2 passes of 16 n) ----
    #pragma unroll
    for (int p = 0; p < 2; ++p) {
        __syncthreads();                         // p0: ldsW reads done; p1: p0 stores done
        #pragma unroll
        for (int hh = 0; hh < 2; ++hh) {
            int h = wave*2 + hh;
            #pragma unroll
            for (int v = 0; v < 4; ++v)
                #pragma unroll
                for (int r2 = 0; r2 < 4; ++r2)
                    ldsO[(size_t)(quad*4 + r2)*516 + h*64 + v*16 + col] = acc[hh][p][v][r2];
        }
        __syncthreads();
        #pragma unroll
        for (int it = 0; it < 8; ++it) {
            int id = tid + it*256;               // 2048 chunks of 16 B (16 rows x 128)
            int row = id >> 7, ch = id & 127;
            int n = n0 + p*16 + row;
            if (n < N_TOK) {
                f32x4 v4 = *(const f32x4*)(ldsO + (size_t)row*516 + ch*4);
                __builtin_nontemporal_store(v4, (f32x4*)(out + (size_t)n*512 + ch*4));
            }
        }
    }
}

// ---------------- launcher ----------------
extern "C" void kernel_launch(void* const* d_in, const int* in_sizes, int n_in,
                              void* d_out, int out_size, void* d_ws, size_t ws_size,
                              hipStream_t stream) {
    const float* x           = (const float*)d_in[0];
    const float* temperature = (const float*)d_in[1];
    const float* w_slice     = (const float*)d_in[2];
    const float* b_slice     = (const float*)d_in[3];
    const float* w1          = (const float*)d_in[4];
    const float* b1          = (const float*)d_in[5];
    const float* wq          = (const float*)d_in[6];
    const float* wk          = (const float*)d_in[7];
    const float* wv          = (const float*)d_in[8];
    const float* w3          = (const float*)d_in[9];
    const float* b3          = (const float*)d_in[10];
    float* out = (float*)d_out;
    char*  ws  = (char*)d_ws;

    f16*   wTf   = (f16*)(ws + O_WT);
    f16*   yTf   = (f16*)(ws + O_YT);
    f16*   wfr   = (f16*)(ws + O_WFR);
    float* spp   = (float*)(ws + O_SPP);
    float* dpp   = (float*)(ws + O_DPP);
    float* spre  = (float*)(ws + O_SPRE);
    float* dstd  = (float*)(ws + O_DSTD);
    f16*   sout  = (f16*)(ws + O_SOUT);

    k0_pack<<<144, 256, 0, stream>>>(w_slice, w1, wfr);
    k1_slice<<<NT1*2, 256, 0, stream>>>(x, temperature, wfr, b_slice, wTf, yTf);
    k2_spre<<<K2SPL*4, 256, 0, stream>>>(wTf, yTf, spp, dpp);
    k2r_reduce<<<512, 256, 0, stream>>>(spp, dpp, spre, dstd);
    k3_attn<<<64, 256, 0, stream>>>(spre, dstd, b1, wq, wk, wv, w3, b3, sout);
    k4_deslice<<<KSTEPS, 256, 0, stream>>>(wTf, sout, out);
}

// Round 15
// 514.627 us; speedup vs baseline: 1.1450x; 1.0031x over previous
//
#include <hip/hip_runtime.h>

typedef _Float16 f16;
typedef _Float16 f16x8 __attribute__((ext_vector_type(8)));
typedef _Float16 f16x4 __attribute__((ext_vector_type(4)));
typedef float    f32x4 __attribute__((ext_vector_type(4)));

#define N_TOK   100000
#define NPAD    100032         // 3126 * 32 = 1563 * 64
#define NT1     1563           // 64-row n-tiles
#define CDIM    512
#define KSTEPS  (NPAD/32)      // 3126
#define K2SPL   256            // split-K slots

// ---------------- workspace layout (bytes) ----------------
#define O_WT     ((size_t)0)
#define SZ_WT    ((size_t)512*NPAD*2)
#define O_YT     (O_WT + SZ_WT)
#define SZ_YT    ((size_t)64*NPAD*2)
#define O_WFR    (O_YT + SZ_YT)                    // frag-linear W+w1 fp16
#define SZ_WFR   ((size_t)16*4*9*64*8*2)
#define O_SPP    (O_WFR + SZ_WFR)                  // s_pre partials [K2SPL][32768] f32
#define SZ_SPP   ((size_t)K2SPL*32768*4)
#define O_DPP    (O_SPP + SZ_SPP)                  // d partials [K2SPL][512] f32
#define SZ_DPP   ((size_t)K2SPL*512*4)
#define O_SPRE   (O_DPP + SZ_DPP)                  // s_pre [512][64] f32
#define SZ_SPRE  ((size_t)32768*4)
#define O_DSTD   (O_SPRE + SZ_SPRE)                // d [512] f32
#define SZ_DSTD  ((size_t)512*4)
#define O_SOUT   (O_DSTD + SZ_DSTD)                // s_out^T fp16 [8][64dh][64m]
#define SZ_SOUT  ((size_t)8*64*64*2)

// ---------------- K0: pack W = [w_slice; w1] (576x512) into MFMA-fragment-linear fp16 ----------------
__global__ void k0_pack(const float* __restrict__ wsf, const float* __restrict__ w1f,
                        f16* __restrict__ wfr) {
    int c = blockIdx.x * 256 + threadIdx.x;      // 36864 chunks total
    int lane = c & 63, g = c >> 6;               // g in 0..575
    int u  = g % 9,  r = g / 9;                  // r in 0..63
    int we = r & 3,  kg = r >> 2;
    int col = lane & 15, quad = lane >> 4;
    int k = kg * 32 + quad * 8;
    const float* src;
    if (u < 8) src = wsf + (size_t)(we*128 + u*16 + col) * CDIM + k;
    else       src = w1f + (size_t)(we*16  + col) * CDIM + k;
    float4 a = *(const float4*)(src);
    float4 b = *(const float4*)(src + 4);
    f16x8 h;
    h[0]=(f16)a.x; h[1]=(f16)a.y; h[2]=(f16)a.z; h[3]=(f16)a.w;
    h[4]=(f16)b.x; h[5]=(f16)b.y; h[6]=(f16)b.z; h[7]=(f16)b.w;
    *(f16x8*)(wfr + (size_t)c * 8) = h;
}

// ---------------- K1: slice GEMM + softmax + y GEMM (r14 pipeline + XCD-paired hgrp blocks) ----------------
// grid = 2*NT1. XCD pairing: the two hgrp-blocks of one n-tile map 8 bids apart
// (same bid%8 -> same XCD under round-robin dispatch), so the second x-tile read
// hits that XCD's L2 instead of HBM: FETCH ~205 MB -> ~112 MB. K1 is now
// traffic-rate-bound (2.06 TB/s x 326 MB = 158 us measured), so bytes -> time.
#define XROW 40
#define TPITCH 72
__launch_bounds__(256, 3)
__global__ void k1_slice(const float* __restrict__ x, const float* __restrict__ temperature,
                         const f16* __restrict__ wfr, const float* __restrict__ bsl,
                         f16* __restrict__ wTf, f16* __restrict__ yTf) {
    __shared__ f16 smem[320 * TPITCH];           // 46080 B: lT [256][72] + lY [64][72]; lX aliases lT
    f16* lX = smem;                               // [2][64*XROW] = 10240 B
    f16* lT = smem;                               // [256][72]
    f16* lY = smem + 256 * TPITCH;                // [64][72]

    const int tid  = threadIdx.x;
    const int wave = tid >> 6;
    const int lane = tid & 63;
    const int quad = lane >> 4;
    const int col  = lane & 15;

    // bid -> (nt, hgrp): pairs land on the same XCD (bid and bid+8)
    const int b = blockIdx.x;
    int nt, hg;
    if (b < 3120) { nt = (b >> 4) * 8 + (b & 7); hg = (b >> 3) & 1; }
    else          { int t = b - 3120; nt = 1560 + (t >> 1); hg = t & 1; }
    const int hgrp = hg;
    const int n0   = nt * 64;
    const int h    = hgrp * 4 + wave;            // head owned by this wave

    const int srow = tid >> 2, sch = tid & 3;
    int snr = n0 + srow; if (snr > N_TOK - 1) snr = N_TOK - 1;
    const float* sbase = x + (size_t)snr * CDIM + sch * 8;

    const f16* wbase  = wfr + ((size_t)(h >> 1) * 9 + (size_t)(h & 1) * 4) * 512 + (size_t)lane * 8;
    const f16* wybase = wfr + ((size_t)wave * 9 + 8) * 512 + (size_t)lane * 8;
    const size_t KGSTR = (size_t)4 * 9 * 512;    // wfr elements per kg

    // prologue: stage x[0] into buf0; preload x[1] into held regs; bf for kg=0
    {
        float4 a = *(const float4*)(sbase);
        float4 bb = *(const float4*)(sbase + 4);
        f16x8 hh;
        hh[0]=(f16)a.x; hh[1]=(f16)a.y; hh[2]=(f16)a.z; hh[3]=(f16)a.w;
        hh[4]=(f16)bb.x; hh[5]=(f16)bb.y; hh[6]=(f16)bb.z; hh[7]=(f16)bb.w;
        *(f16x8*)(&lX[srow * XROW + sch * 8]) = hh;
    }
    float4 xa = *(const float4*)(sbase + 32);
    float4 xb = *(const float4*)(sbase + 36);

    f32x4 acc[4][5];
    #pragma unroll
    for (int nf = 0; nf < 4; ++nf)
        #pragma unroll
        for (int u = 0; u < 5; ++u) acc[nf][u] = f32x4{0.f,0.f,0.f,0.f};

    f16x8 bf[4];
    #pragma unroll
    for (int j = 0; j < 4; ++j) bf[j] = *(const f16x8*)(wbase + j * 512);
    f16x8 bfy;
    if (hgrp == 0) bfy = *(const f16x8*)(wybase);

    __syncthreads();

    #pragma unroll 2
    for (int kg = 0; kg < 16; ++kg) {
        const f16* xbuf = lX + (kg & 1) * (64 * XROW);
        f16x8 af[4];
        #pragma unroll
        for (int nf = 0; nf < 4; ++nf)
            af[nf] = *(const f16x8*)(xbuf + (nf*16 + col) * XROW + quad * 8);

        #pragma unroll
        for (int nf = 0; nf < 4; ++nf)
            #pragma unroll
            for (int j = 0; j < 4; ++j)
                acc[nf][j] = __builtin_amdgcn_mfma_f32_16x16x32_f16(af[nf], bf[j], acc[nf][j], 0, 0, 0);
        if (hgrp == 0) {
            #pragma unroll
            for (int nf = 0; nf < 4; ++nf)
                acc[nf][4] = __builtin_amdgcn_mfma_f32_16x16x32_f16(af[nf], bfy, acc[nf][4], 0, 0, 0);
        }

        // rotated bf prefetch for kg+1 (same registers, pre-barrier)
        if (kg < 15) {
            const f16* wb = wbase + (size_t)(kg + 1) * KGSTR;
            #pragma unroll
            for (int j = 0; j < 4; ++j) bf[j] = *(const f16x8*)(wb + j * 512);
            if (hgrp == 0) bfy = *(const f16x8*)(wybase + (size_t)(kg + 1) * KGSTR);
        }

        // write HELD x[kg+1] (loaded a full step ago -> no HBM wait)
        if (kg < 15) {
            f16x8 hh;
            hh[0]=(f16)xa.x; hh[1]=(f16)xa.y; hh[2]=(f16)xa.z; hh[3]=(f16)xa.w;
            hh[4]=(f16)xb.x; hh[5]=(f16)xb.y; hh[6]=(f16)xb.z; hh[7]=(f16)xb.w;
            *(f16x8*)(&lX[((kg + 1) & 1) * (64 * XROW) + srow * XROW + sch * 8]) = hh;
        }
        // issue x[kg+2] loads (full step of latency slack before their write)
        if (kg < 14) {
            xa = *(const float4*)(sbase + (kg + 2) * 32);
            xb = *(const float4*)(sbase + (kg + 2) * 32 + 4);
        }
        __syncthreads();
    }

    // ---- bias + temperature (one head per wave) ----
    #pragma unroll
    for (int j = 0; j < 4; ++j) {
        float bb = bsl[h*64 + j*16 + col];
        #pragma unroll
        for (int nf = 0; nf < 4; ++nf)
            #pragma unroll
            for (int r = 0; r < 4; ++r) acc[nf][j][r] += bb;
    }
    float tv = temperature[h];
    tv = fminf(fmaxf(tv, 0.1f), 5.0f);
    const float invt = 1.0f / tv;

    // ---- softmax over M=64 (4 frags x 16 cols); w -> lT, y -> lY ----
    #pragma unroll
    for (int nf = 0; nf < 4; ++nf) {
        const int nloc = nf*16 + quad*4;
        float mx[4];
        #pragma unroll
        for (int r = 0; r < 4; ++r) {
            float m01 = fmaxf(acc[nf][0][r], acc[nf][1][r]);
            float m23 = fmaxf(acc[nf][2][r], acc[nf][3][r]);
            mx[r] = fmaxf(m01, m23);
        }
        #pragma unroll
        for (int d = 1; d < 16; d <<= 1)
            #pragma unroll
            for (int r = 0; r < 4; ++r) mx[r] = fmaxf(mx[r], __shfl_xor(mx[r], d));
        float sm[4] = {0.f, 0.f, 0.f, 0.f};
        #pragma unroll
        for (int j = 0; j < 4; ++j)
            #pragma unroll
            for (int r = 0; r < 4; ++r) {
                float ev = __expf((acc[nf][j][r] - mx[r]) * invt);
                acc[nf][j][r] = ev;
                sm[r] += ev;
            }
        #pragma unroll
        for (int d = 1; d < 16; d <<= 1)
            #pragma unroll
            for (int r = 0; r < 4; ++r) sm[r] += __shfl_xor(sm[r], d);
        #pragma unroll
        for (int r = 0; r < 4; ++r) sm[r] = 1.0f / sm[r];
        #pragma unroll
        for (int j = 0; j < 4; ++j) {
            f16x4 pk;
            #pragma unroll
            for (int r = 0; r < 4; ++r) {
                int n = n0 + nloc + r;
                float wv = (n < N_TOK) ? acc[nf][j][r] * sm[r] : 0.0f;
                pk[r] = (f16)wv;
            }
            int e_loc = wave*64 + j*16 + col;        // local e within block's 256
            *(f16x4*)(lT + (size_t)e_loc*TPITCH + nloc) = pk;
        }
        if (hgrp == 0) {
            f16x4 pk;
            #pragma unroll
            for (int r = 0; r < 4; ++r) {
                int n = n0 + nloc + r;
                pk[r] = (n < N_TOK) ? (f16)acc[nf][4][r] : (f16)0.f;
            }
            *(f16x4*)(lY + (size_t)(wave*16 + col)*TPITCH + nloc) = pk;
        }
    }
    __syncthreads();

    // ---- frag-linear wTf emit: [ks][f][lane][8], fully coalesced 4KB bursts ----
    #pragma unroll
    for (int i = 0; i < 8; ++i) {
        int gid = tid + i*256;
        int laneL = gid & 63, chunk = gid >> 6;      // chunk 0..31
        int ks_loc = chunk >> 4, floc = chunk & 15;
        f16x8 v = *(const f16x8*)(lT + (size_t)(floc*16 + (laneL & 15))*TPITCH
                                     + ks_loc*32 + (laneL >> 4)*8);
        *(f16x8*)(wTf + ((size_t)((nt*2 + ks_loc)*32 + hgrp*16 + floc))*512
                       + (size_t)laneL*8) = v;
    }
    // ---- frag-linear yTf emit (hgrp==0): [ks][v][lane][8] ----
    if (hgrp == 0) {
        #pragma unroll
        for (int i = 0; i < 2; ++i) {
            int gid = tid + i*256;
            int laneL = gid & 63, chunk = gid >> 6;  // chunk 0..7
            int ks_loc = chunk >> 2, v4 = chunk & 3;
            f16x8 vv = *(const f16x8*)(lY + (size_t)(v4*16 + (laneL & 15))*TPITCH
                                          + ks_loc*32 + (laneL >> 4)*8);
            *(f16x8*)(yTf + ((size_t)((nt*2 + ks_loc)*4 + v4))*512
                           + (size_t)laneL*8) = vv;
        }
    }
}

// ---------------- K2: s_pre = sum_n w[n,e]*y[n,d]  (frag-linear, XCD-grouped equads) ----------------
#define K2_LOAD(AF, BF, kss)                                                         \
    {   _Pragma("unroll")                                                            \
        for (int v = 0; v < 4; ++v)                                                  \
            BF[v] = *(const f16x8*)(yTf + ((size_t)((kss)*4 + v))*512 + (size_t)lane*8); \
        _Pragma("unroll")                                                            \
        for (int u = 0; u < 2; ++u)                                                  \
            AF[u] = *(const f16x8*)(wTf + ((size_t)((kss)*32 + fbase + u))*512 + (size_t)lane*8); \
    }
#define K2_MFMA(AF, BF)                                                              \
    {   _Pragma("unroll")                                                            \
        for (int u = 0; u < 2; ++u) {                                                \
            _Pragma("unroll")                                                        \
            for (int v = 0; v < 4; ++v)                                              \
                acc[u][v] = __builtin_amdgcn_mfma_f32_16x16x32_f16(AF[u], BF[v], acc[u][v], 0, 0, 0); \
            float s_ = 0.f;                                                          \
            _Pragma("unroll")                                                        \
            for (int j = 0; j < 8; ++j) s_ += (float)AF[u][j];                       \
            dac[u] += s_;                                                            \
        }                                                                            \
    }
__launch_bounds__(256, 4)
__global__ void k2_spre(const f16* __restrict__ wTf, const f16* __restrict__ yTf,
                        float* __restrict__ spp, float* __restrict__ dpp) {
    const int tid = threadIdx.x, wave = tid >> 6, lane = tid & 63;
    const int quad = lane >> 4, col = lane & 15;
    const int b = blockIdx.x;                    // 1024
    const int g = b >> 5, rr = b & 31;
    const int slot = g * 8 + (rr & 7);
    const int equad = rr >> 3;
    const int ebase = equad * 128 + wave * 32;
    const int fbase = equad * 8 + wave * 2;      // e-frag base = ebase/16

    const int ks0 = (int)(((long long)slot * KSTEPS) / K2SPL);
    const int ks1 = (int)(((long long)(slot + 1) * KSTEPS) / K2SPL);

    f32x4 acc[2][4];
    float dac[2];
    #pragma unroll
    for (int u = 0; u < 2; ++u) {
        dac[u] = 0.f;
        #pragma unroll
        for (int v = 0; v < 4; ++v) acc[u][v] = f32x4{0.f,0.f,0.f,0.f};
    }

    f16x8 afA[2], bfA[4], afB[2], bfB[4];
    K2_LOAD(afA, bfA, ks0)
    int ks = ks0;
    for (; ks + 2 <= ks1; ks += 2) {
        K2_LOAD(afB, bfB, ks + 1)
        K2_MFMA(afA, bfA)
        K2_LOAD(afA, bfA, ks + 2)   // one-step overread stays inside workspace; unused
        K2_MFMA(afB, bfB)
    }
    if (ks < ks1) K2_MFMA(afA, bfA)

    #pragma unroll
    for (int u = 0; u < 2; ++u) {
        dac[u] += __shfl_xor(dac[u], 16);
        dac[u] += __shfl_xor(dac[u], 32);
    }
    if (quad == 0) {
        #pragma unroll
        for (int u = 0; u < 2; ++u)
            dpp[slot*512 + ebase + u*16 + col] = dac[u];
    }
    float* dst = spp + (size_t)slot * 32768 + (size_t)equad * 8192;
    #pragma unroll
    for (int u = 0; u < 2; ++u)
        #pragma unroll
        for (int v = 0; v < 4; ++v)
            *(f32x4*)(dst + (size_t)((wave*2 + u)*4 + v)*256 + (size_t)lane*4) = acc[u][v];
}

// ---------------- K2r: reduce partials (grid 512, 4 waves split the p-range) ----------------
__global__ void k2r_reduce(const float* __restrict__ spp, const float* __restrict__ dpp,
                           float* __restrict__ spre, float* __restrict__ dstd) {
    __shared__ float red[4][64];
    __shared__ float rdp[4][64];
    const int lane = threadIdx.x & 63, wave = threadIdx.x >> 6;
    const int i = blockIdx.x * 64 + lane;        // i in [0, 32768)
    float s = 0.f;
    const int p0 = wave * (K2SPL / 4);
    for (int p = p0; p < p0 + K2SPL/4; ++p) s += spp[(size_t)p*32768 + i];
    red[wave][lane] = s;
    float tt = 0.f;
    if (i < 512) {
        for (int p = p0; p < p0 + K2SPL/4; ++p) tt += dpp[p*512 + i];
    }
    rdp[wave][lane] = tt;
    __syncthreads();
    if (wave == 0) {
        float sum = red[0][lane] + red[1][lane] + red[2][lane] + red[3][lane];
        int r = i & 3, L = (i >> 2) & 63, v = (i >> 8) & 3, g = (i >> 10) & 7, eq = (i >> 13) & 3;
        int e = eq*128 + (g >> 1)*32 + (g & 1)*16 + (L >> 4)*4 + r;
        int d = v*16 + (L & 15);
        spre[e*64 + d] = sum;
        if (i < 512)
            dstd[i] = rdp[0][lane] + rdp[1][lane] + rdp[2][lane] + rdp[3][lane];
    }
}

// ---------------- K3: per-head middle block, m-split 8 ways (grid 64) ----------------
__global__ void k3_attn(const float* __restrict__ spre, const float* __restrict__ dstd,
                        const float* __restrict__ b1, const float* __restrict__ wq,
                        const float* __restrict__ wk, const float* __restrict__ wv,
                        const float* __restrict__ w3, const float* __restrict__ b3,
                        f16* __restrict__ sout) {
    __shared__ float wa[64][65], wb[64][65], wc[64][65];   // wq,wk,wv; wa reused for w3
    __shared__ float ss[64][65], kk[64][65], vv[64][65];
    __shared__ float qq[8][65], sc[8][65];                 // slice-local (8 m-rows)
    const int h = blockIdx.x >> 3, ms = blockIdx.x & 7, tid = threadIdx.x;

    for (int i = tid; i < 4096; i += 256) {
        int r = i >> 6, c = i & 63;
        wa[r][c] = wq[i];
        wb[r][c] = wk[i];
        wc[r][c] = wv[i];
        ss[r][c] = spre[h*4096 + i] / (dstd[h*64 + r] + 1e-5f) + b1[c];
    }
    __syncthreads();

    // k, v full (64 rows)
    #pragma unroll
    for (int it = 0; it < 16; ++it) {
        int m = it*4 + (tid >> 6), e = tid & 63;
        float ak = 0.f, av = 0.f;
        #pragma unroll 8
        for (int d = 0; d < 64; ++d) {
            float sv = ss[m][d];
            ak += sv * wb[e][d];
            av += sv * wc[e][d];
        }
        kk[m][e] = ak; vv[m][e] = av;
    }
    // q: slice only (8 rows)
    #pragma unroll
    for (int it = 0; it < 2; ++it) {
        int ml = it*4 + (tid >> 6), e = tid & 63;
        float aq = 0.f;
        #pragma unroll 8
        for (int d = 0; d < 64; ++d) aq += ss[ms*8 + ml][d] * wa[e][d];
        qq[ml][e] = aq;
    }
    __syncthreads();

    // scores (slice); stage w3 into wa (wq dead after qq)
    for (int i = tid; i < 4096; i += 256) wa[i >> 6][i & 63] = w3[i];
    #pragma unroll
    for (int it = 0; it < 2; ++it) {
        int ml = it*4 + (tid >> 6), l = tid & 63;
        float a = 0.f;
        #pragma unroll 8
        for (int e = 0; e < 64; ++e) a += qq[ml][e] * kk[l][e];
        sc[ml][l] = a * 0.125f;
    }
    __syncthreads();

    if (tid < 8) {
        int ml = tid;
        float mx = -1e30f;
        #pragma unroll 8
        for (int l = 0; l < 64; ++l) mx = fmaxf(mx, sc[ml][l]);
        float sm = 0.f;
        #pragma unroll 8
        for (int l = 0; l < 64; ++l) { float ev = __expf(sc[ml][l] - mx); sc[ml][l] = ev; sm += ev; }
        float rs = 1.0f / sm;
        #pragma unroll 8
        for (int l = 0; l < 64; ++l) sc[ml][l] *= rs;
    }
    __syncthreads();

    // s_att (slice) -> qq
    #pragma unroll
    for (int it = 0; it < 2; ++it) {
        int ml = it*4 + (tid >> 6), e = tid & 63;
        float a = 0.f;
        #pragma unroll 8
        for (int l = 0; l < 64; ++l) a += sc[ml][l] * vv[l][e];
        qq[ml][e] = a;
    }
    __syncthreads();

    // s_out^T slice: all 64 d, 8 m
    #pragma unroll
    for (int it = 0; it < 2; ++it) {
        int d = it*32 + (tid >> 3), ml = tid & 7;
        float a = b3[d];
        #pragma unroll 8
        for (int e = 0; e < 64; ++e) a += qq[ml][e] * wa[d][e];
        sout[(h*64 + d)*64 + ms*8 + ml] = (f16)a;
    }
}

// ---------------- K4: deslice x_out = w @ s_out (frag-linear stage, nontemporal stores) ----------------
__launch_bounds__(256, 4)
__global__ void k4_deslice(const f16* __restrict__ wTf, const f16* __restrict__ sout,
                           float* __restrict__ out) {
    __shared__ __align__(16) char lmem[36864];   // ldsW 32768 B / ldsO 33024 B, aliased
    f16*   ldsW = (f16*)lmem;                    // [16384] frag-linear w block (ks = this tile)
    float* ldsO = (float*)lmem;                  // [16][516] f32 store stage

    const int tid = threadIdx.x, wave = tid >> 6, lane = tid & 63;
    const int quad = lane >> 4, col = lane & 15;

    // bijective XCD swizzle (nwg = 3126 = 8*390 + 6)
    const int bid = blockIdx.x;
    const int xcd = bid & 7, idx = bid >> 3;
    const int q = KSTEPS >> 3, r = KSTEPS & 7;   // 390, 6
    const int swz = (xcd < r ? xcd*(q+1) : r*(q+1) + (xcd - r)*q) + idx;
    const int n0 = swz * 32;

    // stage: ONE contiguous 32 KB block (frag-linear tile for ks = swz)
    const f16* srcW = wTf + (size_t)swz * 16384;
    #pragma unroll
    for (int i = 0; i < 8; ++i) {
        int id = tid + i*256;
        *(f16x8*)(ldsW + (size_t)id*8) = *(const f16x8*)(srcW + (size_t)id*8);
    }
    __syncthreads();

    f32x4 acc[2][2][4];
    #pragma unroll
    for (int hh = 0; hh < 2; ++hh)
        #pragma unroll
        for (int t = 0; t < 2; ++t)
            #pragma unroll
            for (int v = 0; v < 4; ++v) acc[hh][t][v] = f32x4{0.f,0.f,0.f,0.f};

    #pragma unroll
    for (int hh = 0; hh < 2; ++hh) {
        int h = wave*2 + hh;
        #pragma unroll
        for (int ks = 0; ks < 2; ++ks) {
            f16x8 af[2], bf[4];
            // af[t][j] = w[e=h*64+ks*32+quad*8+j][n=n0+t*16+col], from frag-linear image
            #pragma unroll
            for (int t = 0; t < 2; ++t) {
                const int fb = (h*4 + ks*2 + (quad >> 1))*512
                             + (t*2 + (col >> 3))*128 + (quad & 1)*64 + (col & 7);
                f16x8 a;
                #pragma unroll
                for (int j = 0; j < 8; ++j)
                    a[j] = ldsW[fb + j*8];
                af[t] = a;
            }
            #pragma unroll
            for (int v = 0; v < 4; ++v)
                bf[v] = *(const f16x8*)(sout + (size_t)(h*64 + v*16 + col)*64 + ks*32 + quad*8);
            #pragma unroll
            for (int t = 0; t < 2; ++t)
                #pragma unroll
                for (int v = 0; v < 4; ++v)
                    acc[hh][t][v] = __builtin_amdgcn_mfma_f32_16x16x32_f16(af[t], bf[v], acc[hh][t][v], 0, 0, 0);
        }
    }

    // ---- epilogue: LDS transpose -> coalesced 2 KB-row NONTEMPORAL stores (2 passes of 16 n) ----
    #pragma unroll
    for (int p = 0; p < 2; ++p) {
        __syncthreads();                         // p0: ldsW reads done; p1: p0 stores done
        #pragma unroll
        for (int hh = 0; hh < 2; ++hh) {
            int h = wave*2 + hh;
            #pragma unroll
            for (int v = 0; v < 4; ++v)
                #pragma unroll
                for (int r2 = 0; r2 < 4; ++r2)
                    ldsO[(size_t)(quad*4 + r2)*516 + h*64 + v*16 + col] = acc[hh][p][v][r2];
        }
        __syncthreads();
        #pragma unroll
        for (int it = 0; it < 8; ++it) {
            int id = tid + it*256;               // 2048 chunks of 16 B (16 rows x 128)
            int row = id >> 7, ch = id & 127;
            int n = n0 + p*16 + row;
            if (n < N_TOK) {
                f32x4 v4 = *(const f32x4*)(ldsO + (size_t)row*516 + ch*4);
                __builtin_nontemporal_store(v4, (f32x4*)(out + (size_t)n*512 + ch*4));
            }
        }
    }
}

// ---------------- launcher ----------------
extern "C" void kernel_launch(void* const* d_in, const int* in_sizes, int n_in,
                              void* d_out, int out_size, void* d_ws, size_t ws_size,
                              hipStream_t stream) {
    const float* x           = (const float*)d_in[0];
    const float* temperature = (const float*)d_in[1];
    const float* w_slice     = (const float*)d_in[2];
    const float* b_slice     = (const float*)d_in[3];
    const float* w1          = (const float*)d_in[4];
    const float* b1          = (const float*)d_in[5];
    const float* wq          = (const float*)d_in[6];
    const float* wk          = (const float*)d_in[7];
    const float* wv          = (const float*)d_in[8];
    const float* w3          = (const float*)d_in[9];
    const float* b3          = (const float*)d_in[10];
    float* out = (float*)d_out;
    char*  ws  = (char*)d_ws;

    f16*   wTf   = (f16*)(ws + O_WT);
    f16*   yTf   = (f16*)(ws + O_YT);
    f16*   wfr   = (f16*)(ws + O_WFR);
    float* spp   = (float*)(ws + O_SPP);
    float* dpp   = (float*)(ws + O_DPP);
    float* spre  = (float*)(ws + O_SPRE);
    float* dstd  = (float*)(ws + O_DSTD);
    f16*   sout  = (f16*)(ws + O_SOUT);

    k0_pack<<<144, 256, 0, stream>>>(w_slice, w1, wfr);
    k1_slice<<<NT1*2, 256, 0, stream>>>(x, temperature, wfr, b_slice, wTf, yTf);
    k2_spre<<<K2SPL*4, 256, 0, stream>>>(wTf, yTf, spp, dpp);
    k2r_reduce<<<512, 256, 0, stream>>>(spp, dpp, spre, dstd);
    k3_attn<<<64, 256, 0, stream>>>(spre, dstd, b1, wq, wk, wv, w3, b3, sout);
    k4_deslice<<<KSTEPS, 256, 0, stream>>>(wTf, sout, out);
}

// Round 16
// 513.819 us; speedup vs baseline: 1.1468x; 1.0016x over previous
//
#include <hip/hip_runtime.h>

typedef _Float16 f16;
typedef _Float16 f16x8 __attribute__((ext_vector_type(8)));
typedef _Float16 f16x4 __attribute__((ext_vector_type(4)));
typedef float    f32x4 __attribute__((ext_vector_type(4)));

#define N_TOK   100000
#define NPAD    100032         // 3126 * 32 = 1563 * 64
#define NT1     1563           // 64-row n-tiles
#define CDIM    512
#define KSTEPS  (NPAD/32)      // 3126
#define K2SPL   256            // split-K slots

// ---------------- workspace layout (bytes) ----------------
#define O_WT     ((size_t)0)
#define SZ_WT    ((size_t)512*NPAD*2)
#define O_YT     (O_WT + SZ_WT)
#define SZ_YT    ((size_t)64*NPAD*2)
#define O_WFR    (O_YT + SZ_YT)                    // frag-linear W+w1 fp16
#define SZ_WFR   ((size_t)16*4*9*64*8*2)
#define O_SPP    (O_WFR + SZ_WFR)                  // s_pre partials [K2SPL][32768] f32
#define SZ_SPP   ((size_t)K2SPL*32768*4)
#define O_DPP    (O_SPP + SZ_SPP)                  // d partials [K2SPL][512] f32
#define SZ_DPP   ((size_t)K2SPL*512*4)
#define O_SPRE   (O_DPP + SZ_DPP)                  // s_pre [512][64] f32
#define SZ_SPRE  ((size_t)32768*4)
#define O_DSTD   (O_SPRE + SZ_SPRE)                // d [512] f32
#define SZ_DSTD  ((size_t)512*4)
#define O_SOUT   (O_DSTD + SZ_DSTD)                // s_out^T fp16 [8][64dh][64m]
#define SZ_SOUT  ((size_t)8*64*64*2)

// ---------------- K0: pack W = [w_slice; w1] (576x512) into MFMA-fragment-linear fp16 ----------------
__global__ void k0_pack(const float* __restrict__ wsf, const float* __restrict__ w1f,
                        f16* __restrict__ wfr) {
    int c = blockIdx.x * 256 + threadIdx.x;      // 36864 chunks total
    int lane = c & 63, g = c >> 6;               // g in 0..575
    int u  = g % 9,  r = g / 9;                  // r in 0..63
    int we = r & 3,  kg = r >> 2;
    int col = lane & 15, quad = lane >> 4;
    int k = kg * 32 + quad * 8;
    const float* src;
    if (u < 8) src = wsf + (size_t)(we*128 + u*16 + col) * CDIM + k;
    else       src = w1f + (size_t)(we*16  + col) * CDIM + k;
    float4 a = *(const float4*)(src);
    float4 b = *(const float4*)(src + 4);
    f16x8 h;
    h[0]=(f16)a.x; h[1]=(f16)a.y; h[2]=(f16)a.z; h[3]=(f16)a.w;
    h[4]=(f16)b.x; h[5]=(f16)b.y; h[6]=(f16)b.z; h[7]=(f16)b.w;
    *(f16x8*)(wfr + (size_t)c * 8) = h;
}

// ---------------- K1: slice GEMM + softmax + y GEMM (r14 exact: rotated bf + T14 x-hold, natural bids) ----------------
// grid = 2*NT1: bid = nt*2 + hgrp; block = 4 waves, wave owns head hgrp*4+wave.
// Pairing REVERTED: two A/B tests (r6, r15) show bid%8 pairing costs ~10 us despite
// halving FETCH — K1 is structure-bound at ~158 us, not byte-bound.
#define XROW 40
#define TPITCH 72
__launch_bounds__(256, 3)
__global__ void k1_slice(const float* __restrict__ x, const float* __restrict__ temperature,
                         const f16* __restrict__ wfr, const float* __restrict__ bsl,
                         f16* __restrict__ wTf, f16* __restrict__ yTf) {
    __shared__ f16 smem[320 * TPITCH];           // 46080 B: lT [256][72] + lY [64][72]; lX aliases lT
    f16* lX = smem;                               // [2][64*XROW] = 10240 B
    f16* lT = smem;                               // [256][72]
    f16* lY = smem + 256 * TPITCH;                // [64][72]

    const int tid  = threadIdx.x;
    const int wave = tid >> 6;
    const int lane = tid & 63;
    const int quad = lane >> 4;
    const int col  = lane & 15;
    const int hgrp = blockIdx.x & 1;
    const int nt   = blockIdx.x >> 1;
    const int n0   = nt * 64;
    const int h    = hgrp * 4 + wave;            // head owned by this wave

    const int srow = tid >> 2, sch = tid & 3;
    int snr = n0 + srow; if (snr > N_TOK - 1) snr = N_TOK - 1;
    const float* sbase = x + (size_t)snr * CDIM + sch * 8;

    const f16* wbase  = wfr + ((size_t)(h >> 1) * 9 + (size_t)(h & 1) * 4) * 512 + (size_t)lane * 8;
    const f16* wybase = wfr + ((size_t)wave * 9 + 8) * 512 + (size_t)lane * 8;
    const size_t KGSTR = (size_t)4 * 9 * 512;    // wfr elements per kg

    // prologue: stage x[0] into buf0; preload x[1] into held regs; bf for kg=0
    {
        float4 a = *(const float4*)(sbase);
        float4 bb = *(const float4*)(sbase + 4);
        f16x8 hh;
        hh[0]=(f16)a.x; hh[1]=(f16)a.y; hh[2]=(f16)a.z; hh[3]=(f16)a.w;
        hh[4]=(f16)bb.x; hh[5]=(f16)bb.y; hh[6]=(f16)bb.z; hh[7]=(f16)bb.w;
        *(f16x8*)(&lX[srow * XROW + sch * 8]) = hh;
    }
    float4 xa = *(const float4*)(sbase + 32);
    float4 xb = *(const float4*)(sbase + 36);

    f32x4 acc[4][5];
    #pragma unroll
    for (int nf = 0; nf < 4; ++nf)
        #pragma unroll
        for (int u = 0; u < 5; ++u) acc[nf][u] = f32x4{0.f,0.f,0.f,0.f};

    f16x8 bf[4];
    #pragma unroll
    for (int j = 0; j < 4; ++j) bf[j] = *(const f16x8*)(wbase + j * 512);
    f16x8 bfy;
    if (hgrp == 0) bfy = *(const f16x8*)(wybase);

    __syncthreads();

    #pragma unroll 2
    for (int kg = 0; kg < 16; ++kg) {
        const f16* xbuf = lX + (kg & 1) * (64 * XROW);
        f16x8 af[4];
        #pragma unroll
        for (int nf = 0; nf < 4; ++nf)
            af[nf] = *(const f16x8*)(xbuf + (nf*16 + col) * XROW + quad * 8);

        #pragma unroll
        for (int nf = 0; nf < 4; ++nf)
            #pragma unroll
            for (int j = 0; j < 4; ++j)
                acc[nf][j] = __builtin_amdgcn_mfma_f32_16x16x32_f16(af[nf], bf[j], acc[nf][j], 0, 0, 0);
        if (hgrp == 0) {
            #pragma unroll
            for (int nf = 0; nf < 4; ++nf)
                acc[nf][4] = __builtin_amdgcn_mfma_f32_16x16x32_f16(af[nf], bfy, acc[nf][4], 0, 0, 0);
        }

        // rotated bf prefetch for kg+1 (same registers, pre-barrier)
        if (kg < 15) {
            const f16* wb = wbase + (size_t)(kg + 1) * KGSTR;
            #pragma unroll
            for (int j = 0; j < 4; ++j) bf[j] = *(const f16x8*)(wb + j * 512);
            if (hgrp == 0) bfy = *(const f16x8*)(wybase + (size_t)(kg + 1) * KGSTR);
        }

        // write HELD x[kg+1] (loaded a full step ago -> no HBM wait)
        if (kg < 15) {
            f16x8 hh;
            hh[0]=(f16)xa.x; hh[1]=(f16)xa.y; hh[2]=(f16)xa.z; hh[3]=(f16)xa.w;
            hh[4]=(f16)xb.x; hh[5]=(f16)xb.y; hh[6]=(f16)xb.z; hh[7]=(f16)xb.w;
            *(f16x8*)(&lX[((kg + 1) & 1) * (64 * XROW) + srow * XROW + sch * 8]) = hh;
        }
        // issue x[kg+2] loads (full step of latency slack before their write)
        if (kg < 14) {
            xa = *(const float4*)(sbase + (kg + 2) * 32);
            xb = *(const float4*)(sbase + (kg + 2) * 32 + 4);
        }
        __syncthreads();
    }

    // ---- bias + temperature (one head per wave) ----
    #pragma unroll
    for (int j = 0; j < 4; ++j) {
        float bb = bsl[h*64 + j*16 + col];
        #pragma unroll
        for (int nf = 0; nf < 4; ++nf)
            #pragma unroll
            for (int r = 0; r < 4; ++r) acc[nf][j][r] += bb;
    }
    float tv = temperature[h];
    tv = fminf(fmaxf(tv, 0.1f), 5.0f);
    const float invt = 1.0f / tv;

    // ---- softmax over M=64 (4 frags x 16 cols); w -> lT, y -> lY ----
    #pragma unroll
    for (int nf = 0; nf < 4; ++nf) {
        const int nloc = nf*16 + quad*4;
        float mx[4];
        #pragma unroll
        for (int r = 0; r < 4; ++r) {
            float m01 = fmaxf(acc[nf][0][r], acc[nf][1][r]);
            float m23 = fmaxf(acc[nf][2][r], acc[nf][3][r]);
            mx[r] = fmaxf(m01, m23);
        }
        #pragma unroll
        for (int d = 1; d < 16; d <<= 1)
            #pragma unroll
            for (int r = 0; r < 4; ++r) mx[r] = fmaxf(mx[r], __shfl_xor(mx[r], d));
        float sm[4] = {0.f, 0.f, 0.f, 0.f};
        #pragma unroll
        for (int j = 0; j < 4; ++j)
            #pragma unroll
            for (int r = 0; r < 4; ++r) {
                float ev = __expf((acc[nf][j][r] - mx[r]) * invt);
                acc[nf][j][r] = ev;
                sm[r] += ev;
            }
        #pragma unroll
        for (int d = 1; d < 16; d <<= 1)
            #pragma unroll
            for (int r = 0; r < 4; ++r) sm[r] += __shfl_xor(sm[r], d);
        #pragma unroll
        for (int r = 0; r < 4; ++r) sm[r] = 1.0f / sm[r];
        #pragma unroll
        for (int j = 0; j < 4; ++j) {
            f16x4 pk;
            #pragma unroll
            for (int r = 0; r < 4; ++r) {
                int n = n0 + nloc + r;
                float wv = (n < N_TOK) ? acc[nf][j][r] * sm[r] : 0.0f;
                pk[r] = (f16)wv;
            }
            int e_loc = wave*64 + j*16 + col;        // local e within block's 256
            *(f16x4*)(lT + (size_t)e_loc*TPITCH + nloc) = pk;
        }
        if (hgrp == 0) {
            f16x4 pk;
            #pragma unroll
            for (int r = 0; r < 4; ++r) {
                int n = n0 + nloc + r;
                pk[r] = (n < N_TOK) ? (f16)acc[nf][4][r] : (f16)0.f;
            }
            *(f16x4*)(lY + (size_t)(wave*16 + col)*TPITCH + nloc) = pk;
        }
    }
    __syncthreads();

    // ---- frag-linear wTf emit: [ks][f][lane][8], fully coalesced 4KB bursts ----
    #pragma unroll
    for (int i = 0; i < 8; ++i) {
        int gid = tid + i*256;
        int laneL = gid & 63, chunk = gid >> 6;      // chunk 0..31
        int ks_loc = chunk >> 4, floc = chunk & 15;
        f16x8 v = *(const f16x8*)(lT + (size_t)(floc*16 + (laneL & 15))*TPITCH
                                     + ks_loc*32 + (laneL >> 4)*8);
        *(f16x8*)(wTf + ((size_t)((nt*2 + ks_loc)*32 + hgrp*16 + floc))*512
                       + (size_t)laneL*8) = v;
    }
    // ---- frag-linear yTf emit (hgrp==0): [ks][v][lane][8] ----
    if (hgrp == 0) {
        #pragma unroll
        for (int i = 0; i < 2; ++i) {
            int gid = tid + i*256;
            int laneL = gid & 63, chunk = gid >> 6;  // chunk 0..7
            int ks_loc = chunk >> 2, v4 = chunk & 3;
            f16x8 vv = *(const f16x8*)(lY + (size_t)(v4*16 + (laneL & 15))*TPITCH
                                          + ks_loc*32 + (laneL >> 4)*8);
            *(f16x8*)(yTf + ((size_t)((nt*2 + ks_loc)*4 + v4))*512
                           + (size_t)laneL*8) = vv;
        }
    }
}

// ---------------- K2: s_pre = sum_n w[n,e]*y[n,d]  (frag-linear, XCD-grouped equads) ----------------
#define K2_LOAD(AF, BF, kss)                                                         \
    {   _Pragma("unroll")                                                            \
        for (int v = 0; v < 4; ++v)                                                  \
            BF[v] = *(const f16x8*)(yTf + ((size_t)((kss)*4 + v))*512 + (size_t)lane*8); \
        _Pragma("unroll")                                                            \
        for (int u = 0; u < 2; ++u)                                                  \
            AF[u] = *(const f16x8*)(wTf + ((size_t)((kss)*32 + fbase + u))*512 + (size_t)lane*8); \
    }
#define K2_MFMA(AF, BF)                                                              \
    {   _Pragma("unroll")                                                            \
        for (int u = 0; u < 2; ++u) {                                                \
            _Pragma("unroll")                                                        \
            for (int v = 0; v < 4; ++v)                                              \
                acc[u][v] = __builtin_amdgcn_mfma_f32_16x16x32_f16(AF[u], BF[v], acc[u][v], 0, 0, 0); \
            float s_ = 0.f;                                                          \
            _Pragma("unroll")                                                        \
            for (int j = 0; j < 8; ++j) s_ += (float)AF[u][j];                       \
            dac[u] += s_;                                                            \
        }                                                                            \
    }
__launch_bounds__(256, 4)
__global__ void k2_spre(const f16* __restrict__ wTf, const f16* __restrict__ yTf,
                        float* __restrict__ spp, float* __restrict__ dpp) {
    const int tid = threadIdx.x, wave = tid >> 6, lane = tid & 63;
    const int quad = lane >> 4, col = lane & 15;
    const int b = blockIdx.x;                    // 1024
    const int g = b >> 5, rr = b & 31;
    const int slot = g * 8 + (rr & 7);
    const int equad = rr >> 3;
    const int ebase = equad * 128 + wave * 32;
    const int fbase = equad * 8 + wave * 2;      // e-frag base = ebase/16

    const int ks0 = (int)(((long long)slot * KSTEPS) / K2SPL);
    const int ks1 = (int)(((long long)(slot + 1) * KSTEPS) / K2SPL);

    f32x4 acc[2][4];
    float dac[2];
    #pragma unroll
    for (int u = 0; u < 2; ++u) {
        dac[u] = 0.f;
        #pragma unroll
        for (int v = 0; v < 4; ++v) acc[u][v] = f32x4{0.f,0.f,0.f,0.f};
    }

    f16x8 afA[2], bfA[4], afB[2], bfB[4];
    K2_LOAD(afA, bfA, ks0)
    int ks = ks0;
    for (; ks + 2 <= ks1; ks += 2) {
        K2_LOAD(afB, bfB, ks + 1)
        K2_MFMA(afA, bfA)
        K2_LOAD(afA, bfA, ks + 2)   // one-step overread stays inside workspace; unused
        K2_MFMA(afB, bfB)
    }
    if (ks < ks1) K2_MFMA(afA, bfA)

    #pragma unroll
    for (int u = 0; u < 2; ++u) {
        dac[u] += __shfl_xor(dac[u], 16);
        dac[u] += __shfl_xor(dac[u], 32);
    }
    if (quad == 0) {
        #pragma unroll
        for (int u = 0; u < 2; ++u)
            dpp[slot*512 + ebase + u*16 + col] = dac[u];
    }
    float* dst = spp + (size_t)slot * 32768 + (size_t)equad * 8192;
    #pragma unroll
    for (int u = 0; u < 2; ++u)
        #pragma unroll
        for (int v = 0; v < 4; ++v)
            *(f32x4*)(dst + (size_t)((wave*2 + u)*4 + v)*256 + (size_t)lane*4) = acc[u][v];
}

// ---------------- K2r: reduce partials (grid 512, 4 waves split the p-range) ----------------
__global__ void k2r_reduce(const float* __restrict__ spp, const float* __restrict__ dpp,
                           float* __restrict__ spre, float* __restrict__ dstd) {
    __shared__ float red[4][64];
    __shared__ float rdp[4][64];
    const int lane = threadIdx.x & 63, wave = threadIdx.x >> 6;
    const int i = blockIdx.x * 64 + lane;        // i in [0, 32768)
    float s = 0.f;
    const int p0 = wave * (K2SPL / 4);
    for (int p = p0; p < p0 + K2SPL/4; ++p) s += spp[(size_t)p*32768 + i];
    red[wave][lane] = s;
    float tt = 0.f;
    if (i < 512) {
        for (int p = p0; p < p0 + K2SPL/4; ++p) tt += dpp[p*512 + i];
    }
    rdp[wave][lane] = tt;
    __syncthreads();
    if (wave == 0) {
        float sum = red[0][lane] + red[1][lane] + red[2][lane] + red[3][lane];
        int r = i & 3, L = (i >> 2) & 63, v = (i >> 8) & 3, g = (i >> 10) & 7, eq = (i >> 13) & 3;
        int e = eq*128 + (g >> 1)*32 + (g & 1)*16 + (L >> 4)*4 + r;
        int d = v*16 + (L & 15);
        spre[e*64 + d] = sum;
        if (i < 512)
            dstd[i] = rdp[0][lane] + rdp[1][lane] + rdp[2][lane] + rdp[3][lane];
    }
}

// ---------------- K3: per-head middle block, m-split 8 ways (grid 64) ----------------
__global__ void k3_attn(const float* __restrict__ spre, const float* __restrict__ dstd,
                        const float* __restrict__ b1, const float* __restrict__ wq,
                        const float* __restrict__ wk, const float* __restrict__ wv,
                        const float* __restrict__ w3, const float* __restrict__ b3,
                        f16* __restrict__ sout) {
    __shared__ float wa[64][65], wb[64][65], wc[64][65];   // wq,wk,wv; wa reused for w3
    __shared__ float ss[64][65], kk[64][65], vv[64][65];
    __shared__ float qq[8][65], sc[8][65];                 // slice-local (8 m-rows)
    const int h = blockIdx.x >> 3, ms = blockIdx.x & 7, tid = threadIdx.x;

    for (int i = tid; i < 4096; i += 256) {
        int r = i >> 6, c = i & 63;
        wa[r][c] = wq[i];
        wb[r][c] = wk[i];
        wc[r][c] = wv[i];
        ss[r][c] = spre[h*4096 + i] / (dstd[h*64 + r] + 1e-5f) + b1[c];
    }
    __syncthreads();

    // k, v full (64 rows)
    #pragma unroll
    for (int it = 0; it < 16; ++it) {
        int m = it*4 + (tid >> 6), e = tid & 63;
        float ak = 0.f, av = 0.f;
        #pragma unroll 8
        for (int d = 0; d < 64; ++d) {
            float sv = ss[m][d];
            ak += sv * wb[e][d];
            av += sv * wc[e][d];
        }
        kk[m][e] = ak; vv[m][e] = av;
    }
    // q: slice only (8 rows)
    #pragma unroll
    for (int it = 0; it < 2; ++it) {
        int ml = it*4 + (tid >> 6), e = tid & 63;
        float aq = 0.f;
        #pragma unroll 8
        for (int d = 0; d < 64; ++d) aq += ss[ms*8 + ml][d] * wa[e][d];
        qq[ml][e] = aq;
    }
    __syncthreads();

    // scores (slice); stage w3 into wa (wq dead after qq)
    for (int i = tid; i < 4096; i += 256) wa[i >> 6][i & 63] = w3[i];
    #pragma unroll
    for (int it = 0; it < 2; ++it) {
        int ml = it*4 + (tid >> 6), l = tid & 63;
        float a = 0.f;
        #pragma unroll 8
        for (int e = 0; e < 64; ++e) a += qq[ml][e] * kk[l][e];
        sc[ml][l] = a * 0.125f;
    }
    __syncthreads();

    if (tid < 8) {
        int ml = tid;
        float mx = -1e30f;
        #pragma unroll 8
        for (int l = 0; l < 64; ++l) mx = fmaxf(mx, sc[ml][l]);
        float sm = 0.f;
        #pragma unroll 8
        for (int l = 0; l < 64; ++l) { float ev = __expf(sc[ml][l] - mx); sc[ml][l] = ev; sm += ev; }
        float rs = 1.0f / sm;
        #pragma unroll 8
        for (int l = 0; l < 64; ++l) sc[ml][l] *= rs;
    }
    __syncthreads();

    // s_att (slice) -> qq
    #pragma unroll
    for (int it = 0; it < 2; ++it) {
        int ml = it*4 + (tid >> 6), e = tid & 63;
        float a = 0.f;
        #pragma unroll 8
        for (int l = 0; l < 64; ++l) a += sc[ml][l] * vv[l][e];
        qq[ml][e] = a;
    }
    __syncthreads();

    // s_out^T slice: all 64 d, 8 m
    #pragma unroll
    for (int it = 0; it < 2; ++it) {
        int d = it*32 + (tid >> 3), ml = tid & 7;
        float a = b3[d];
        #pragma unroll 8
        for (int e = 0; e < 64; ++e) a += qq[ml][e] * wa[d][e];
        sout[(h*64 + d)*64 + ms*8 + ml] = (f16)a;
    }
}

// ---------------- K4: deslice x_out = w @ s_out (frag-linear stage, nontemporal stores) ----------------
__launch_bounds__(256, 4)
__global__ void k4_deslice(const f16* __restrict__ wTf, const f16* __restrict__ sout,
                           float* __restrict__ out) {
    __shared__ __align__(16) char lmem[36864];   // ldsW 32768 B / ldsO 33024 B, aliased
    f16*   ldsW = (f16*)lmem;                    // [16384] frag-linear w block (ks = this tile)
    float* ldsO = (float*)lmem;                  // [16][516] f32 store stage

    const int tid = threadIdx.x, wave = tid >> 6, lane = tid & 63;
    const int quad = lane >> 4, col = lane & 15;

    // bijective XCD swizzle (nwg = 3126 = 8*390 + 6)
    const int bid = blockIdx.x;
    const int xcd = bid & 7, idx = bid >> 3;
    const int q = KSTEPS >> 3, r = KSTEPS & 7;   // 390, 6
    const int swz = (xcd < r ? xcd*(q+1) : r*(q+1) + (xcd - r)*q) + idx;
    const int n0 = swz * 32;

    // stage: ONE contiguous 32 KB block (frag-linear tile for ks = swz)
    const f16* srcW = wTf + (size_t)swz * 16384;
    #pragma unroll
    for (int i = 0; i < 8; ++i) {
        int id = tid + i*256;
        *(f16x8*)(ldsW + (size_t)id*8) = *(const f16x8*)(srcW + (size_t)id*8);
    }
    __syncthreads();

    f32x4 acc[2][2][4];
    #pragma unroll
    for (int hh = 0; hh < 2; ++hh)
        #pragma unroll
        for (int t = 0; t < 2; ++t)
            #pragma unroll
            for (int v = 0; v < 4; ++v) acc[hh][t][v] = f32x4{0.f,0.f,0.f,0.f};

    #pragma unroll
    for (int hh = 0; hh < 2; ++hh) {
        int h = wave*2 + hh;
        #pragma unroll
        for (int ks = 0; ks < 2; ++ks) {
            f16x8 af[2], bf[4];
            // af[t][j] = w[e=h*64+ks*32+quad*8+j][n=n0+t*16+col], from frag-linear image
            #pragma unroll
            for (int t = 0; t < 2; ++t) {
                const int fb = (h*4 + ks*2 + (quad >> 1))*512
                             + (t*2 + (col >> 3))*128 + (quad & 1)*64 + (col & 7);
                f16x8 a;
                #pragma unroll
                for (int j = 0; j < 8; ++j)
                    a[j] = ldsW[fb + j*8];
                af[t] = a;
            }
            #pragma unroll
            for (int v = 0; v < 4; ++v)
                bf[v] = *(const f16x8*)(sout + (size_t)(h*64 + v*16 + col)*64 + ks*32 + quad*8);
            #pragma unroll
            for (int t = 0; t < 2; ++t)
                #pragma unroll
                for (int v = 0; v < 4; ++v)
                    acc[hh][t][v] = __builtin_amdgcn_mfma_f32_16x16x32_f16(af[t], bf[v], acc[hh][t][v], 0, 0, 0);
        }
    }

    // ---- epilogue: LDS transpose -> coalesced 2 KB-row NONTEMPORAL stores (2 passes of 16 n) ----
    #pragma unroll
    for (int p = 0; p < 2; ++p) {
        __syncthreads();                         // p0: ldsW reads done; p1: p0 stores done
        #pragma unroll
        for (int hh = 0; hh < 2; ++hh) {
            int h = wave*2 + hh;
            #pragma unroll
            for (int v = 0; v < 4; ++v)
                #pragma unroll
                for (int r2 = 0; r2 < 4; ++r2)
                    ldsO[(size_t)(quad*4 + r2)*516 + h*64 + v*16 + col] = acc[hh][p][v][r2];
        }
        __syncthreads();
        #pragma unroll
        for (int it = 0; it < 8; ++it) {
            int id = tid + it*256;               // 2048 chunks of 16 B (16 rows x 128)
            int row = id >> 7, ch = id & 127;
            int n = n0 + p*16 + row;
            if (n < N_TOK) {
                f32x4 v4 = *(const f32x4*)(ldsO + (size_t)row*516 + ch*4);
                __builtin_nontemporal_store(v4, (f32x4*)(out + (size_t)n*512 + ch*4));
            }
        }
    }
}

// ---------------- launcher ----------------
extern "C" void kernel_launch(void* const* d_in, const int* in_sizes, int n_in,
                              void* d_out, int out_size, void* d_ws, size_t ws_size,
                              hipStream_t stream) {
    const float* x           = (const float*)d_in[0];
    const float* temperature = (const float*)d_in[1];
    const float* w_slice     = (const float*)d_in[2];
    const float* b_slice     = (const float*)d_in[3];
    const float* w1          = (const float*)d_in[4];
    const float* b1          = (const float*)d_in[5];
    const float* wq          = (const float*)d_in[6];
    const float* wk          = (const float*)d_in[7];
    const float* wv          = (const float*)d_in[8];
    const float* w3          = (const float*)d_in[9];
    const float* b3          = (const float*)d_in[10];
    float* out = (float*)d_out;
    char*  ws  = (char*)d_ws;

    f16*   wTf   = (f16*)(ws + O_WT);
    f16*   yTf   = (f16*)(ws + O_YT);
    f16*   wfr   = (f16*)(ws + O_WFR);
    float* spp   = (float*)(ws + O_SPP);
    float* dpp   = (float*)(ws + O_DPP);
    float* spre  = (float*)(ws + O_SPRE);
    float* dstd  = (float*)(ws + O_DSTD);
    f16*   sout  = (f16*)(ws + O_SOUT);

    k0_pack<<<144, 256, 0, stream>>>(w_slice, w1, wfr);
    k1_slice<<<NT1*2, 256, 0, stream>>>(x, temperature, wfr, b_slice, wTf, yTf);
    k2_spre<<<K2SPL*4, 256, 0, stream>>>(wTf, yTf, spp, dpp);
    k2r_reduce<<<512, 256, 0, stream>>>(spp, dpp, spre, dstd);
    k3_attn<<<64, 256, 0, stream>>>(spre, dstd, b1, wq, wk, wv, w3, b3, sout);
    k4_deslice<<<KSTEPS, 256, 0, stream>>>(wTf, sout, out);
}